// Round 1
// baseline (929.060 us; speedup 1.0000x reference)
//
#include <hip/hip_runtime.h>

#define IN_DIM 128
#define F1 256      // HEADS*HID = 4*64
#define HID 64
#define OUT_DIM 32
#define NEG 0.2f

// ---------------- GEMM1: h1[N,256] = x[N,128] @ W1[128,256] ----------------
// 64x64 tile, 256 threads, 4x4 per thread, fp32 vector ALU.
__global__ __launch_bounds__(256) void k_gemm1(const float* __restrict__ x,
    const float* __restrict__ W1, float* __restrict__ h1, int n) {
  __shared__ float xs[32][68];   // xs[k][row], padded so float4 reads stay 16B-aligned
  __shared__ float ws[32][64];   // ws[k][col]
  const int tid = threadIdx.x;
  const int tx = tid & 15, ty = tid >> 4;
  const int rb = blockIdx.x * 64, cb = blockIdx.y * 64;
  float acc[4][4] = {{0.f}};
  for (int kb = 0; kb < IN_DIM; kb += 32) {
#pragma unroll
    for (int i = 0; i < 8; ++i) {
      int idx = tid + i * 256;
      int r = idx >> 5, c = idx & 31;
      int row = rb + r;
      xs[c][r] = (row < n) ? x[(size_t)row * IN_DIM + kb + c] : 0.f;
    }
#pragma unroll
    for (int i = 0; i < 8; ++i) {
      int idx = tid + i * 256;
      int kk = idx >> 6, cc = idx & 63;
      ws[kk][cc] = W1[(size_t)(kb + kk) * F1 + cb + cc];
    }
    __syncthreads();
#pragma unroll
    for (int kk = 0; kk < 32; ++kk) {
      const float4 a4 = *(const float4*)&xs[kk][ty * 4];
      const float4 b4 = *(const float4*)&ws[kk][tx * 4];
      const float av[4] = {a4.x, a4.y, a4.z, a4.w};
      const float bv[4] = {b4.x, b4.y, b4.z, b4.w};
#pragma unroll
      for (int i = 0; i < 4; ++i)
#pragma unroll
        for (int j = 0; j < 4; ++j)
          acc[i][j] += av[i] * bv[j];
    }
    __syncthreads();
  }
#pragma unroll
  for (int i = 0; i < 4; ++i) {
    int row = rb + ty * 4 + i;
    if (row < n) {
      float4 v = make_float4(acc[i][0], acc[i][1], acc[i][2], acc[i][3]);
      *(float4*)&h1[(size_t)row * F1 + cb + tx * 4] = v;
    }
  }
}

// ------------- alphas1: as1/ad1[N,4] = rowwise dots of h1 with a1_src/a1_dst -------------
// one wave per node; lane l holds h1[n][h*64+l]
__global__ __launch_bounds__(256) void k_alphas1(const float* __restrict__ h1,
    const float* __restrict__ a_src, const float* __restrict__ a_dst,
    float* __restrict__ as1, float* __restrict__ ad1, int n) {
  int node = blockIdx.x * 4 + (threadIdx.x >> 6);
  int lane = threadIdx.x & 63;
  if (node >= n) return;
  const float* hrow = h1 + (size_t)node * F1;
  float s[4], d[4];
#pragma unroll
  for (int h = 0; h < 4; ++h) {
    float v = hrow[h * 64 + lane];
    s[h] = v * a_src[h * 64 + lane];
    d[h] = v * a_dst[h * 64 + lane];
  }
#pragma unroll
  for (int m = 32; m >= 1; m >>= 1) {
#pragma unroll
    for (int h = 0; h < 4; ++h) {
      s[h] += __shfl_xor(s[h], m, 64);
      d[h] += __shfl_xor(d[h], m, 64);
    }
  }
  if (lane == 0) {
#pragma unroll
    for (int h = 0; h < 4; ++h) {
      as1[(size_t)node * 4 + h] = s[h];
      ad1[(size_t)node * 4 + h] = d[h];
    }
  }
}

// ---------------- CSR build: histogram over dst (self loops appended) ----------------
__global__ __launch_bounds__(256) void k_hist(const int* __restrict__ adj,
    int* __restrict__ cnt, int E_, int n) {
  int e = blockIdx.x * 256 + threadIdx.x;
  int ET = E_ + n;
  if (e >= ET) return;
  int d = (e < E_) ? adj[E_ + e] : (e - E_);
  atomicAdd(&cnt[d], 1);
}

// single-block exclusive scan over cnt[0..n) -> offs[0..n], cursor copy
__global__ __launch_bounds__(1024) void k_scan(const int* __restrict__ cnt,
    int* __restrict__ offs, int* __restrict__ cursor, int n) {
  __shared__ int wsum[16];
  __shared__ int carry_s;
  const int tid = threadIdx.x;
  const int lane = tid & 63;
  const int w = tid >> 6;
  if (tid == 0) carry_s = 0;
  __syncthreads();
  for (int base = 0; base < n; base += 1024) {
    int i = base + tid;
    int v = (i < n) ? cnt[i] : 0;
    int incl = v;
#pragma unroll
    for (int d = 1; d < 64; d <<= 1) {
      int t = __shfl_up(incl, (unsigned)d, 64);
      if (lane >= d) incl += t;
    }
    if (lane == 63) wsum[w] = incl;
    __syncthreads();
    if (tid == 0) {
      int run = carry_s;
#pragma unroll
      for (int k = 0; k < 16; ++k) { int t = wsum[k]; wsum[k] = run; run += t; }
      carry_s = run;
    }
    __syncthreads();
    int excl = wsum[w] + incl - v;
    if (i < n) { offs[i] = excl; cursor[i] = excl; }
    __syncthreads();
  }
  if (tid == 0) offs[n] = carry_s;
}

// scatter edge srcs into CSR slots by dst
__global__ __launch_bounds__(256) void k_scatter(const int* __restrict__ adj,
    int* __restrict__ cursor, int* __restrict__ csr_src, int E_, int n) {
  int e = blockIdx.x * 256 + threadIdx.x;
  int ET = E_ + n;
  if (e >= ET) return;
  int s, d;
  if (e < E_) { s = adj[e]; d = adj[E_ + e]; } else { s = d = e - E_; }
  int pos = atomicAdd(&cursor[d], 1);
  csr_src[pos] = s;
}

// ---------------- fused GAT layer 1 aggregate + normalize + bias + ReLU ----------------
// one wave per dst node; lane l handles feature l of each of 4 heads
__global__ __launch_bounds__(256) void k_agg1(const float* __restrict__ h1,
    const float* __restrict__ as1, const float* __restrict__ ad1,
    const int* __restrict__ offs, const int* __restrict__ csr_src,
    const float* __restrict__ b1, float* __restrict__ relu1, int n) {
  int node = blockIdx.x * 4 + (threadIdx.x >> 6);
  int lane = threadIdx.x & 63;
  if (node >= n) return;
  const int j0 = offs[node], j1 = offs[node + 1];
  const float4 ad = *(const float4*)(ad1 + (size_t)node * 4);
  float acc0 = 0.f, acc1 = 0.f, acc2 = 0.f, acc3 = 0.f;
  float den0 = 0.f, den1 = 0.f, den2 = 0.f, den3 = 0.f;
  for (int j = j0; j < j1; ++j) {
    int src = csr_src[j];
    const float* hs = h1 + (size_t)src * F1;
    const float4 as = *(const float4*)(as1 + (size_t)src * 4);
    float e0 = as.x + ad.x; e0 = (e0 >= 0.f) ? e0 : NEG * e0; float w0 = __expf(e0);
    float e1 = as.y + ad.y; e1 = (e1 >= 0.f) ? e1 : NEG * e1; float w1 = __expf(e1);
    float e2 = as.z + ad.z; e2 = (e2 >= 0.f) ? e2 : NEG * e2; float w2 = __expf(e2);
    float e3 = as.w + ad.w; e3 = (e3 >= 0.f) ? e3 : NEG * e3; float w3 = __expf(e3);
    den0 += w0; den1 += w1; den2 += w2; den3 += w3;
    acc0 += w0 * hs[lane];
    acc1 += w1 * hs[64 + lane];
    acc2 += w2 * hs[128 + lane];
    acc3 += w3 * hs[192 + lane];
  }
  float r0 = acc0 / den0 + b1[lane];        r0 = fmaxf(r0, 0.f);
  float r1 = acc1 / den1 + b1[64 + lane];   r1 = fmaxf(r1, 0.f);
  float r2 = acc2 / den2 + b1[128 + lane];  r2 = fmaxf(r2, 0.f);
  float r3 = acc3 / den3 + b1[192 + lane];  r3 = fmaxf(r3, 0.f);
  size_t base = (size_t)node * F1;
  relu1[base + lane] = r0;
  relu1[base + 64 + lane] = r1;
  relu1[base + 128 + lane] = r2;
  relu1[base + 192 + lane] = r3;
}

// ---------------- GEMM2: h2[N,32] = relu1[N,256] @ W2[256,32]; fused alpha2 dots --------
__global__ __launch_bounds__(256) void k_gemm2(const float* __restrict__ relu1,
    const float* __restrict__ W2, const float* __restrict__ a2s_w,
    const float* __restrict__ a2d_w, float* __restrict__ h2,
    float* __restrict__ as2, float* __restrict__ ad2, int n) {
  __shared__ float w2s[F1 * OUT_DIM];  // 32 KB, whole W2
  __shared__ float xs[64][33];
  const int tid = threadIdx.x;
  const int tx = tid & 31, ty = tid >> 5;   // ty in [0,8)
  const int rb = blockIdx.x * 64;
  for (int i = tid; i < F1 * OUT_DIM; i += 256) w2s[i] = W2[i];
  float acc[8] = {0.f, 0.f, 0.f, 0.f, 0.f, 0.f, 0.f, 0.f};
  for (int kb = 0; kb < F1; kb += 32) {
#pragma unroll
    for (int i = 0; i < 8; ++i) {
      int idx = tid + i * 256;
      int r = idx >> 5, c = idx & 31;
      int row = rb + r;
      xs[r][c] = (row < n) ? relu1[(size_t)row * F1 + kb + c] : 0.f;
    }
    __syncthreads();
#pragma unroll
    for (int kk = 0; kk < 32; ++kk) {
      float b = w2s[(kb + kk) * OUT_DIM + tx];
#pragma unroll
      for (int i = 0; i < 8; ++i)
        acc[i] += xs[ty + i * 8][kk] * b;
    }
    __syncthreads();
  }
#pragma unroll
  for (int i = 0; i < 8; ++i) {
    int row = rb + ty + i * 8;
    float v = acc[i];
    if (row < n) h2[(size_t)row * OUT_DIM + tx] = v;
    float ssrc = v * a2s_w[tx];
    float sdst = v * a2d_w[tx];
#pragma unroll
    for (int m = 16; m >= 1; m >>= 1) {
      ssrc += __shfl_xor(ssrc, m, 64);
      sdst += __shfl_xor(sdst, m, 64);
    }
    if (tx == 0 && row < n) { as2[row] = ssrc; ad2[row] = sdst; }
  }
}

// -------- fused GAT layer 2 aggregate + log_softmax + lin_W contraction + pool --------
// one wave per dst node; lanes 0..31 hold the 32 output features
__global__ __launch_bounds__(256) void k_agg2(const float* __restrict__ h2,
    const float* __restrict__ as2, const float* __restrict__ ad2,
    const int* __restrict__ offs, const int* __restrict__ csr_src,
    const float* __restrict__ b2, const float* __restrict__ linW,
    const int* __restrict__ batch, float* __restrict__ gsum,
    float* __restrict__ gcnt, int n) {
  int node = blockIdx.x * 4 + (threadIdx.x >> 6);
  int lane = threadIdx.x & 63;
  if (node >= n) return;
  const int j0 = offs[node], j1 = offs[node + 1];
  const float adv = ad2[node];
  const int l = lane & 31;
  const bool lo = lane < 32;
  float acc = 0.f, den = 0.f;
  for (int j = j0; j < j1; ++j) {
    int src = csr_src[j];
    float e = as2[src] + adv;
    e = (e >= 0.f) ? e : NEG * e;
    float w = __expf(e);
    den += w;
    float hv = lo ? h2[(size_t)src * OUT_DIM + l] : 0.f;
    acc += w * hv;
  }
  float o = acc / den + b2[l];
  // log_softmax over 32 lanes (masks<32 keep halves independent; upper half unused)
  float m = o;
#pragma unroll
  for (int mm = 16; mm >= 1; mm >>= 1) m = fmaxf(m, __shfl_xor(m, mm, 64));
  float ex = __expf(o - m);
  float ssum = ex;
#pragma unroll
  for (int mm = 16; mm >= 1; mm >>= 1) ssum += __shfl_xor(ssum, mm, 64);
  float ls = o - m - __logf(ssum);
  float sc = lo ? ls * linW[l] : 0.f;
#pragma unroll
  for (int mm = 16; mm >= 1; mm >>= 1) sc += __shfl_xor(sc, mm, 64);
  if (lane == 0) {
    int g = batch[node];
    atomicAdd(&gsum[g], sc);
    atomicAdd(&gcnt[g], 1.0f);
  }
}

__global__ void k_final(const float* __restrict__ gsum, const float* __restrict__ gcnt,
                        const float* __restrict__ linb, float* __restrict__ out, int g_) {
  int g = threadIdx.x;
  if (g < g_) out[g] = gsum[g] / fmaxf(gcnt[g], 1.0f) + linb[0];
}

extern "C" void kernel_launch(void* const* d_in, const int* in_sizes, int n_in,
                              void* d_out, int out_size, void* d_ws, size_t ws_size,
                              hipStream_t stream) {
  const float* x    = (const float*)d_in[0];
  const int*   adj  = (const int*)d_in[1];
  const int*   batch= (const int*)d_in[2];
  const float* W1   = (const float*)d_in[3];
  const float* a1s  = (const float*)d_in[4];
  const float* a1d  = (const float*)d_in[5];
  const float* b1   = (const float*)d_in[6];
  const float* W2   = (const float*)d_in[7];
  const float* a2s  = (const float*)d_in[8];
  const float* a2d  = (const float*)d_in[9];
  const float* b2   = (const float*)d_in[10];
  const float* linW = (const float*)d_in[11];
  const float* linb = (const float*)d_in[12];

  const int N = in_sizes[0] / IN_DIM;
  const int E = in_sizes[1] / 2;
  const int ET = E + N;
  const int G = out_size;   // 64

  char* wsb = (char*)d_ws;
  size_t off = 0;
  auto take = [&](size_t bytes) -> char* {
    char* p = wsb + off;
    off += (bytes + 255) & ~(size_t)255;
    return p;
  };
  float* h1     = (float*)take((size_t)N * F1 * 4);
  float* relu1  = (float*)take((size_t)N * F1 * 4);
  float* as1    = (float*)take((size_t)N * 4 * 4);
  float* ad1    = (float*)take((size_t)N * 4 * 4);
  float* h2     = (float*)take((size_t)N * OUT_DIM * 4);
  float* as2v   = (float*)take((size_t)N * 4);
  float* ad2v   = (float*)take((size_t)N * 4);
  int*   cnt    = (int*)take((size_t)N * 4);
  int*   offs   = (int*)take((size_t)(N + 1) * 4);
  int*   cursor = (int*)take((size_t)N * 4);
  int*   csr_src= (int*)take((size_t)ET * 4);
  float* gsum   = (float*)take((size_t)G * 4);
  float* gcnt   = (float*)take((size_t)G * 4);
  (void)ws_size; (void)n_in;

  hipMemsetAsync(cnt, 0, (size_t)N * 4, stream);
  hipMemsetAsync(gsum, 0, (size_t)G * 4, stream);
  hipMemsetAsync(gcnt, 0, (size_t)G * 4, stream);

  dim3 b256(256);
  k_gemm1<<<dim3((N + 63) / 64, F1 / 64), b256, 0, stream>>>(x, W1, h1, N);
  k_alphas1<<<dim3((N + 3) / 4), b256, 0, stream>>>(h1, a1s, a1d, as1, ad1, N);
  k_hist<<<dim3((ET + 255) / 256), b256, 0, stream>>>(adj, cnt, E, N);
  k_scan<<<1, 1024, 0, stream>>>(cnt, offs, cursor, N);
  k_scatter<<<dim3((ET + 255) / 256), b256, 0, stream>>>(adj, cursor, csr_src, E, N);
  k_agg1<<<dim3((N + 3) / 4), b256, 0, stream>>>(h1, as1, ad1, offs, csr_src, b1, relu1, N);
  k_gemm2<<<dim3((N + 63) / 64), b256, 0, stream>>>(relu1, W2, a2s, a2d, h2, as2v, ad2v, N);
  k_agg2<<<dim3((N + 3) / 4), b256, 0, stream>>>(h2, as2v, ad2v, offs, csr_src, b2, linW, batch, gsum, gcnt, N);
  k_final<<<1, 64, 0, stream>>>(gsum, gcnt, linb, (float*)d_out, G);
}

// Round 2
// 895.797 us; speedup vs baseline: 1.0371x; 1.0371x over previous
//
#include <hip/hip_runtime.h>

#define IN_DIM 128
#define F1 256      // HEADS*HID = 4*64
#define HID 64
#define OUT_DIM 32
#define NEG 0.2f

// ---------------- GEMM1: h1[N,256] = x[N,128] @ W1[128,256] ----------------
__global__ __launch_bounds__(256) void k_gemm1(const float* __restrict__ x,
    const float* __restrict__ W1, float* __restrict__ h1, int n) {
  __shared__ float xs[32][68];
  __shared__ float ws[32][64];
  const int tid = threadIdx.x;
  const int tx = tid & 15, ty = tid >> 4;
  const int rb = blockIdx.x * 64, cb = blockIdx.y * 64;
  float acc[4][4] = {{0.f}};
  for (int kb = 0; kb < IN_DIM; kb += 32) {
#pragma unroll
    for (int i = 0; i < 8; ++i) {
      int idx = tid + i * 256;
      int r = idx >> 5, c = idx & 31;
      int row = rb + r;
      xs[c][r] = (row < n) ? x[(size_t)row * IN_DIM + kb + c] : 0.f;
    }
#pragma unroll
    for (int i = 0; i < 8; ++i) {
      int idx = tid + i * 256;
      int kk = idx >> 6, cc = idx & 63;
      ws[kk][cc] = W1[(size_t)(kb + kk) * F1 + cb + cc];
    }
    __syncthreads();
#pragma unroll
    for (int kk = 0; kk < 32; ++kk) {
      const float4 a4 = *(const float4*)&xs[kk][ty * 4];
      const float4 b4 = *(const float4*)&ws[kk][tx * 4];
      const float av[4] = {a4.x, a4.y, a4.z, a4.w};
      const float bv[4] = {b4.x, b4.y, b4.z, b4.w};
#pragma unroll
      for (int i = 0; i < 4; ++i)
#pragma unroll
        for (int j = 0; j < 4; ++j)
          acc[i][j] += av[i] * bv[j];
    }
    __syncthreads();
  }
#pragma unroll
  for (int i = 0; i < 4; ++i) {
    int row = rb + ty * 4 + i;
    if (row < n) {
      float4 v = make_float4(acc[i][0], acc[i][1], acc[i][2], acc[i][3]);
      *(float4*)&h1[(size_t)row * F1 + cb + tx * 4] = v;
    }
  }
}

// ------------- alphas1 -------------
__global__ __launch_bounds__(256) void k_alphas1(const float* __restrict__ h1,
    const float* __restrict__ a_src, const float* __restrict__ a_dst,
    float* __restrict__ as1, float* __restrict__ ad1, int n) {
  int node = blockIdx.x * 4 + (threadIdx.x >> 6);
  int lane = threadIdx.x & 63;
  if (node >= n) return;
  const float* hrow = h1 + (size_t)node * F1;
  float s[4], d[4];
#pragma unroll
  for (int h = 0; h < 4; ++h) {
    float v = hrow[h * 64 + lane];
    s[h] = v * a_src[h * 64 + lane];
    d[h] = v * a_dst[h * 64 + lane];
  }
#pragma unroll
  for (int m = 32; m >= 1; m >>= 1) {
#pragma unroll
    for (int h = 0; h < 4; ++h) {
      s[h] += __shfl_xor(s[h], m, 64);
      d[h] += __shfl_xor(d[h], m, 64);
    }
  }
  if (lane == 0) {
#pragma unroll
    for (int h = 0; h < 4; ++h) {
      as1[(size_t)node * 4 + h] = s[h];
      ad1[(size_t)node * 4 + h] = d[h];
    }
  }
}

// ---------------- CSR build ----------------
__global__ __launch_bounds__(256) void k_hist(const int* __restrict__ adj,
    int* __restrict__ cnt, int E_, int n) {
  int e = blockIdx.x * 256 + threadIdx.x;
  int ET = E_ + n;
  if (e >= ET) return;
  int d = (e < E_) ? adj[E_ + e] : (e - E_);
  atomicAdd(&cnt[d], 1);
}

// parallel scan, phase A: per-block (1024 elems) local exclusive scan + block sums
__global__ __launch_bounds__(256) void k_scan_local(const int* __restrict__ cnt,
    int* __restrict__ offs, int* __restrict__ bsum, int n) {
  __shared__ int wsums[4];
  const int tid = threadIdx.x;
  const int lane = tid & 63, w = tid >> 6;
  const int base = blockIdx.x * 1024;
  const int i0 = base + tid * 4;
  int v[4];
#pragma unroll
  for (int k = 0; k < 4; ++k) { int i = i0 + k; v[k] = (i < n) ? cnt[i] : 0; }
  int tsum = v[0] + v[1] + v[2] + v[3];
  int incl = tsum;
#pragma unroll
  for (int d = 1; d < 64; d <<= 1) {
    int t = __shfl_up(incl, (unsigned)d, 64);
    if (lane >= d) incl += t;
  }
  if (lane == 63) wsums[w] = incl;
  __syncthreads();
  int pre = 0;
  for (int k = 0; k < w; ++k) pre += wsums[k];
  int run = pre + incl - tsum;   // exclusive before this thread's 4 elements
#pragma unroll
  for (int k = 0; k < 4; ++k) { int i = i0 + k; if (i < n) offs[i] = run; run += v[k]; }
  if (tid == 255) bsum[blockIdx.x] = pre + incl;
}

// phase B: single-wave exclusive scan of block sums; writes total to offs[n]
__global__ void k_scan_bsum(int* __restrict__ bsum, int nb, int* __restrict__ offs_n) {
  int lane = threadIdx.x;   // 64 threads
  int carry = 0;
  for (int base = 0; base < nb; base += 64) {
    int i = base + lane;
    int v = (i < nb) ? bsum[i] : 0;
    int incl = v;
#pragma unroll
    for (int d = 1; d < 64; d <<= 1) {
      int t = __shfl_up(incl, (unsigned)d, 64);
      if (lane >= d) incl += t;
    }
    if (i < nb) bsum[i] = carry + incl - v;
    int tot = __shfl(incl, 63, 64);
    carry += tot;
  }
  if (lane == 0) *offs_n = carry;
}

// phase C: add block offsets in place; also fill cursor
__global__ __launch_bounds__(256) void k_scan_add(int* __restrict__ offs,
    const int* __restrict__ bsum, int* __restrict__ cursor, int n) {
  int i = blockIdx.x * 256 + threadIdx.x;
  if (i < n) {
    int v = offs[i] + bsum[i >> 10];
    offs[i] = v;
    cursor[i] = v;
  }
}

__global__ __launch_bounds__(256) void k_scatter(const int* __restrict__ adj,
    int* __restrict__ cursor, int* __restrict__ csr_src, int E_, int n) {
  int e = blockIdx.x * 256 + threadIdx.x;
  int ET = E_ + n;
  if (e >= ET) return;
  int s, d;
  if (e < E_) { s = adj[e]; d = adj[E_ + e]; } else { s = d = e - E_; }
  int pos = atomicAdd(&cursor[d], 1);
  csr_src[pos] = s;
}

// ---------------- fused GAT layer 1: 4-edge chunked for MLP ----------------
__global__ __launch_bounds__(256) void k_agg1(const float* __restrict__ h1,
    const float* __restrict__ as1, const float* __restrict__ ad1,
    const int* __restrict__ offs, const int* __restrict__ csr_src,
    const float* __restrict__ b1, float* __restrict__ relu1, int n) {
  int node = blockIdx.x * 4 + (threadIdx.x >> 6);
  int lane = threadIdx.x & 63;
  if (node >= n) return;
  const int j0 = offs[node], j1 = offs[node + 1];
  const float4 ad = *(const float4*)(ad1 + (size_t)node * 4);
  float acc0 = 0.f, acc1 = 0.f, acc2 = 0.f, acc3 = 0.f;
  float den0 = 0.f, den1 = 0.f, den2 = 0.f, den3 = 0.f;
  int j = j0;
  for (; j + 4 <= j1; j += 4) {
    // 4 independent edge gathers in flight
    const int s0 = csr_src[j + 0], s1 = csr_src[j + 1];
    const int s2 = csr_src[j + 2], s3 = csr_src[j + 3];
    const float4 A0 = *(const float4*)(as1 + (size_t)s0 * 4);
    const float4 A1 = *(const float4*)(as1 + (size_t)s1 * 4);
    const float4 A2 = *(const float4*)(as1 + (size_t)s2 * 4);
    const float4 A3 = *(const float4*)(as1 + (size_t)s3 * 4);
    const float* p0 = h1 + (size_t)s0 * F1 + lane;
    const float* p1 = h1 + (size_t)s1 * F1 + lane;
    const float* p2 = h1 + (size_t)s2 * F1 + lane;
    const float* p3 = h1 + (size_t)s3 * F1 + lane;
    float v00 = p0[0], v01 = p0[64], v02 = p0[128], v03 = p0[192];
    float v10 = p1[0], v11 = p1[64], v12 = p1[128], v13 = p1[192];
    float v20 = p2[0], v21 = p2[64], v22 = p2[128], v23 = p2[192];
    float v30 = p3[0], v31 = p3[64], v32 = p3[128], v33 = p3[192];
    float e, w;
    e = A0.x + ad.x; e = (e >= 0.f) ? e : NEG * e; w = __expf(e); den0 += w; acc0 += w * v00;
    e = A0.y + ad.y; e = (e >= 0.f) ? e : NEG * e; w = __expf(e); den1 += w; acc1 += w * v01;
    e = A0.z + ad.z; e = (e >= 0.f) ? e : NEG * e; w = __expf(e); den2 += w; acc2 += w * v02;
    e = A0.w + ad.w; e = (e >= 0.f) ? e : NEG * e; w = __expf(e); den3 += w; acc3 += w * v03;
    e = A1.x + ad.x; e = (e >= 0.f) ? e : NEG * e; w = __expf(e); den0 += w; acc0 += w * v10;
    e = A1.y + ad.y; e = (e >= 0.f) ? e : NEG * e; w = __expf(e); den1 += w; acc1 += w * v11;
    e = A1.z + ad.z; e = (e >= 0.f) ? e : NEG * e; w = __expf(e); den2 += w; acc2 += w * v12;
    e = A1.w + ad.w; e = (e >= 0.f) ? e : NEG * e; w = __expf(e); den3 += w; acc3 += w * v13;
    e = A2.x + ad.x; e = (e >= 0.f) ? e : NEG * e; w = __expf(e); den0 += w; acc0 += w * v20;
    e = A2.y + ad.y; e = (e >= 0.f) ? e : NEG * e; w = __expf(e); den1 += w; acc1 += w * v21;
    e = A2.z + ad.z; e = (e >= 0.f) ? e : NEG * e; w = __expf(e); den2 += w; acc2 += w * v22;
    e = A2.w + ad.w; e = (e >= 0.f) ? e : NEG * e; w = __expf(e); den3 += w; acc3 += w * v23;
    e = A3.x + ad.x; e = (e >= 0.f) ? e : NEG * e; w = __expf(e); den0 += w; acc0 += w * v30;
    e = A3.y + ad.y; e = (e >= 0.f) ? e : NEG * e; w = __expf(e); den1 += w; acc1 += w * v31;
    e = A3.z + ad.z; e = (e >= 0.f) ? e : NEG * e; w = __expf(e); den2 += w; acc2 += w * v32;
    e = A3.w + ad.w; e = (e >= 0.f) ? e : NEG * e; w = __expf(e); den3 += w; acc3 += w * v33;
  }
  for (; j < j1; ++j) {
    const int src = csr_src[j];
    const float* hs = h1 + (size_t)src * F1;
    const float4 as = *(const float4*)(as1 + (size_t)src * 4);
    float e0 = as.x + ad.x; e0 = (e0 >= 0.f) ? e0 : NEG * e0; float w0 = __expf(e0);
    float e1 = as.y + ad.y; e1 = (e1 >= 0.f) ? e1 : NEG * e1; float w1 = __expf(e1);
    float e2 = as.z + ad.z; e2 = (e2 >= 0.f) ? e2 : NEG * e2; float w2 = __expf(e2);
    float e3 = as.w + ad.w; e3 = (e3 >= 0.f) ? e3 : NEG * e3; float w3 = __expf(e3);
    den0 += w0; den1 += w1; den2 += w2; den3 += w3;
    acc0 += w0 * hs[lane];
    acc1 += w1 * hs[64 + lane];
    acc2 += w2 * hs[128 + lane];
    acc3 += w3 * hs[192 + lane];
  }
  float r0 = acc0 / den0 + b1[lane];        r0 = fmaxf(r0, 0.f);
  float r1 = acc1 / den1 + b1[64 + lane];   r1 = fmaxf(r1, 0.f);
  float r2 = acc2 / den2 + b1[128 + lane];  r2 = fmaxf(r2, 0.f);
  float r3 = acc3 / den3 + b1[192 + lane];  r3 = fmaxf(r3, 0.f);
  size_t base = (size_t)node * F1;
  relu1[base + lane] = r0;
  relu1[base + 64 + lane] = r1;
  relu1[base + 128 + lane] = r2;
  relu1[base + 192 + lane] = r3;
}

// ---------------- GEMM2 + fused alpha2 dots ----------------
__global__ __launch_bounds__(256) void k_gemm2(const float* __restrict__ relu1,
    const float* __restrict__ W2, const float* __restrict__ a2s_w,
    const float* __restrict__ a2d_w, float* __restrict__ h2,
    float* __restrict__ as2, float* __restrict__ ad2, int n) {
  __shared__ float w2s[F1 * OUT_DIM];
  __shared__ float xs[64][33];
  const int tid = threadIdx.x;
  const int tx = tid & 31, ty = tid >> 5;
  const int rb = blockIdx.x * 64;
  for (int i = tid; i < F1 * OUT_DIM; i += 256) w2s[i] = W2[i];
  float acc[8] = {0.f, 0.f, 0.f, 0.f, 0.f, 0.f, 0.f, 0.f};
  for (int kb = 0; kb < F1; kb += 32) {
#pragma unroll
    for (int i = 0; i < 8; ++i) {
      int idx = tid + i * 256;
      int r = idx >> 5, c = idx & 31;
      int row = rb + r;
      xs[r][c] = (row < n) ? relu1[(size_t)row * F1 + kb + c] : 0.f;
    }
    __syncthreads();
#pragma unroll
    for (int kk = 0; kk < 32; ++kk) {
      float b = w2s[(kb + kk) * OUT_DIM + tx];
#pragma unroll
      for (int i = 0; i < 8; ++i)
        acc[i] += xs[ty + i * 8][kk] * b;
    }
    __syncthreads();
  }
#pragma unroll
  for (int i = 0; i < 8; ++i) {
    int row = rb + ty + i * 8;
    float v = acc[i];
    if (row < n) h2[(size_t)row * OUT_DIM + tx] = v;
    float ssrc = v * a2s_w[tx];
    float sdst = v * a2d_w[tx];
#pragma unroll
    for (int m = 16; m >= 1; m >>= 1) {
      ssrc += __shfl_xor(ssrc, m, 64);
      sdst += __shfl_xor(sdst, m, 64);
    }
    if (tx == 0 && row < n) { as2[row] = ssrc; ad2[row] = sdst; }
  }
}

// -------- fused GAT layer 2: half-wave edge pairing + 4-step chunk (8 edges in flight) --------
__global__ __launch_bounds__(256) void k_agg2(const float* __restrict__ h2,
    const float* __restrict__ as2, const float* __restrict__ ad2,
    const int* __restrict__ offs, const int* __restrict__ csr_src,
    const float* __restrict__ b2, const float* __restrict__ linW,
    const int* __restrict__ batch, float* __restrict__ gsum,
    float* __restrict__ gcnt, int n) {
  int node = blockIdx.x * 4 + (threadIdx.x >> 6);
  int lane = threadIdx.x & 63;
  if (node >= n) return;
  const int j0 = offs[node], j1 = offs[node + 1];
  const float adv = ad2[node];
  const int g = lane >> 5;       // which half-wave → which edge of the pair
  const int l = lane & 31;       // feature
  float acc = 0.f, den = 0.f;
  int jj = j0;
  for (; jj + 8 <= j1; jj += 8) {
    const int s0 = csr_src[jj + 0 + g];
    const int s1 = csr_src[jj + 2 + g];
    const int s2 = csr_src[jj + 4 + g];
    const int s3 = csr_src[jj + 6 + g];
    const float a0 = as2[s0], a1 = as2[s1], a2 = as2[s2], a3 = as2[s3];
    const float hv0 = h2[(size_t)s0 * OUT_DIM + l];
    const float hv1 = h2[(size_t)s1 * OUT_DIM + l];
    const float hv2 = h2[(size_t)s2 * OUT_DIM + l];
    const float hv3 = h2[(size_t)s3 * OUT_DIM + l];
    float e, w;
    e = a0 + adv; e = (e >= 0.f) ? e : NEG * e; w = __expf(e); den += w; acc += w * hv0;
    e = a1 + adv; e = (e >= 0.f) ? e : NEG * e; w = __expf(e); den += w; acc += w * hv1;
    e = a2 + adv; e = (e >= 0.f) ? e : NEG * e; w = __expf(e); den += w; acc += w * hv2;
    e = a3 + adv; e = (e >= 0.f) ? e : NEG * e; w = __expf(e); den += w; acc += w * hv3;
  }
  for (; jj < j1; jj += 2) {
    const int e_idx = jj + g;
    const bool valid = e_idx < j1;
    const int s = valid ? csr_src[e_idx] : 0;
    const float a = as2[s];
    const float hv = h2[(size_t)s * OUT_DIM + l];
    float e = a + adv; e = (e >= 0.f) ? e : NEG * e;
    float w = __expf(e);
    if (valid) { den += w; acc += w * hv; }
  }
  // combine the two half-waves (each lane pairs with lane^32, same feature l)
  den += __shfl_xor(den, 32, 64);
  acc += __shfl_xor(acc, 32, 64);
  float o = acc / den + b2[l];
  // log_softmax over 32 features (masks<32 keep half-waves independent & mirrored)
  float m = o;
#pragma unroll
  for (int mm = 16; mm >= 1; mm >>= 1) m = fmaxf(m, __shfl_xor(m, mm, 64));
  float ex = __expf(o - m);
  float ssum = ex;
#pragma unroll
  for (int mm = 16; mm >= 1; mm >>= 1) ssum += __shfl_xor(ssum, mm, 64);
  float ls = o - m - __logf(ssum);
  float sc = ls * linW[l];
#pragma unroll
  for (int mm = 16; mm >= 1; mm >>= 1) sc += __shfl_xor(sc, mm, 64);
  if (lane == 0) {
    int gidx = batch[node];
    atomicAdd(&gsum[gidx], sc);
    atomicAdd(&gcnt[gidx], 1.0f);
  }
}

__global__ void k_final(const float* __restrict__ gsum, const float* __restrict__ gcnt,
                        const float* __restrict__ linb, float* __restrict__ out, int g_) {
  int g = threadIdx.x;
  if (g < g_) out[g] = gsum[g] / fmaxf(gcnt[g], 1.0f) + linb[0];
}

extern "C" void kernel_launch(void* const* d_in, const int* in_sizes, int n_in,
                              void* d_out, int out_size, void* d_ws, size_t ws_size,
                              hipStream_t stream) {
  const float* x    = (const float*)d_in[0];
  const int*   adj  = (const int*)d_in[1];
  const int*   batch= (const int*)d_in[2];
  const float* W1   = (const float*)d_in[3];
  const float* a1s  = (const float*)d_in[4];
  const float* a1d  = (const float*)d_in[5];
  const float* b1   = (const float*)d_in[6];
  const float* W2   = (const float*)d_in[7];
  const float* a2s  = (const float*)d_in[8];
  const float* a2d  = (const float*)d_in[9];
  const float* b2   = (const float*)d_in[10];
  const float* linW = (const float*)d_in[11];
  const float* linb = (const float*)d_in[12];

  const int N = in_sizes[0] / IN_DIM;
  const int E = in_sizes[1] / 2;
  const int ET = E + N;
  const int G = out_size;   // 64
  const int NB = (N + 1023) / 1024;

  char* wsb = (char*)d_ws;
  size_t off = 0;
  auto take = [&](size_t bytes) -> char* {
    char* p = wsb + off;
    off += (bytes + 255) & ~(size_t)255;
    return p;
  };
  float* h1     = (float*)take((size_t)N * F1 * 4);
  float* relu1  = (float*)take((size_t)N * F1 * 4);
  float* as1    = (float*)take((size_t)N * 4 * 4);
  float* ad1    = (float*)take((size_t)N * 4 * 4);
  float* h2     = (float*)take((size_t)N * OUT_DIM * 4);
  float* as2v   = (float*)take((size_t)N * 4);
  float* ad2v   = (float*)take((size_t)N * 4);
  int*   cnt    = (int*)take((size_t)N * 4);
  int*   offs   = (int*)take((size_t)(N + 1) * 4);
  int*   cursor = (int*)take((size_t)N * 4);
  int*   csr_src= (int*)take((size_t)ET * 4);
  int*   bsum   = (int*)take((size_t)(NB + 1) * 4);
  float* gsum   = (float*)take((size_t)G * 4);
  float* gcnt   = (float*)take((size_t)G * 4);
  (void)ws_size; (void)n_in;

  hipMemsetAsync(cnt, 0, (size_t)N * 4, stream);
  hipMemsetAsync(gsum, 0, (size_t)G * 4, stream);
  hipMemsetAsync(gcnt, 0, (size_t)G * 4, stream);

  dim3 b256(256);
  k_gemm1<<<dim3((N + 63) / 64, F1 / 64), b256, 0, stream>>>(x, W1, h1, N);
  k_alphas1<<<dim3((N + 3) / 4), b256, 0, stream>>>(h1, a1s, a1d, as1, ad1, N);
  k_hist<<<dim3((ET + 255) / 256), b256, 0, stream>>>(adj, cnt, E, N);
  k_scan_local<<<dim3(NB), b256, 0, stream>>>(cnt, offs, bsum, N);
  k_scan_bsum<<<1, 64, 0, stream>>>(bsum, NB, offs + N);
  k_scan_add<<<dim3((N + 255) / 256), b256, 0, stream>>>(offs, bsum, cursor, N);
  k_scatter<<<dim3((ET + 255) / 256), b256, 0, stream>>>(adj, cursor, csr_src, E, N);
  k_agg1<<<dim3((N + 3) / 4), b256, 0, stream>>>(h1, as1, ad1, offs, csr_src, b1, relu1, N);
  k_gemm2<<<dim3((N + 63) / 64), b256, 0, stream>>>(relu1, W2, a2s, a2d, h2, as2v, ad2v, N);
  k_agg2<<<dim3((N + 3) / 4), b256, 0, stream>>>(h2, as2v, ad2v, offs, csr_src, b2, linW, batch, gsum, gcnt, N);
  k_final<<<1, 64, 0, stream>>>(gsum, gcnt, linb, (float*)d_out, G);
}

// Round 3
// 508.993 us; speedup vs baseline: 1.8253x; 1.7599x over previous
//
#include <hip/hip_runtime.h>

#define IN_DIM 128
#define F1 256      // HEADS*HID = 4*64
#define HID 64
#define OUT_DIM 32
#define NEG 0.2f

// ---------------- GEMM1: h1[N,256] = x[N,128] @ W1[128,256] ----------------
__global__ __launch_bounds__(256) void k_gemm1(const float* __restrict__ x,
    const float* __restrict__ W1, float* __restrict__ h1, int n) {
  __shared__ float xs[32][68];
  __shared__ float ws[32][64];
  const int tid = threadIdx.x;
  const int tx = tid & 15, ty = tid >> 4;
  const int rb = blockIdx.x * 64, cb = blockIdx.y * 64;
  float acc[4][4] = {{0.f}};
  for (int kb = 0; kb < IN_DIM; kb += 32) {
#pragma unroll
    for (int i = 0; i < 8; ++i) {
      int idx = tid + i * 256;
      int r = idx >> 5, c = idx & 31;
      int row = rb + r;
      xs[c][r] = (row < n) ? x[(size_t)row * IN_DIM + kb + c] : 0.f;
    }
#pragma unroll
    for (int i = 0; i < 8; ++i) {
      int idx = tid + i * 256;
      int kk = idx >> 6, cc = idx & 63;
      ws[kk][cc] = W1[(size_t)(kb + kk) * F1 + cb + cc];
    }
    __syncthreads();
#pragma unroll
    for (int kk = 0; kk < 32; ++kk) {
      const float4 a4 = *(const float4*)&xs[kk][ty * 4];
      const float4 b4 = *(const float4*)&ws[kk][tx * 4];
      const float av[4] = {a4.x, a4.y, a4.z, a4.w};
      const float bv[4] = {b4.x, b4.y, b4.z, b4.w};
#pragma unroll
      for (int i = 0; i < 4; ++i)
#pragma unroll
        for (int j = 0; j < 4; ++j)
          acc[i][j] += av[i] * bv[j];
    }
    __syncthreads();
  }
#pragma unroll
  for (int i = 0; i < 4; ++i) {
    int row = rb + ty * 4 + i;
    if (row < n) {
      float4 v = make_float4(acc[i][0], acc[i][1], acc[i][2], acc[i][3]);
      *(float4*)&h1[(size_t)row * F1 + cb + tx * 4] = v;
    }
  }
}

// ------------- alphas1 -------------
__global__ __launch_bounds__(256) void k_alphas1(const float* __restrict__ h1,
    const float* __restrict__ a_src, const float* __restrict__ a_dst,
    float* __restrict__ as1, float* __restrict__ ad1, int n) {
  int node = blockIdx.x * 4 + (threadIdx.x >> 6);
  int lane = threadIdx.x & 63;
  if (node >= n) return;
  const float* hrow = h1 + (size_t)node * F1;
  float s[4], d[4];
#pragma unroll
  for (int h = 0; h < 4; ++h) {
    float v = hrow[h * 64 + lane];
    s[h] = v * a_src[h * 64 + lane];
    d[h] = v * a_dst[h * 64 + lane];
  }
#pragma unroll
  for (int m = 32; m >= 1; m >>= 1) {
#pragma unroll
    for (int h = 0; h < 4; ++h) {
      s[h] += __shfl_xor(s[h], m, 64);
      d[h] += __shfl_xor(d[h], m, 64);
    }
  }
  if (lane == 0) {
#pragma unroll
    for (int h = 0; h < 4; ++h) {
      as1[(size_t)node * 4 + h] = s[h];
      ad1[(size_t)node * 4 + h] = d[h];
    }
  }
}

// ---------------- CSR build ----------------
__global__ __launch_bounds__(256) void k_hist(const int* __restrict__ adj,
    int* __restrict__ cnt, int E_, int n) {
  int e = blockIdx.x * 256 + threadIdx.x;
  int ET = E_ + n;
  if (e >= ET) return;
  int d = (e < E_) ? adj[E_ + e] : (e - E_);
  atomicAdd(&cnt[d], 1);
}

// parallel scan, phase A
__global__ __launch_bounds__(256) void k_scan_local(const int* __restrict__ cnt,
    int* __restrict__ offs, int* __restrict__ bsum, int n) {
  __shared__ int wsums[4];
  const int tid = threadIdx.x;
  const int lane = tid & 63, w = tid >> 6;
  const int base = blockIdx.x * 1024;
  const int i0 = base + tid * 4;
  int v[4];
#pragma unroll
  for (int k = 0; k < 4; ++k) { int i = i0 + k; v[k] = (i < n) ? cnt[i] : 0; }
  int tsum = v[0] + v[1] + v[2] + v[3];
  int incl = tsum;
#pragma unroll
  for (int d = 1; d < 64; d <<= 1) {
    int t = __shfl_up(incl, (unsigned)d, 64);
    if (lane >= d) incl += t;
  }
  if (lane == 63) wsums[w] = incl;
  __syncthreads();
  int pre = 0;
  for (int k = 0; k < w; ++k) pre += wsums[k];
  int run = pre + incl - tsum;
#pragma unroll
  for (int k = 0; k < 4; ++k) { int i = i0 + k; if (i < n) offs[i] = run; run += v[k]; }
  if (tid == 255) bsum[blockIdx.x] = pre + incl;
}

// phase B
__global__ void k_scan_bsum(int* __restrict__ bsum, int nb, int* __restrict__ offs_n) {
  int lane = threadIdx.x;   // 64 threads
  int carry = 0;
  for (int base = 0; base < nb; base += 64) {
    int i = base + lane;
    int v = (i < nb) ? bsum[i] : 0;
    int incl = v;
#pragma unroll
    for (int d = 1; d < 64; d <<= 1) {
      int t = __shfl_up(incl, (unsigned)d, 64);
      if (lane >= d) incl += t;
    }
    if (i < nb) bsum[i] = carry + incl - v;
    int tot = __shfl(incl, 63, 64);
    carry += tot;
  }
  if (lane == 0) *offs_n = carry;
}

// phase C
__global__ __launch_bounds__(256) void k_scan_add(int* __restrict__ offs,
    const int* __restrict__ bsum, int* __restrict__ cursor, int n) {
  int i = blockIdx.x * 256 + threadIdx.x;
  if (i < n) {
    int v = offs[i] + bsum[i >> 10];
    offs[i] = v;
    cursor[i] = v;
  }
}

__global__ __launch_bounds__(256) void k_scatter(const int* __restrict__ adj,
    int* __restrict__ cursor, int* __restrict__ csr_src, int E_, int n) {
  int e = blockIdx.x * 256 + threadIdx.x;
  int ET = E_ + n;
  if (e >= ET) return;
  int s, d;
  if (e < E_) { s = adj[e]; d = adj[E_ + e]; } else { s = d = e - E_; }
  int pos = atomicAdd(&cursor[d], 1);
  csr_src[pos] = s;
}

// ---------------- fused GAT layer 1: 4-edge chunked for MLP ----------------
__global__ __launch_bounds__(256) void k_agg1(const float* __restrict__ h1,
    const float* __restrict__ as1, const float* __restrict__ ad1,
    const int* __restrict__ offs, const int* __restrict__ csr_src,
    const float* __restrict__ b1, float* __restrict__ relu1, int n) {
  int node = blockIdx.x * 4 + (threadIdx.x >> 6);
  int lane = threadIdx.x & 63;
  if (node >= n) return;
  const int j0 = offs[node], j1 = offs[node + 1];
  const float4 ad = *(const float4*)(ad1 + (size_t)node * 4);
  float acc0 = 0.f, acc1 = 0.f, acc2 = 0.f, acc3 = 0.f;
  float den0 = 0.f, den1 = 0.f, den2 = 0.f, den3 = 0.f;
  int j = j0;
  for (; j + 4 <= j1; j += 4) {
    const int s0 = csr_src[j + 0], s1 = csr_src[j + 1];
    const int s2 = csr_src[j + 2], s3 = csr_src[j + 3];
    const float4 A0 = *(const float4*)(as1 + (size_t)s0 * 4);
    const float4 A1 = *(const float4*)(as1 + (size_t)s1 * 4);
    const float4 A2 = *(const float4*)(as1 + (size_t)s2 * 4);
    const float4 A3 = *(const float4*)(as1 + (size_t)s3 * 4);
    const float* p0 = h1 + (size_t)s0 * F1 + lane;
    const float* p1 = h1 + (size_t)s1 * F1 + lane;
    const float* p2 = h1 + (size_t)s2 * F1 + lane;
    const float* p3 = h1 + (size_t)s3 * F1 + lane;
    float v00 = p0[0], v01 = p0[64], v02 = p0[128], v03 = p0[192];
    float v10 = p1[0], v11 = p1[64], v12 = p1[128], v13 = p1[192];
    float v20 = p2[0], v21 = p2[64], v22 = p2[128], v23 = p2[192];
    float v30 = p3[0], v31 = p3[64], v32 = p3[128], v33 = p3[192];
    float e, w;
    e = A0.x + ad.x; e = (e >= 0.f) ? e : NEG * e; w = __expf(e); den0 += w; acc0 += w * v00;
    e = A0.y + ad.y; e = (e >= 0.f) ? e : NEG * e; w = __expf(e); den1 += w; acc1 += w * v01;
    e = A0.z + ad.z; e = (e >= 0.f) ? e : NEG * e; w = __expf(e); den2 += w; acc2 += w * v02;
    e = A0.w + ad.w; e = (e >= 0.f) ? e : NEG * e; w = __expf(e); den3 += w; acc3 += w * v03;
    e = A1.x + ad.x; e = (e >= 0.f) ? e : NEG * e; w = __expf(e); den0 += w; acc0 += w * v10;
    e = A1.y + ad.y; e = (e >= 0.f) ? e : NEG * e; w = __expf(e); den1 += w; acc1 += w * v11;
    e = A1.z + ad.z; e = (e >= 0.f) ? e : NEG * e; w = __expf(e); den2 += w; acc2 += w * v12;
    e = A1.w + ad.w; e = (e >= 0.f) ? e : NEG * e; w = __expf(e); den3 += w; acc3 += w * v13;
    e = A2.x + ad.x; e = (e >= 0.f) ? e : NEG * e; w = __expf(e); den0 += w; acc0 += w * v20;
    e = A2.y + ad.y; e = (e >= 0.f) ? e : NEG * e; w = __expf(e); den1 += w; acc1 += w * v21;
    e = A2.z + ad.z; e = (e >= 0.f) ? e : NEG * e; w = __expf(e); den2 += w; acc2 += w * v22;
    e = A2.w + ad.w; e = (e >= 0.f) ? e : NEG * e; w = __expf(e); den3 += w; acc3 += w * v23;
    e = A3.x + ad.x; e = (e >= 0.f) ? e : NEG * e; w = __expf(e); den0 += w; acc0 += w * v30;
    e = A3.y + ad.y; e = (e >= 0.f) ? e : NEG * e; w = __expf(e); den1 += w; acc1 += w * v31;
    e = A3.z + ad.z; e = (e >= 0.f) ? e : NEG * e; w = __expf(e); den2 += w; acc2 += w * v32;
    e = A3.w + ad.w; e = (e >= 0.f) ? e : NEG * e; w = __expf(e); den3 += w; acc3 += w * v33;
  }
  for (; j < j1; ++j) {
    const int src = csr_src[j];
    const float* hs = h1 + (size_t)src * F1;
    const float4 as = *(const float4*)(as1 + (size_t)src * 4);
    float e0 = as.x + ad.x; e0 = (e0 >= 0.f) ? e0 : NEG * e0; float w0 = __expf(e0);
    float e1 = as.y + ad.y; e1 = (e1 >= 0.f) ? e1 : NEG * e1; float w1 = __expf(e1);
    float e2 = as.z + ad.z; e2 = (e2 >= 0.f) ? e2 : NEG * e2; float w2 = __expf(e2);
    float e3 = as.w + ad.w; e3 = (e3 >= 0.f) ? e3 : NEG * e3; float w3 = __expf(e3);
    den0 += w0; den1 += w1; den2 += w2; den3 += w3;
    acc0 += w0 * hs[lane];
    acc1 += w1 * hs[64 + lane];
    acc2 += w2 * hs[128 + lane];
    acc3 += w3 * hs[192 + lane];
  }
  float r0 = acc0 / den0 + b1[lane];        r0 = fmaxf(r0, 0.f);
  float r1 = acc1 / den1 + b1[64 + lane];   r1 = fmaxf(r1, 0.f);
  float r2 = acc2 / den2 + b1[128 + lane];  r2 = fmaxf(r2, 0.f);
  float r3 = acc3 / den3 + b1[192 + lane];  r3 = fmaxf(r3, 0.f);
  size_t base = (size_t)node * F1;
  relu1[base + lane] = r0;
  relu1[base + 64 + lane] = r1;
  relu1[base + 128 + lane] = r2;
  relu1[base + 192 + lane] = r3;
}

// ---------------- GEMM2 + fused alpha2 dots ----------------
__global__ __launch_bounds__(256) void k_gemm2(const float* __restrict__ relu1,
    const float* __restrict__ W2, const float* __restrict__ a2s_w,
    const float* __restrict__ a2d_w, float* __restrict__ h2,
    float* __restrict__ as2, float* __restrict__ ad2, int n) {
  __shared__ float w2s[F1 * OUT_DIM];
  __shared__ float xs[64][33];
  const int tid = threadIdx.x;
  const int tx = tid & 31, ty = tid >> 5;
  const int rb = blockIdx.x * 64;
  for (int i = tid; i < F1 * OUT_DIM; i += 256) w2s[i] = W2[i];
  float acc[8] = {0.f, 0.f, 0.f, 0.f, 0.f, 0.f, 0.f, 0.f};
  for (int kb = 0; kb < F1; kb += 32) {
#pragma unroll
    for (int i = 0; i < 8; ++i) {
      int idx = tid + i * 256;
      int r = idx >> 5, c = idx & 31;
      int row = rb + r;
      xs[r][c] = (row < n) ? relu1[(size_t)row * F1 + kb + c] : 0.f;
    }
    __syncthreads();
#pragma unroll
    for (int kk = 0; kk < 32; ++kk) {
      float b = w2s[(kb + kk) * OUT_DIM + tx];
#pragma unroll
      for (int i = 0; i < 8; ++i)
        acc[i] += xs[ty + i * 8][kk] * b;
    }
    __syncthreads();
  }
#pragma unroll
  for (int i = 0; i < 8; ++i) {
    int row = rb + ty + i * 8;
    float v = acc[i];
    if (row < n) h2[(size_t)row * OUT_DIM + tx] = v;
    float ssrc = v * a2s_w[tx];
    float sdst = v * a2d_w[tx];
#pragma unroll
    for (int m = 16; m >= 1; m >>= 1) {
      ssrc += __shfl_xor(ssrc, m, 64);
      sdst += __shfl_xor(sdst, m, 64);
    }
    if (tx == 0 && row < n) { as2[row] = ssrc; ad2[row] = sdst; }
  }
}

// -------- fused GAT layer 2: aggregate + log_softmax + lin_W dot → score[node] --------
// NO global atomics here (they were the round-1/2 bottleneck: 100K fp32 atomics
// onto 64 sorted addresses → same-line convoy). Pooling moved to k_pool.
__global__ __launch_bounds__(256) void k_agg2(const float* __restrict__ h2,
    const float* __restrict__ as2, const float* __restrict__ ad2,
    const int* __restrict__ offs, const int* __restrict__ csr_src,
    const float* __restrict__ b2, const float* __restrict__ linW,
    float* __restrict__ score, int n) {
  int node = blockIdx.x * 4 + (threadIdx.x >> 6);
  int lane = threadIdx.x & 63;
  if (node >= n) return;
  const int j0 = offs[node], j1 = offs[node + 1];
  const float adv = ad2[node];
  const int g = lane >> 5;       // which half-wave → which edge of the pair
  const int l = lane & 31;       // feature
  float acc = 0.f, den = 0.f;
  int jj = j0;
  for (; jj + 8 <= j1; jj += 8) {
    const int s0 = csr_src[jj + 0 + g];
    const int s1 = csr_src[jj + 2 + g];
    const int s2 = csr_src[jj + 4 + g];
    const int s3 = csr_src[jj + 6 + g];
    const float a0 = as2[s0], a1 = as2[s1], a2 = as2[s2], a3 = as2[s3];
    const float hv0 = h2[(size_t)s0 * OUT_DIM + l];
    const float hv1 = h2[(size_t)s1 * OUT_DIM + l];
    const float hv2 = h2[(size_t)s2 * OUT_DIM + l];
    const float hv3 = h2[(size_t)s3 * OUT_DIM + l];
    float e, w;
    e = a0 + adv; e = (e >= 0.f) ? e : NEG * e; w = __expf(e); den += w; acc += w * hv0;
    e = a1 + adv; e = (e >= 0.f) ? e : NEG * e; w = __expf(e); den += w; acc += w * hv1;
    e = a2 + adv; e = (e >= 0.f) ? e : NEG * e; w = __expf(e); den += w; acc += w * hv2;
    e = a3 + adv; e = (e >= 0.f) ? e : NEG * e; w = __expf(e); den += w; acc += w * hv3;
  }
  for (; jj < j1; jj += 2) {
    const int e_idx = jj + g;
    const bool valid = e_idx < j1;
    const int s = valid ? csr_src[e_idx] : 0;
    const float a = as2[s];
    const float hv = h2[(size_t)s * OUT_DIM + l];
    float e = a + adv; e = (e >= 0.f) ? e : NEG * e;
    float w = __expf(e);
    if (valid) { den += w; acc += w * hv; }
  }
  den += __shfl_xor(den, 32, 64);
  acc += __shfl_xor(acc, 32, 64);
  float o = acc / den + b2[l];
  float m = o;
#pragma unroll
  for (int mm = 16; mm >= 1; mm >>= 1) m = fmaxf(m, __shfl_xor(m, mm, 64));
  float ex = __expf(o - m);
  float ssum = ex;
#pragma unroll
  for (int mm = 16; mm >= 1; mm >>= 1) ssum += __shfl_xor(ssum, mm, 64);
  float ls = o - m - __logf(ssum);
  float sc = ls * linW[l];
#pragma unroll
  for (int mm = 16; mm >= 1; mm >>= 1) sc += __shfl_xor(sc, mm, 64);
  if (lane == 0) score[node] = sc;
}

// -------- pooling: LDS per-graph partials, ~1-3 global atomics per block --------
__global__ __launch_bounds__(256) void k_pool(const float* __restrict__ score,
    const int* __restrict__ batch, float* __restrict__ gsum,
    float* __restrict__ gcnt, int n) {
  __shared__ float ps[64];
  __shared__ float pc[64];
  const int tid = threadIdx.x;
  if (tid < 64) { ps[tid] = 0.f; pc[tid] = 0.f; }
  __syncthreads();
  int i = blockIdx.x * 256 + tid;
  if (i < n) {
    int g = batch[i];
    atomicAdd(&ps[g], score[i]);   // LDS atomic — cheap, block-local
    atomicAdd(&pc[g], 1.0f);
  }
  __syncthreads();
  if (tid < 64 && pc[tid] != 0.f) {
    atomicAdd(&gsum[tid], ps[tid]);
    atomicAdd(&gcnt[tid], pc[tid]);
  }
}

__global__ void k_final(const float* __restrict__ gsum, const float* __restrict__ gcnt,
                        const float* __restrict__ linb, float* __restrict__ out, int g_) {
  int g = threadIdx.x;
  if (g < g_) out[g] = gsum[g] / fmaxf(gcnt[g], 1.0f) + linb[0];
}

extern "C" void kernel_launch(void* const* d_in, const int* in_sizes, int n_in,
                              void* d_out, int out_size, void* d_ws, size_t ws_size,
                              hipStream_t stream) {
  const float* x    = (const float*)d_in[0];
  const int*   adj  = (const int*)d_in[1];
  const int*   batch= (const int*)d_in[2];
  const float* W1   = (const float*)d_in[3];
  const float* a1s  = (const float*)d_in[4];
  const float* a1d  = (const float*)d_in[5];
  const float* b1   = (const float*)d_in[6];
  const float* W2   = (const float*)d_in[7];
  const float* a2s  = (const float*)d_in[8];
  const float* a2d  = (const float*)d_in[9];
  const float* b2   = (const float*)d_in[10];
  const float* linW = (const float*)d_in[11];
  const float* linb = (const float*)d_in[12];

  const int N = in_sizes[0] / IN_DIM;
  const int E = in_sizes[1] / 2;
  const int ET = E + N;
  const int G = out_size;   // 64
  const int NB = (N + 1023) / 1024;

  char* wsb = (char*)d_ws;
  size_t off = 0;
  auto take = [&](size_t bytes) -> char* {
    char* p = wsb + off;
    off += (bytes + 255) & ~(size_t)255;
    return p;
  };
  float* h1     = (float*)take((size_t)N * F1 * 4);
  float* relu1  = (float*)take((size_t)N * F1 * 4);
  float* as1    = (float*)take((size_t)N * 4 * 4);
  float* ad1    = (float*)take((size_t)N * 4 * 4);
  float* h2     = (float*)take((size_t)N * OUT_DIM * 4);
  float* as2v   = (float*)take((size_t)N * 4);
  float* ad2v   = (float*)take((size_t)N * 4);
  float* score  = (float*)take((size_t)N * 4);
  int*   cnt    = (int*)take((size_t)N * 4);
  int*   offs   = (int*)take((size_t)(N + 1) * 4);
  int*   cursor = (int*)take((size_t)N * 4);
  int*   csr_src= (int*)take((size_t)ET * 4);
  int*   bsum   = (int*)take((size_t)(NB + 1) * 4);
  float* gsum   = (float*)take((size_t)G * 4);
  float* gcnt   = (float*)take((size_t)G * 4);
  (void)ws_size; (void)n_in;

  hipMemsetAsync(cnt, 0, (size_t)N * 4, stream);
  hipMemsetAsync(gsum, 0, (size_t)G * 4, stream);
  hipMemsetAsync(gcnt, 0, (size_t)G * 4, stream);

  dim3 b256(256);
  k_gemm1<<<dim3((N + 63) / 64, F1 / 64), b256, 0, stream>>>(x, W1, h1, N);
  k_alphas1<<<dim3((N + 3) / 4), b256, 0, stream>>>(h1, a1s, a1d, as1, ad1, N);
  k_hist<<<dim3((ET + 255) / 256), b256, 0, stream>>>(adj, cnt, E, N);
  k_scan_local<<<dim3(NB), b256, 0, stream>>>(cnt, offs, bsum, N);
  k_scan_bsum<<<1, 64, 0, stream>>>(bsum, NB, offs + N);
  k_scan_add<<<dim3((N + 255) / 256), b256, 0, stream>>>(offs, bsum, cursor, N);
  k_scatter<<<dim3((ET + 255) / 256), b256, 0, stream>>>(adj, cursor, csr_src, E, N);
  k_agg1<<<dim3((N + 3) / 4), b256, 0, stream>>>(h1, as1, ad1, offs, csr_src, b1, relu1, N);
  k_gemm2<<<dim3((N + 63) / 64), b256, 0, stream>>>(relu1, W2, a2s, a2d, h2, as2v, ad2v, N);
  k_agg2<<<dim3((N + 3) / 4), b256, 0, stream>>>(h2, as2v, ad2v, offs, csr_src, b2, linW, score, N);
  k_pool<<<dim3((N + 255) / 256), b256, 0, stream>>>(score, batch, gsum, gcnt, N);
  k_final<<<1, 64, 0, stream>>>(gsum, gcnt, linb, (float*)d_out, G);
}

// Round 4
// 416.300 us; speedup vs baseline: 2.2317x; 1.2227x over previous
//
#include <hip/hip_runtime.h>

#define IN_DIM 128
#define F1 256      // HEADS*HID = 4*64
#define HID 64
#define OUT_DIM 32
#define NEG 0.2f

// ---- bf16 helpers (storage format for gathered feature tables) ----
__device__ __forceinline__ float b2fl(unsigned u) {
  union { unsigned i; float f; } c; c.i = u << 16; return c.f;
}
__device__ __forceinline__ float b2fh(unsigned u) {
  union { unsigned i; float f; } c; c.i = u & 0xffff0000u; return c.f;
}
__device__ __forceinline__ unsigned short f2b(float f) {
  union { float f; unsigned i; } c; c.f = f;
  unsigned r = c.i + 0x7fffu + ((c.i >> 16) & 1u);   // RNE
  return (unsigned short)(r >> 16);
}

// ---------------- GEMM1: h1b[N,256](bf16) = x[N,128] @ W1[128,256] ----------------
__global__ __launch_bounds__(256) void k_gemm1(const float* __restrict__ x,
    const float* __restrict__ W1, unsigned short* __restrict__ h1b, int n) {
  __shared__ float xs[32][68];
  __shared__ float ws[32][64];
  const int tid = threadIdx.x;
  const int tx = tid & 15, ty = tid >> 4;
  const int rb = blockIdx.x * 64, cb = blockIdx.y * 64;
  float acc[4][4] = {{0.f}};
  for (int kb = 0; kb < IN_DIM; kb += 32) {
#pragma unroll
    for (int i = 0; i < 8; ++i) {
      int idx = tid + i * 256;
      int r = idx >> 5, c = idx & 31;
      int row = rb + r;
      xs[c][r] = (row < n) ? x[(size_t)row * IN_DIM + kb + c] : 0.f;
    }
#pragma unroll
    for (int i = 0; i < 8; ++i) {
      int idx = tid + i * 256;
      int kk = idx >> 6, cc = idx & 63;
      ws[kk][cc] = W1[(size_t)(kb + kk) * F1 + cb + cc];
    }
    __syncthreads();
#pragma unroll
    for (int kk = 0; kk < 32; ++kk) {
      const float4 a4 = *(const float4*)&xs[kk][ty * 4];
      const float4 b4 = *(const float4*)&ws[kk][tx * 4];
      const float av[4] = {a4.x, a4.y, a4.z, a4.w};
      const float bv[4] = {b4.x, b4.y, b4.z, b4.w};
#pragma unroll
      for (int i = 0; i < 4; ++i)
#pragma unroll
        for (int j = 0; j < 4; ++j)
          acc[i][j] += av[i] * bv[j];
    }
    __syncthreads();
  }
#pragma unroll
  for (int i = 0; i < 4; ++i) {
    int row = rb + ty * 4 + i;
    if (row < n) {
      ushort4 v;
      v.x = f2b(acc[i][0]); v.y = f2b(acc[i][1]);
      v.z = f2b(acc[i][2]); v.w = f2b(acc[i][3]);
      *(ushort4*)&h1b[(size_t)row * F1 + cb + tx * 4] = v;
    }
  }
}

// ------------- alphas1 from bf16 h1: lane l -> head l>>4, feats 4(l&15)..+3 -------------
__global__ __launch_bounds__(256) void k_alphas1(const unsigned short* __restrict__ h1b,
    const float* __restrict__ a_src, const float* __restrict__ a_dst,
    float* __restrict__ as1, float* __restrict__ ad1, int n) {
  int node = blockIdx.x * 4 + (threadIdx.x >> 6);
  int lane = threadIdx.x & 63;
  if (node >= n) return;
  const int h = lane >> 4;
  const int p = lane & 15;
  uint2 u = ((const uint2*)(h1b + (size_t)node * F1))[lane];
  float f0 = b2fl(u.x), f1 = b2fh(u.x), f2 = b2fl(u.y), f3 = b2fh(u.y);
  const float4 av = ((const float4*)(a_src + h * 64))[p];
  const float4 dv = ((const float4*)(a_dst + h * 64))[p];
  float s = f0 * av.x + f1 * av.y + f2 * av.z + f3 * av.w;
  float d = f0 * dv.x + f1 * dv.y + f2 * dv.z + f3 * dv.w;
#pragma unroll
  for (int m = 1; m <= 8; m <<= 1) {
    s += __shfl_xor(s, m, 64);
    d += __shfl_xor(d, m, 64);
  }
  if (p == 0) {
    as1[(size_t)node * 4 + h] = s;
    ad1[(size_t)node * 4 + h] = d;
  }
}

// ---------------- CSR build ----------------
__global__ __launch_bounds__(256) void k_hist(const int* __restrict__ adj,
    int* __restrict__ cnt, int E_, int n) {
  int e = blockIdx.x * 256 + threadIdx.x;
  int ET = E_ + n;
  if (e >= ET) return;
  int d = (e < E_) ? adj[E_ + e] : (e - E_);
  atomicAdd(&cnt[d], 1);
}

__global__ __launch_bounds__(256) void k_scan_local(const int* __restrict__ cnt,
    int* __restrict__ offs, int* __restrict__ bsum, int n) {
  __shared__ int wsums[4];
  const int tid = threadIdx.x;
  const int lane = tid & 63, w = tid >> 6;
  const int base = blockIdx.x * 1024;
  const int i0 = base + tid * 4;
  int v[4];
#pragma unroll
  for (int k = 0; k < 4; ++k) { int i = i0 + k; v[k] = (i < n) ? cnt[i] : 0; }
  int tsum = v[0] + v[1] + v[2] + v[3];
  int incl = tsum;
#pragma unroll
  for (int d = 1; d < 64; d <<= 1) {
    int t = __shfl_up(incl, (unsigned)d, 64);
    if (lane >= d) incl += t;
  }
  if (lane == 63) wsums[w] = incl;
  __syncthreads();
  int pre = 0;
  for (int k = 0; k < w; ++k) pre += wsums[k];
  int run = pre + incl - tsum;
#pragma unroll
  for (int k = 0; k < 4; ++k) { int i = i0 + k; if (i < n) offs[i] = run; run += v[k]; }
  if (tid == 255) bsum[blockIdx.x] = pre + incl;
}

__global__ void k_scan_bsum(int* __restrict__ bsum, int nb, int* __restrict__ offs_n) {
  int lane = threadIdx.x;   // 64 threads
  int carry = 0;
  for (int base = 0; base < nb; base += 64) {
    int i = base + lane;
    int v = (i < nb) ? bsum[i] : 0;
    int incl = v;
#pragma unroll
    for (int d = 1; d < 64; d <<= 1) {
      int t = __shfl_up(incl, (unsigned)d, 64);
      if (lane >= d) incl += t;
    }
    if (i < nb) bsum[i] = carry + incl - v;
    int tot = __shfl(incl, 63, 64);
    carry += tot;
  }
  if (lane == 0) *offs_n = carry;
}

__global__ __launch_bounds__(256) void k_scan_add(int* __restrict__ offs,
    const int* __restrict__ bsum, int* __restrict__ cursor, int n) {
  int i = blockIdx.x * 256 + threadIdx.x;
  if (i < n) {
    int v = offs[i] + bsum[i >> 10];
    offs[i] = v;
    cursor[i] = v;
  }
}

__global__ __launch_bounds__(256) void k_scatter(const int* __restrict__ adj,
    int* __restrict__ cursor, int* __restrict__ csr_src, int E_, int n) {
  int e = blockIdx.x * 256 + threadIdx.x;
  int ET = E_ + n;
  if (e >= ET) return;
  int s, d;
  if (e < E_) { s = adj[e]; d = adj[E_ + e]; } else { s = d = e - E_; }
  int pos = atomicAdd(&cursor[d], 1);
  csr_src[pos] = s;
}

// ---------------- fused GAT layer 1 (bf16 gather, head-split lanes) ----------------
// lane l: head h=l>>4, features 4(l&15)..+3. One uint2 load = whole 512B row per wave.
// 1 exp per lane per edge (was 4). 4-edge chunk for MLP.
__global__ __launch_bounds__(256) void k_agg1(const unsigned short* __restrict__ h1b,
    const float* __restrict__ as1, const float* __restrict__ ad1,
    const int* __restrict__ offs, const int* __restrict__ csr_src,
    const float* __restrict__ b1, float* __restrict__ relu1, int n) {
  int node = blockIdx.x * 4 + (threadIdx.x >> 6);
  int lane = threadIdx.x & 63;
  if (node >= n) return;
  const int h = lane >> 4;
  const int j0 = offs[node], j1 = offs[node + 1];
  const float adv = ad1[(size_t)node * 4 + h];
  float a0 = 0.f, a1 = 0.f, a2 = 0.f, a3 = 0.f, den = 0.f;
  int j = j0;
  for (; j + 4 <= j1; j += 4) {
    const int s0 = csr_src[j + 0], s1 = csr_src[j + 1];
    const int s2 = csr_src[j + 2], s3 = csr_src[j + 3];
    const float q0 = as1[(size_t)s0 * 4 + h];
    const float q1 = as1[(size_t)s1 * 4 + h];
    const float q2 = as1[(size_t)s2 * 4 + h];
    const float q3 = as1[(size_t)s3 * 4 + h];
    const uint2 u0 = ((const uint2*)(h1b + (size_t)s0 * F1))[lane];
    const uint2 u1 = ((const uint2*)(h1b + (size_t)s1 * F1))[lane];
    const uint2 u2 = ((const uint2*)(h1b + (size_t)s2 * F1))[lane];
    const uint2 u3 = ((const uint2*)(h1b + (size_t)s3 * F1))[lane];
    float e, w;
    e = q0 + adv; e = (e >= 0.f) ? e : NEG * e; w = __expf(e);
    den += w; a0 += w * b2fl(u0.x); a1 += w * b2fh(u0.x); a2 += w * b2fl(u0.y); a3 += w * b2fh(u0.y);
    e = q1 + adv; e = (e >= 0.f) ? e : NEG * e; w = __expf(e);
    den += w; a0 += w * b2fl(u1.x); a1 += w * b2fh(u1.x); a2 += w * b2fl(u1.y); a3 += w * b2fh(u1.y);
    e = q2 + adv; e = (e >= 0.f) ? e : NEG * e; w = __expf(e);
    den += w; a0 += w * b2fl(u2.x); a1 += w * b2fh(u2.x); a2 += w * b2fl(u2.y); a3 += w * b2fh(u2.y);
    e = q3 + adv; e = (e >= 0.f) ? e : NEG * e; w = __expf(e);
    den += w; a0 += w * b2fl(u3.x); a1 += w * b2fh(u3.x); a2 += w * b2fl(u3.y); a3 += w * b2fh(u3.y);
  }
  for (; j < j1; ++j) {
    const int s = csr_src[j];
    const float q = as1[(size_t)s * 4 + h];
    const uint2 u = ((const uint2*)(h1b + (size_t)s * F1))[lane];
    float e = q + adv; e = (e >= 0.f) ? e : NEG * e;
    float w = __expf(e);
    den += w; a0 += w * b2fl(u.x); a1 += w * b2fh(u.x); a2 += w * b2fl(u.y); a3 += w * b2fh(u.y);
  }
  const float inv = 1.0f / den;
  const float4 bb = ((const float4*)b1)[lane];
  float r0 = fmaxf(a0 * inv + bb.x, 0.f);
  float r1 = fmaxf(a1 * inv + bb.y, 0.f);
  float r2 = fmaxf(a2 * inv + bb.z, 0.f);
  float r3 = fmaxf(a3 * inv + bb.w, 0.f);
  ((float4*)(relu1 + (size_t)node * F1))[lane] = make_float4(r0, r1, r2, r3);
}

// ---------------- GEMM2 + fused alpha2 dots; h2 stored bf16 ----------------
__global__ __launch_bounds__(256) void k_gemm2(const float* __restrict__ relu1,
    const float* __restrict__ W2, const float* __restrict__ a2s_w,
    const float* __restrict__ a2d_w, unsigned short* __restrict__ h2b,
    float* __restrict__ as2, float* __restrict__ ad2, int n) {
  __shared__ float w2s[F1 * OUT_DIM];
  __shared__ float xs[64][33];
  const int tid = threadIdx.x;
  const int tx = tid & 31, ty = tid >> 5;
  const int rb = blockIdx.x * 64;
  for (int i = tid; i < F1 * OUT_DIM; i += 256) w2s[i] = W2[i];
  float acc[8] = {0.f, 0.f, 0.f, 0.f, 0.f, 0.f, 0.f, 0.f};
  for (int kb = 0; kb < F1; kb += 32) {
#pragma unroll
    for (int i = 0; i < 8; ++i) {
      int idx = tid + i * 256;
      int r = idx >> 5, c = idx & 31;
      int row = rb + r;
      xs[r][c] = (row < n) ? relu1[(size_t)row * F1 + kb + c] : 0.f;
    }
    __syncthreads();
#pragma unroll
    for (int kk = 0; kk < 32; ++kk) {
      float b = w2s[(kb + kk) * OUT_DIM + tx];
#pragma unroll
      for (int i = 0; i < 8; ++i)
        acc[i] += xs[ty + i * 8][kk] * b;
    }
    __syncthreads();
  }
#pragma unroll
  for (int i = 0; i < 8; ++i) {
    int row = rb + ty + i * 8;
    float v = acc[i];
    if (row < n) h2b[(size_t)row * OUT_DIM + tx] = f2b(v);
    float ssrc = v * a2s_w[tx];
    float sdst = v * a2d_w[tx];
#pragma unroll
    for (int m = 16; m >= 1; m >>= 1) {
      ssrc += __shfl_xor(ssrc, m, 64);
      sdst += __shfl_xor(sdst, m, 64);
    }
    if (tx == 0 && row < n) { as2[row] = ssrc; ad2[row] = sdst; }
  }
}

// -------- fused GAT layer 2 (bf16 gather, quarter-wave per edge) --------
// lane l: edge slot sub=l>>4, feature pair p=l&15 (feats 2p,2p+1).
// 4 edges per step, 8 in flight with 2-step unroll. No global atomics.
__global__ __launch_bounds__(256) void k_agg2(const unsigned short* __restrict__ h2b,
    const float* __restrict__ as2, const float* __restrict__ ad2,
    const int* __restrict__ offs, const int* __restrict__ csr_src,
    const float* __restrict__ b2, const float* __restrict__ linW,
    float* __restrict__ score, int n) {
  int node = blockIdx.x * 4 + (threadIdx.x >> 6);
  int lane = threadIdx.x & 63;
  if (node >= n) return;
  const int sub = lane >> 4;
  const int p = lane & 15;
  const int j0 = offs[node], j1 = offs[node + 1];
  const float adv = ad2[node];
  float acc0 = 0.f, acc1 = 0.f, den = 0.f;
  int jj = j0;
  for (; jj + 8 <= j1; jj += 8) {
    const int sA = csr_src[jj + sub];
    const int sB = csr_src[jj + 4 + sub];
    const float aA = as2[sA], aB = as2[sB];
    const unsigned uA = ((const unsigned*)(h2b + (size_t)sA * OUT_DIM))[p];
    const unsigned uB = ((const unsigned*)(h2b + (size_t)sB * OUT_DIM))[p];
    float e, w;
    e = aA + adv; e = (e >= 0.f) ? e : NEG * e; w = __expf(e);
    den += w; acc0 += w * b2fl(uA); acc1 += w * b2fh(uA);
    e = aB + adv; e = (e >= 0.f) ? e : NEG * e; w = __expf(e);
    den += w; acc0 += w * b2fl(uB); acc1 += w * b2fh(uB);
  }
  for (; jj < j1; jj += 4) {
    const int idx = jj + sub;
    const bool valid = idx < j1;
    const int s = valid ? csr_src[idx] : csr_src[j1 - 1];
    const float a = as2[s];
    const unsigned u = ((const unsigned*)(h2b + (size_t)s * OUT_DIM))[p];
    float e = a + adv; e = (e >= 0.f) ? e : NEG * e;
    float w = valid ? __expf(e) : 0.f;
    den += w; acc0 += w * b2fl(u); acc1 += w * b2fh(u);
  }
  // combine 4 quarter-waves (same p across subs)
  den  += __shfl_xor(den, 16, 64);  den  += __shfl_xor(den, 32, 64);
  acc0 += __shfl_xor(acc0, 16, 64); acc0 += __shfl_xor(acc0, 32, 64);
  acc1 += __shfl_xor(acc1, 16, 64); acc1 += __shfl_xor(acc1, 32, 64);
  const float inv = 1.0f / den;
  float o0 = acc0 * inv + b2[2 * p];
  float o1 = acc1 * inv + b2[2 * p + 1];
  // log_softmax over 32 features (2 per lane, reduce over p within 16-lane groups)
  float m = fmaxf(o0, o1);
#pragma unroll
  for (int mm = 1; mm <= 8; mm <<= 1) m = fmaxf(m, __shfl_xor(m, mm, 64));
  float ssum = __expf(o0 - m) + __expf(o1 - m);
#pragma unroll
  for (int mm = 1; mm <= 8; mm <<= 1) ssum += __shfl_xor(ssum, mm, 64);
  const float lse = m + __logf(ssum);
  float sc = (o0 - lse) * linW[2 * p] + (o1 - lse) * linW[2 * p + 1];
#pragma unroll
  for (int mm = 1; mm <= 8; mm <<= 1) sc += __shfl_xor(sc, mm, 64);
  if (lane == 0) score[node] = sc;
}

// -------- pooling: LDS per-graph partials, few global atomics per block --------
__global__ __launch_bounds__(256) void k_pool(const float* __restrict__ score,
    const int* __restrict__ batch, float* __restrict__ gsum,
    float* __restrict__ gcnt, int n) {
  __shared__ float ps[64];
  __shared__ float pc[64];
  const int tid = threadIdx.x;
  if (tid < 64) { ps[tid] = 0.f; pc[tid] = 0.f; }
  __syncthreads();
  int i = blockIdx.x * 256 + tid;
  if (i < n) {
    int g = batch[i];
    atomicAdd(&ps[g], score[i]);
    atomicAdd(&pc[g], 1.0f);
  }
  __syncthreads();
  if (tid < 64 && pc[tid] != 0.f) {
    atomicAdd(&gsum[tid], ps[tid]);
    atomicAdd(&gcnt[tid], pc[tid]);
  }
}

__global__ void k_final(const float* __restrict__ gsum, const float* __restrict__ gcnt,
                        const float* __restrict__ linb, float* __restrict__ out, int g_) {
  int g = threadIdx.x;
  if (g < g_) out[g] = gsum[g] / fmaxf(gcnt[g], 1.0f) + linb[0];
}

extern "C" void kernel_launch(void* const* d_in, const int* in_sizes, int n_in,
                              void* d_out, int out_size, void* d_ws, size_t ws_size,
                              hipStream_t stream) {
  const float* x    = (const float*)d_in[0];
  const int*   adj  = (const int*)d_in[1];
  const int*   batch= (const int*)d_in[2];
  const float* W1   = (const float*)d_in[3];
  const float* a1s  = (const float*)d_in[4];
  const float* a1d  = (const float*)d_in[5];
  const float* b1   = (const float*)d_in[6];
  const float* W2   = (const float*)d_in[7];
  const float* a2s  = (const float*)d_in[8];
  const float* a2d  = (const float*)d_in[9];
  const float* b2   = (const float*)d_in[10];
  const float* linW = (const float*)d_in[11];
  const float* linb = (const float*)d_in[12];

  const int N = in_sizes[0] / IN_DIM;
  const int E = in_sizes[1] / 2;
  const int ET = E + N;
  const int G = out_size;   // 64
  const int NB = (N + 1023) / 1024;

  char* wsb = (char*)d_ws;
  size_t off = 0;
  auto take = [&](size_t bytes) -> char* {
    char* p = wsb + off;
    off += (bytes + 255) & ~(size_t)255;
    return p;
  };
  unsigned short* h1b = (unsigned short*)take((size_t)N * F1 * 2);
  float* relu1  = (float*)take((size_t)N * F1 * 4);
  float* as1    = (float*)take((size_t)N * 4 * 4);
  float* ad1    = (float*)take((size_t)N * 4 * 4);
  unsigned short* h2b = (unsigned short*)take((size_t)N * OUT_DIM * 2);
  float* as2v   = (float*)take((size_t)N * 4);
  float* ad2v   = (float*)take((size_t)N * 4);
  float* score  = (float*)take((size_t)N * 4);
  int*   cnt    = (int*)take((size_t)N * 4);
  int*   offs   = (int*)take((size_t)(N + 1) * 4);
  int*   cursor = (int*)take((size_t)N * 4);
  int*   csr_src= (int*)take((size_t)ET * 4);
  int*   bsum   = (int*)take((size_t)(NB + 1) * 4);
  float* gsum   = (float*)take((size_t)G * 4);
  float* gcnt   = (float*)take((size_t)G * 4);
  (void)ws_size; (void)n_in;

  hipMemsetAsync(cnt, 0, (size_t)N * 4, stream);
  hipMemsetAsync(gsum, 0, (size_t)G * 4, stream);
  hipMemsetAsync(gcnt, 0, (size_t)G * 4, stream);

  dim3 b256(256);
  k_gemm1<<<dim3((N + 63) / 64, F1 / 64), b256, 0, stream>>>(x, W1, h1b, N);
  k_alphas1<<<dim3((N + 3) / 4), b256, 0, stream>>>(h1b, a1s, a1d, as1, ad1, N);
  k_hist<<<dim3((ET + 255) / 256), b256, 0, stream>>>(adj, cnt, E, N);
  k_scan_local<<<dim3(NB), b256, 0, stream>>>(cnt, offs, bsum, N);
  k_scan_bsum<<<1, 64, 0, stream>>>(bsum, NB, offs + N);
  k_scan_add<<<dim3((N + 255) / 256), b256, 0, stream>>>(offs, bsum, cursor, N);
  k_scatter<<<dim3((ET + 255) / 256), b256, 0, stream>>>(adj, cursor, csr_src, E, N);
  k_agg1<<<dim3((N + 3) / 4), b256, 0, stream>>>(h1b, as1, ad1, offs, csr_src, b1, relu1, N);
  k_gemm2<<<dim3((N + 63) / 64), b256, 0, stream>>>(relu1, W2, a2s, a2d, h2b, as2v, ad2v, N);
  k_agg2<<<dim3((N + 3) / 4), b256, 0, stream>>>(h2b, as2v, ad2v, offs, csr_src, b2, linW, score, N);
  k_pool<<<dim3((N + 255) / 256), b256, 0, stream>>>(score, batch, gsum, gcnt, N);
  k_final<<<1, 64, 0, stream>>>(gsum, gcnt, linb, (float*)d_out, G);
}

// Round 5
// 397.334 us; speedup vs baseline: 2.3382x; 1.0477x over previous
//
#include <hip/hip_runtime.h>

#define IN_DIM 128
#define F1 256      // HEADS*HID = 4*64
#define HID 64
#define OUT_DIM 32
#define NEG 0.2f

// ---- bf16 helpers (storage format for gathered feature tables) ----
__device__ __forceinline__ float b2fl(unsigned u) {
  union { unsigned i; float f; } c; c.i = u << 16; return c.f;
}
__device__ __forceinline__ float b2fh(unsigned u) {
  union { unsigned i; float f; } c; c.i = u & 0xffff0000u; return c.f;
}
__device__ __forceinline__ unsigned short f2b(float f) {
  union { float f; unsigned i; } c; c.f = f;
  unsigned r = c.i + 0x7fffu + ((c.i >> 16) & 1u);   // RNE
  return (unsigned short)(r >> 16);
}

// ------- GEMM1: h1b[N,256](bf16) = x[N,128] @ W1[128,256], fused a1 dots -------
// blockIdx.y = head (64-col slice == one head). Epilogue computes this head's
// a1_src/a1_dst dots from fp32 acc and shuffle-reduces over the 16 tx lanes.
__global__ __launch_bounds__(256) void k_gemm1(const float* __restrict__ x,
    const float* __restrict__ W1, const float* __restrict__ a1s_w,
    const float* __restrict__ a1d_w, unsigned short* __restrict__ h1b,
    float* __restrict__ as1, float* __restrict__ ad1, int n) {
  __shared__ float xs[32][68];
  __shared__ float ws[32][64];
  const int tid = threadIdx.x;
  const int tx = tid & 15, ty = tid >> 4;
  const int rb = blockIdx.x * 64, cb = blockIdx.y * 64;
  const int hb = blockIdx.y;   // head index
  float acc[4][4] = {{0.f}};
  for (int kb = 0; kb < IN_DIM; kb += 32) {
#pragma unroll
    for (int i = 0; i < 8; ++i) {
      int idx = tid + i * 256;
      int r = idx >> 5, c = idx & 31;
      int row = rb + r;
      xs[c][r] = (row < n) ? x[(size_t)row * IN_DIM + kb + c] : 0.f;
    }
#pragma unroll
    for (int i = 0; i < 8; ++i) {
      int idx = tid + i * 256;
      int kk = idx >> 6, cc = idx & 63;
      ws[kk][cc] = W1[(size_t)(kb + kk) * F1 + cb + cc];
    }
    __syncthreads();
#pragma unroll
    for (int kk = 0; kk < 32; ++kk) {
      const float4 a4 = *(const float4*)&xs[kk][ty * 4];
      const float4 b4 = *(const float4*)&ws[kk][tx * 4];
      const float av[4] = {a4.x, a4.y, a4.z, a4.w};
      const float bv[4] = {b4.x, b4.y, b4.z, b4.w};
#pragma unroll
      for (int i = 0; i < 4; ++i)
#pragma unroll
        for (int j = 0; j < 4; ++j)
          acc[i][j] += av[i] * bv[j];
    }
    __syncthreads();
  }
  const float4 asv = *(const float4*)&a1s_w[cb + tx * 4];
  const float4 adv = *(const float4*)&a1d_w[cb + tx * 4];
#pragma unroll
  for (int i = 0; i < 4; ++i) {
    int row = rb + ty * 4 + i;
    float ds = acc[i][0] * asv.x + acc[i][1] * asv.y + acc[i][2] * asv.z + acc[i][3] * asv.w;
    float dd = acc[i][0] * adv.x + acc[i][1] * adv.y + acc[i][2] * adv.z + acc[i][3] * adv.w;
#pragma unroll
    for (int m = 1; m <= 8; m <<= 1) {
      ds += __shfl_xor(ds, m, 64);
      dd += __shfl_xor(dd, m, 64);
    }
    if (row < n) {
      ushort4 v;
      v.x = f2b(acc[i][0]); v.y = f2b(acc[i][1]);
      v.z = f2b(acc[i][2]); v.w = f2b(acc[i][3]);
      *(ushort4*)&h1b[(size_t)row * F1 + cb + tx * 4] = v;
      if (tx == 0) {
        as1[(size_t)row * 4 + hb] = ds;
        ad1[(size_t)row * 4 + hb] = dd;
      }
    }
  }
}

// ---------------- CSR build ----------------
__global__ __launch_bounds__(256) void k_hist(const int* __restrict__ adj,
    int* __restrict__ cnt, int E_, int n) {
  int e = blockIdx.x * 256 + threadIdx.x;
  int ET = E_ + n;
  if (e >= ET) return;
  int d = (e < E_) ? adj[E_ + e] : (e - E_);
  atomicAdd(&cnt[d], 1);
}

__global__ __launch_bounds__(256) void k_scan_local(const int* __restrict__ cnt,
    int* __restrict__ offs, int* __restrict__ bsum, int n) {
  __shared__ int wsums[4];
  const int tid = threadIdx.x;
  const int lane = tid & 63, w = tid >> 6;
  const int base = blockIdx.x * 1024;
  const int i0 = base + tid * 4;
  int v[4];
#pragma unroll
  for (int k = 0; k < 4; ++k) { int i = i0 + k; v[k] = (i < n) ? cnt[i] : 0; }
  int tsum = v[0] + v[1] + v[2] + v[3];
  int incl = tsum;
#pragma unroll
  for (int d = 1; d < 64; d <<= 1) {
    int t = __shfl_up(incl, (unsigned)d, 64);
    if (lane >= d) incl += t;
  }
  if (lane == 63) wsums[w] = incl;
  __syncthreads();
  int pre = 0;
  for (int k = 0; k < w; ++k) pre += wsums[k];
  int run = pre + incl - tsum;
#pragma unroll
  for (int k = 0; k < 4; ++k) { int i = i0 + k; if (i < n) offs[i] = run; run += v[k]; }
  if (tid == 255) bsum[blockIdx.x] = pre + incl;
}

__global__ void k_scan_bsum(int* __restrict__ bsum, int nb, int* __restrict__ offs_n) {
  int lane = threadIdx.x;   // 64 threads
  int carry = 0;
  for (int base = 0; base < nb; base += 64) {
    int i = base + lane;
    int v = (i < nb) ? bsum[i] : 0;
    int incl = v;
#pragma unroll
    for (int d = 1; d < 64; d <<= 1) {
      int t = __shfl_up(incl, (unsigned)d, 64);
      if (lane >= d) incl += t;
    }
    if (i < nb) bsum[i] = carry + incl - v;
    int tot = __shfl(incl, 63, 64);
    carry += tot;
  }
  if (lane == 0) *offs_n = carry;
}

__global__ __launch_bounds__(256) void k_scan_add(int* __restrict__ offs,
    const int* __restrict__ bsum, int* __restrict__ cursor, int n) {
  int i = blockIdx.x * 256 + threadIdx.x;
  if (i < n) {
    int v = offs[i] + bsum[i >> 10];
    offs[i] = v;
    cursor[i] = v;
  }
}

__global__ __launch_bounds__(256) void k_scatter(const int* __restrict__ adj,
    int* __restrict__ cursor, int* __restrict__ csr_src, int E_, int n) {
  int e = blockIdx.x * 256 + threadIdx.x;
  int ET = E_ + n;
  if (e >= ET) return;
  int s, d;
  if (e < E_) { s = adj[e]; d = adj[E_ + e]; } else { s = d = e - E_; }
  int pos = atomicAdd(&cursor[d], 1);
  csr_src[pos] = s;
}

// ---------------- fused GAT layer 1 (bf16 gather, head-split lanes) ----------------
__global__ __launch_bounds__(256) void k_agg1(const unsigned short* __restrict__ h1b,
    const float* __restrict__ as1, const float* __restrict__ ad1,
    const int* __restrict__ offs, const int* __restrict__ csr_src,
    const float* __restrict__ b1, float* __restrict__ relu1, int n) {
  int node = blockIdx.x * 4 + (threadIdx.x >> 6);
  int lane = threadIdx.x & 63;
  if (node >= n) return;
  const int h = lane >> 4;
  const int j0 = offs[node], j1 = offs[node + 1];
  const float adv = ad1[(size_t)node * 4 + h];
  float a0 = 0.f, a1 = 0.f, a2 = 0.f, a3 = 0.f, den = 0.f;
  int j = j0;
  for (; j + 4 <= j1; j += 4) {
    const int s0 = csr_src[j + 0], s1 = csr_src[j + 1];
    const int s2 = csr_src[j + 2], s3 = csr_src[j + 3];
    const float q0 = as1[(size_t)s0 * 4 + h];
    const float q1 = as1[(size_t)s1 * 4 + h];
    const float q2 = as1[(size_t)s2 * 4 + h];
    const float q3 = as1[(size_t)s3 * 4 + h];
    const uint2 u0 = ((const uint2*)(h1b + (size_t)s0 * F1))[lane];
    const uint2 u1 = ((const uint2*)(h1b + (size_t)s1 * F1))[lane];
    const uint2 u2 = ((const uint2*)(h1b + (size_t)s2 * F1))[lane];
    const uint2 u3 = ((const uint2*)(h1b + (size_t)s3 * F1))[lane];
    float e, w;
    e = q0 + adv; e = (e >= 0.f) ? e : NEG * e; w = __expf(e);
    den += w; a0 += w * b2fl(u0.x); a1 += w * b2fh(u0.x); a2 += w * b2fl(u0.y); a3 += w * b2fh(u0.y);
    e = q1 + adv; e = (e >= 0.f) ? e : NEG * e; w = __expf(e);
    den += w; a0 += w * b2fl(u1.x); a1 += w * b2fh(u1.x); a2 += w * b2fl(u1.y); a3 += w * b2fh(u1.y);
    e = q2 + adv; e = (e >= 0.f) ? e : NEG * e; w = __expf(e);
    den += w; a0 += w * b2fl(u2.x); a1 += w * b2fh(u2.x); a2 += w * b2fl(u2.y); a3 += w * b2fh(u2.y);
    e = q3 + adv; e = (e >= 0.f) ? e : NEG * e; w = __expf(e);
    den += w; a0 += w * b2fl(u3.x); a1 += w * b2fh(u3.x); a2 += w * b2fl(u3.y); a3 += w * b2fh(u3.y);
  }
  for (; j < j1; ++j) {
    const int s = csr_src[j];
    const float q = as1[(size_t)s * 4 + h];
    const uint2 u = ((const uint2*)(h1b + (size_t)s * F1))[lane];
    float e = q + adv; e = (e >= 0.f) ? e : NEG * e;
    float w = __expf(e);
    den += w; a0 += w * b2fl(u.x); a1 += w * b2fh(u.x); a2 += w * b2fl(u.y); a3 += w * b2fh(u.y);
  }
  const float inv = 1.0f / den;
  const float4 bb = ((const float4*)b1)[lane];
  float r0 = fmaxf(a0 * inv + bb.x, 0.f);
  float r1 = fmaxf(a1 * inv + bb.y, 0.f);
  float r2 = fmaxf(a2 * inv + bb.z, 0.f);
  float r3 = fmaxf(a3 * inv + bb.w, 0.f);
  ((float4*)(relu1 + (size_t)node * F1))[lane] = make_float4(r0, r1, r2, r3);
}

// ---------------- GEMM2 (register-tiled: 2 rows x 4 cols / thread) ----------------
// LDS instr budget was the R4 bottleneck (9 b32 per 8 FMA). Now per kk:
// 2 broadcast b32 (xs[k][row]) + 1 b128 (w2s float4) per 8 FMA.
__global__ __launch_bounds__(256) void k_gemm2(const float* __restrict__ relu1,
    const float* __restrict__ W2, const float* __restrict__ a2s_w,
    const float* __restrict__ a2d_w, unsigned short* __restrict__ h2b,
    float* __restrict__ as2, float* __restrict__ ad2, int n) {
  __shared__ float w2s[F1 * OUT_DIM];  // 32 KB
  __shared__ float xs[32][72];         // [k][row], 2-way bank alias = free
  const int tid = threadIdx.x;
  const int rb = blockIdx.x * 64;
  for (int i = tid; i < F1 * OUT_DIM; i += 256) w2s[i] = W2[i];
  const int rx = tid >> 3;       // 0..31 -> rows rx, rx+32
  const int cq = tid & 7;        // 0..7  -> cols 4cq..4cq+3
  float accA[4] = {0.f, 0.f, 0.f, 0.f};
  float accB[4] = {0.f, 0.f, 0.f, 0.f};
  for (int kb = 0; kb < F1; kb += 32) {
    __syncthreads();
#pragma unroll
    for (int i = 0; i < 8; ++i) {
      int idx = tid + i * 256;
      int r = idx >> 5, c = idx & 31;
      int row = rb + r;
      xs[c][r] = (row < n) ? relu1[(size_t)row * F1 + kb + c] : 0.f;
    }
    __syncthreads();
#pragma unroll
    for (int kk = 0; kk < 32; ++kk) {
      const float xa = xs[kk][rx];
      const float xb = xs[kk][rx + 32];
      const float4 wv = *(const float4*)&w2s[(kb + kk) * OUT_DIM + 4 * cq];
      accA[0] += xa * wv.x; accA[1] += xa * wv.y; accA[2] += xa * wv.z; accA[3] += xa * wv.w;
      accB[0] += xb * wv.x; accB[1] += xb * wv.y; accB[2] += xb * wv.z; accB[3] += xb * wv.w;
    }
  }
  const float4 sv = *(const float4*)&a2s_w[4 * cq];
  const float4 dv = *(const float4*)&a2d_w[4 * cq];
  const int rA = rb + rx, rB = rb + rx + 32;
  // store h2 bf16
  if (rA < n) {
    ushort4 v; v.x = f2b(accA[0]); v.y = f2b(accA[1]); v.z = f2b(accA[2]); v.w = f2b(accA[3]);
    *(ushort4*)&h2b[(size_t)rA * OUT_DIM + 4 * cq] = v;
  }
  if (rB < n) {
    ushort4 v; v.x = f2b(accB[0]); v.y = f2b(accB[1]); v.z = f2b(accB[2]); v.w = f2b(accB[3]);
    *(ushort4*)&h2b[(size_t)rB * OUT_DIM + 4 * cq] = v;
  }
  // alpha2 dots, reduce over the 8 cq lanes
  float ssA = accA[0] * sv.x + accA[1] * sv.y + accA[2] * sv.z + accA[3] * sv.w;
  float sdA = accA[0] * dv.x + accA[1] * dv.y + accA[2] * dv.z + accA[3] * dv.w;
  float ssB = accB[0] * sv.x + accB[1] * sv.y + accB[2] * sv.z + accB[3] * sv.w;
  float sdB = accB[0] * dv.x + accB[1] * dv.y + accB[2] * dv.z + accB[3] * dv.w;
#pragma unroll
  for (int m = 1; m <= 4; m <<= 1) {
    ssA += __shfl_xor(ssA, m, 64);
    sdA += __shfl_xor(sdA, m, 64);
    ssB += __shfl_xor(ssB, m, 64);
    sdB += __shfl_xor(sdB, m, 64);
  }
  if (cq == 0) {
    if (rA < n) { as2[rA] = ssA; ad2[rA] = sdA; }
    if (rB < n) { as2[rB] = ssB; ad2[rB] = sdB; }
  }
}

// -------- fused GAT layer 2 (bf16 gather, quarter-wave per edge) --------
__global__ __launch_bounds__(256) void k_agg2(const unsigned short* __restrict__ h2b,
    const float* __restrict__ as2, const float* __restrict__ ad2,
    const int* __restrict__ offs, const int* __restrict__ csr_src,
    const float* __restrict__ b2, const float* __restrict__ linW,
    float* __restrict__ score, int n) {
  int node = blockIdx.x * 4 + (threadIdx.x >> 6);
  int lane = threadIdx.x & 63;
  if (node >= n) return;
  const int sub = lane >> 4;
  const int p = lane & 15;
  const int j0 = offs[node], j1 = offs[node + 1];
  const float adv = ad2[node];
  float acc0 = 0.f, acc1 = 0.f, den = 0.f;
  int jj = j0;
  for (; jj + 8 <= j1; jj += 8) {
    const int sA = csr_src[jj + sub];
    const int sB = csr_src[jj + 4 + sub];
    const float aA = as2[sA], aB = as2[sB];
    const unsigned uA = ((const unsigned*)(h2b + (size_t)sA * OUT_DIM))[p];
    const unsigned uB = ((const unsigned*)(h2b + (size_t)sB * OUT_DIM))[p];
    float e, w;
    e = aA + adv; e = (e >= 0.f) ? e : NEG * e; w = __expf(e);
    den += w; acc0 += w * b2fl(uA); acc1 += w * b2fh(uA);
    e = aB + adv; e = (e >= 0.f) ? e : NEG * e; w = __expf(e);
    den += w; acc0 += w * b2fl(uB); acc1 += w * b2fh(uB);
  }
  for (; jj < j1; jj += 4) {
    const int idx = jj + sub;
    const bool valid = idx < j1;
    const int s = valid ? csr_src[idx] : csr_src[j1 - 1];
    const float a = as2[s];
    const unsigned u = ((const unsigned*)(h2b + (size_t)s * OUT_DIM))[p];
    float e = a + adv; e = (e >= 0.f) ? e : NEG * e;
    float w = valid ? __expf(e) : 0.f;
    den += w; acc0 += w * b2fl(u); acc1 += w * b2fh(u);
  }
  den  += __shfl_xor(den, 16, 64);  den  += __shfl_xor(den, 32, 64);
  acc0 += __shfl_xor(acc0, 16, 64); acc0 += __shfl_xor(acc0, 32, 64);
  acc1 += __shfl_xor(acc1, 16, 64); acc1 += __shfl_xor(acc1, 32, 64);
  const float inv = 1.0f / den;
  float o0 = acc0 * inv + b2[2 * p];
  float o1 = acc1 * inv + b2[2 * p + 1];
  float m = fmaxf(o0, o1);
#pragma unroll
  for (int mm = 1; mm <= 8; mm <<= 1) m = fmaxf(m, __shfl_xor(m, mm, 64));
  float ssum = __expf(o0 - m) + __expf(o1 - m);
#pragma unroll
  for (int mm = 1; mm <= 8; mm <<= 1) ssum += __shfl_xor(ssum, mm, 64);
  const float lse = m + __logf(ssum);
  float sc = (o0 - lse) * linW[2 * p] + (o1 - lse) * linW[2 * p + 1];
#pragma unroll
  for (int mm = 1; mm <= 8; mm <<= 1) sc += __shfl_xor(sc, mm, 64);
  if (lane == 0) score[node] = sc;
}

// -------- pooling: LDS per-graph partials, few global atomics per block --------
__global__ __launch_bounds__(256) void k_pool(const float* __restrict__ score,
    const int* __restrict__ batch, float* __restrict__ gsum,
    float* __restrict__ gcnt, int n) {
  __shared__ float ps[64];
  __shared__ float pc[64];
  const int tid = threadIdx.x;
  if (tid < 64) { ps[tid] = 0.f; pc[tid] = 0.f; }
  __syncthreads();
  int i = blockIdx.x * 256 + tid;
  if (i < n) {
    int g = batch[i];
    atomicAdd(&ps[g], score[i]);
    atomicAdd(&pc[g], 1.0f);
  }
  __syncthreads();
  if (tid < 64 && pc[tid] != 0.f) {
    atomicAdd(&gsum[tid], ps[tid]);
    atomicAdd(&gcnt[tid], pc[tid]);
  }
}

__global__ void k_final(const float* __restrict__ gsum, const float* __restrict__ gcnt,
                        const float* __restrict__ linb, float* __restrict__ out, int g_) {
  int g = threadIdx.x;
  if (g < g_) out[g] = gsum[g] / fmaxf(gcnt[g], 1.0f) + linb[0];
}

extern "C" void kernel_launch(void* const* d_in, const int* in_sizes, int n_in,
                              void* d_out, int out_size, void* d_ws, size_t ws_size,
                              hipStream_t stream) {
  const float* x    = (const float*)d_in[0];
  const int*   adj  = (const int*)d_in[1];
  const int*   batch= (const int*)d_in[2];
  const float* W1   = (const float*)d_in[3];
  const float* a1s  = (const float*)d_in[4];
  const float* a1d  = (const float*)d_in[5];
  const float* b1   = (const float*)d_in[6];
  const float* W2   = (const float*)d_in[7];
  const float* a2s  = (const float*)d_in[8];
  const float* a2d  = (const float*)d_in[9];
  const float* b2   = (const float*)d_in[10];
  const float* linW = (const float*)d_in[11];
  const float* linb = (const float*)d_in[12];

  const int N = in_sizes[0] / IN_DIM;
  const int E = in_sizes[1] / 2;
  const int ET = E + N;
  const int G = out_size;   // 64
  const int NB = (N + 1023) / 1024;

  char* wsb = (char*)d_ws;
  size_t off = 0;
  auto take = [&](size_t bytes) -> char* {
    char* p = wsb + off;
    off += (bytes + 255) & ~(size_t)255;
    return p;
  };
  unsigned short* h1b = (unsigned short*)take((size_t)N * F1 * 2);
  float* relu1  = (float*)take((size_t)N * F1 * 4);
  float* as1    = (float*)take((size_t)N * 4 * 4);
  float* ad1    = (float*)take((size_t)N * 4 * 4);
  unsigned short* h2b = (unsigned short*)take((size_t)N * OUT_DIM * 2);
  float* as2v   = (float*)take((size_t)N * 4);
  float* ad2v   = (float*)take((size_t)N * 4);
  float* score  = (float*)take((size_t)N * 4);
  int*   cnt    = (int*)take((size_t)N * 4);
  int*   offs   = (int*)take((size_t)(N + 1) * 4);
  int*   cursor = (int*)take((size_t)N * 4);
  int*   csr_src= (int*)take((size_t)ET * 4);
  int*   bsum   = (int*)take((size_t)(NB + 1) * 4);
  float* gsum   = (float*)take((size_t)G * 4);
  float* gcnt   = (float*)take((size_t)G * 4);
  (void)ws_size; (void)n_in;

  hipMemsetAsync(cnt, 0, (size_t)N * 4, stream);
  hipMemsetAsync(gsum, 0, (size_t)G * 4, stream);
  hipMemsetAsync(gcnt, 0, (size_t)G * 4, stream);

  dim3 b256(256);
  k_gemm1<<<dim3((N + 63) / 64, F1 / 64), b256, 0, stream>>>(x, W1, a1s, a1d, h1b, as1, ad1, N);
  k_hist<<<dim3((ET + 255) / 256), b256, 0, stream>>>(adj, cnt, E, N);
  k_scan_local<<<dim3(NB), b256, 0, stream>>>(cnt, offs, bsum, N);
  k_scan_bsum<<<1, 64, 0, stream>>>(bsum, NB, offs + N);
  k_scan_add<<<dim3((N + 255) / 256), b256, 0, stream>>>(offs, bsum, cursor, N);
  k_scatter<<<dim3((ET + 255) / 256), b256, 0, stream>>>(adj, cursor, csr_src, E, N);
  k_agg1<<<dim3((N + 3) / 4), b256, 0, stream>>>(h1b, as1, ad1, offs, csr_src, b1, relu1, N);
  k_gemm2<<<dim3((N + 63) / 64), b256, 0, stream>>>(relu1, W2, a2s, a2d, h2b, as2v, ad2v, N);
  k_agg2<<<dim3((N + 3) / 4), b256, 0, stream>>>(h2b, as2v, ad2v, offs, csr_src, b2, linW, score, N);
  k_pool<<<dim3((N + 255) / 256), b256, 0, stream>>>(score, batch, gsum, gcnt, N);
  k_final<<<1, 64, 0, stream>>>(gsum, gcnt, linb, (float*)d_out, G);
}

// Round 7
// 368.304 us; speedup vs baseline: 2.5225x; 1.0788x over previous
//
#include <hip/hip_runtime.h>

#define IN_DIM 128
#define F1 256      // HEADS*HID = 4*64
#define HID 64
#define OUT_DIM 32
#define NEG 0.2f
#define PADK 136    // LDS row pitch in bf16 elems (128 + 8): frag reads 2-way alias = free

typedef __attribute__((ext_vector_type(8))) short short8;
typedef __attribute__((ext_vector_type(4))) float v4f;

// ---- bf16 helpers ----
__device__ __forceinline__ float b2fl(unsigned u) {
  union { unsigned i; float f; } c; c.i = u << 16; return c.f;
}
__device__ __forceinline__ float b2fh(unsigned u) {
  union { unsigned i; float f; } c; c.i = u & 0xffff0000u; return c.f;
}
__device__ __forceinline__ unsigned short f2b(float f) {
  union { float f; unsigned i; } c; c.f = f;
  unsigned r = c.i + 0x7fffu + ((c.i >> 16) & 1u);   // RNE
  return (unsigned short)(r >> 16);
}

// ---- prep: W1t[n][k] bf16 = transpose of W1[k][n] fp32 (one-time, 32K elems) ----
__global__ __launch_bounds__(256) void k_prep(const float* __restrict__ W1,
    unsigned short* __restrict__ W1t) {
  int idx = blockIdx.x * 256 + threadIdx.x;   // 0..32767
  int nn = idx >> 7, k = idx & 127;
  W1t[idx] = f2b(W1[(size_t)k * F1 + nn]);
}

// ------- GEMM1 via MFMA: h1b[N,256](bf16) = bf16(x)[N,128] @ W1[128,256] -------
// block = 64 rows x 64 cols (one head), 4 waves; wave w = rows 16w..16w+15.
// Verified layouts (learn_hip m89/m120): A[m=lane&15][k=quad*8+j],
// B[k=quad*8+j][n=lane&15] (from W1t n-major), C/D row=quad*4+reg, col=lane&15.
__global__ __launch_bounds__(256) void k_gemm1(const float* __restrict__ x,
    const unsigned short* __restrict__ W1t,
    const float* __restrict__ a1s_w, const float* __restrict__ a1d_w,
    unsigned short* __restrict__ h1b, float* __restrict__ as1,
    float* __restrict__ ad1, int n) {
  __shared__ unsigned short xs[64 * PADK];   // 17.4 KB
  __shared__ unsigned short ws[64 * PADK];   // 17.4 KB
  const int tid = threadIdx.x;
  const int rb = blockIdx.x * 64;
  const int head = blockIdx.y;
  const int cb = head * 64;

  // stage x tile: 64 rows x 128 cols fp32 -> bf16 (2048 float4 chunks, 8/thread)
#pragma unroll
  for (int i = 0; i < 8; ++i) {
    int idx = tid + i * 256;
    int row = idx >> 5, c4 = idx & 31;
    float4 v = make_float4(0.f, 0.f, 0.f, 0.f);
    if (rb + row < n) v = *(const float4*)&x[(size_t)(rb + row) * IN_DIM + c4 * 4];
    ushort4 b; b.x = f2b(v.x); b.y = f2b(v.y); b.z = f2b(v.z); b.w = f2b(v.w);
    *(ushort4*)&xs[row * PADK + c4 * 4] = b;
  }
  // stage W1t slice rows cb..cb+63 (bf16, n-major): 64 rows x 16 uint4 chunks
  // (R6 BUG was row=idx>>3,c=idx&7: half-K stale + OOB. Fixed: >>4, &15.)
#pragma unroll
  for (int i = 0; i < 4; ++i) {
    int idx = tid + i * 256;
    int row = idx >> 4, c = idx & 15;
    *(uint4*)&ws[row * PADK + c * 8] =
        *(const uint4*)&W1t[(size_t)(cb + row) * IN_DIM + c * 8];
  }
  __syncthreads();

  const int wv = tid >> 6;
  const int lane = tid & 63;
  const int l15 = lane & 15, quad = lane >> 4;
  v4f acc0 = {0.f, 0.f, 0.f, 0.f}, acc1 = acc0, acc2 = acc0, acc3 = acc0;
#pragma unroll
  for (int kt = 0; kt < 4; ++kt) {
    const int ko = kt * 32 + quad * 8;
    short8 af = *(const short8*)&xs[(wv * 16 + l15) * PADK + ko];
    short8 b0 = *(const short8*)&ws[(l15) * PADK + ko];
    short8 b1 = *(const short8*)&ws[(16 + l15) * PADK + ko];
    short8 b2 = *(const short8*)&ws[(32 + l15) * PADK + ko];
    short8 b3 = *(const short8*)&ws[(48 + l15) * PADK + ko];
    acc0 = __builtin_amdgcn_mfma_f32_16x16x32_bf16(af, b0, acc0, 0, 0, 0);
    acc1 = __builtin_amdgcn_mfma_f32_16x16x32_bf16(af, b1, acc1, 0, 0, 0);
    acc2 = __builtin_amdgcn_mfma_f32_16x16x32_bf16(af, b2, acc2, 0, 0, 0);
    acc3 = __builtin_amdgcn_mfma_f32_16x16x32_bf16(af, b3, acc3, 0, 0, 0);
  }

  // epilogue: h1b stores + fused a1_src/a1_dst dots (per-row, this head)
  const float s0 = a1s_w[cb + l15],      s1 = a1s_w[cb + 16 + l15];
  const float s2 = a1s_w[cb + 32 + l15], s3 = a1s_w[cb + 48 + l15];
  const float d0 = a1d_w[cb + l15],      d1 = a1d_w[cb + 16 + l15];
  const float d2 = a1d_w[cb + 32 + l15], d3 = a1d_w[cb + 48 + l15];
#pragma unroll
  for (int r = 0; r < 4; ++r) {
    const int row = rb + wv * 16 + quad * 4 + r;
    const bool ok = row < n;
    if (ok) {
      size_t base = (size_t)row * F1 + cb;
      h1b[base + l15]      = f2b(acc0[r]);
      h1b[base + 16 + l15] = f2b(acc1[r]);
      h1b[base + 32 + l15] = f2b(acc2[r]);
      h1b[base + 48 + l15] = f2b(acc3[r]);
    }
    float ds = acc0[r] * s0 + acc1[r] * s1 + acc2[r] * s2 + acc3[r] * s3;
    float dd = acc0[r] * d0 + acc1[r] * d1 + acc2[r] * d2 + acc3[r] * d3;
#pragma unroll
    for (int m = 1; m <= 8; m <<= 1) {
      ds += __shfl_xor(ds, m, 64);
      dd += __shfl_xor(dd, m, 64);
    }
    if (ok && l15 == 0) {
      as1[(size_t)row * 4 + head] = ds;
      ad1[(size_t)row * 4 + head] = dd;
    }
  }
}

// ---------------- CSR build ----------------
__global__ __launch_bounds__(256) void k_hist(const int* __restrict__ adj,
    int* __restrict__ cnt, int E_, int n) {
  int e = blockIdx.x * 256 + threadIdx.x;
  int ET = E_ + n;
  if (e >= ET) return;
  int d = (e < E_) ? adj[E_ + e] : (e - E_);
  atomicAdd(&cnt[d], 1);
}

__global__ __launch_bounds__(256) void k_scan_local(const int* __restrict__ cnt,
    int* __restrict__ offs, int* __restrict__ bsum, int n) {
  __shared__ int wsums[4];
  const int tid = threadIdx.x;
  const int lane = tid & 63, w = tid >> 6;
  const int base = blockIdx.x * 1024;
  const int i0 = base + tid * 4;
  int v[4];
#pragma unroll
  for (int k = 0; k < 4; ++k) { int i = i0 + k; v[k] = (i < n) ? cnt[i] : 0; }
  int tsum = v[0] + v[1] + v[2] + v[3];
  int incl = tsum;
#pragma unroll
  for (int d = 1; d < 64; d <<= 1) {
    int t = __shfl_up(incl, (unsigned)d, 64);
    if (lane >= d) incl += t;
  }
  if (lane == 63) wsums[w] = incl;
  __syncthreads();
  int pre = 0;
  for (int k = 0; k < w; ++k) pre += wsums[k];
  int run = pre + incl - tsum;
#pragma unroll
  for (int k = 0; k < 4; ++k) { int i = i0 + k; if (i < n) offs[i] = run; run += v[k]; }
  if (tid == 255) bsum[blockIdx.x] = pre + incl;
}

__global__ void k_scan_bsum(int* __restrict__ bsum, int nb, int* __restrict__ offs_n) {
  int lane = threadIdx.x;   // 64 threads
  int carry = 0;
  for (int base = 0; base < nb; base += 64) {
    int i = base + lane;
    int v = (i < nb) ? bsum[i] : 0;
    int incl = v;
#pragma unroll
    for (int d = 1; d < 64; d <<= 1) {
      int t = __shfl_up(incl, (unsigned)d, 64);
      if (lane >= d) incl += t;
    }
    if (i < nb) bsum[i] = carry + incl - v;
    int tot = __shfl(incl, 63, 64);
    carry += tot;
  }
  if (lane == 0) *offs_n = carry;
}

__global__ __launch_bounds__(256) void k_scan_add(int* __restrict__ offs,
    const int* __restrict__ bsum, int* __restrict__ cursor, int n) {
  int i = blockIdx.x * 256 + threadIdx.x;
  if (i < n) {
    int v = offs[i] + bsum[i >> 10];
    offs[i] = v;
    cursor[i] = v;
  }
}

__global__ __launch_bounds__(256) void k_scatter(const int* __restrict__ adj,
    int* __restrict__ cursor, int* __restrict__ csr_src, int E_, int n) {
  int e = blockIdx.x * 256 + threadIdx.x;
  int ET = E_ + n;
  if (e >= ET) return;
  int s, d;
  if (e < E_) { s = adj[e]; d = adj[E_ + e]; } else { s = d = e - E_; }
  int pos = atomicAdd(&cursor[d], 1);
  csr_src[pos] = s;
}

// ---------------- fused GAT layer 1 (bf16 gather, head-split lanes) ----------------
__global__ __launch_bounds__(256) void k_agg1(const unsigned short* __restrict__ h1b,
    const float* __restrict__ as1, const float* __restrict__ ad1,
    const int* __restrict__ offs, const int* __restrict__ csr_src,
    const float* __restrict__ b1, float* __restrict__ relu1, int n) {
  int node = blockIdx.x * 4 + (threadIdx.x >> 6);
  int lane = threadIdx.x & 63;
  if (node >= n) return;
  const int h = lane >> 4;
  const int j0 = offs[node], j1 = offs[node + 1];
  const float adv = ad1[(size_t)node * 4 + h];
  float a0 = 0.f, a1 = 0.f, a2 = 0.f, a3 = 0.f, den = 0.f;
  int j = j0;
  for (; j + 4 <= j1; j += 4) {
    const int s0 = csr_src[j + 0], s1 = csr_src[j + 1];
    const int s2 = csr_src[j + 2], s3 = csr_src[j + 3];
    const float q0 = as1[(size_t)s0 * 4 + h];
    const float q1 = as1[(size_t)s1 * 4 + h];
    const float q2 = as1[(size_t)s2 * 4 + h];
    const float q3 = as1[(size_t)s3 * 4 + h];
    const uint2 u0 = ((const uint2*)(h1b + (size_t)s0 * F1))[lane];
    const uint2 u1 = ((const uint2*)(h1b + (size_t)s1 * F1))[lane];
    const uint2 u2 = ((const uint2*)(h1b + (size_t)s2 * F1))[lane];
    const uint2 u3 = ((const uint2*)(h1b + (size_t)s3 * F1))[lane];
    float e, w;
    e = q0 + adv; e = (e >= 0.f) ? e : NEG * e; w = __expf(e);
    den += w; a0 += w * b2fl(u0.x); a1 += w * b2fh(u0.x); a2 += w * b2fl(u0.y); a3 += w * b2fh(u0.y);
    e = q1 + adv; e = (e >= 0.f) ? e : NEG * e; w = __expf(e);
    den += w; a0 += w * b2fl(u1.x); a1 += w * b2fh(u1.x); a2 += w * b2fl(u1.y); a3 += w * b2fh(u1.y);
    e = q2 + adv; e = (e >= 0.f) ? e : NEG * e; w = __expf(e);
    den += w; a0 += w * b2fl(u2.x); a1 += w * b2fh(u2.x); a2 += w * b2fl(u2.y); a3 += w * b2fh(u2.y);
    e = q3 + adv; e = (e >= 0.f) ? e : NEG * e; w = __expf(e);
    den += w; a0 += w * b2fl(u3.x); a1 += w * b2fh(u3.x); a2 += w * b2fl(u3.y); a3 += w * b2fh(u3.y);
  }
  for (; j < j1; ++j) {
    const int s = csr_src[j];
    const float q = as1[(size_t)s * 4 + h];
    const uint2 u = ((const uint2*)(h1b + (size_t)s * F1))[lane];
    float e = q + adv; e = (e >= 0.f) ? e : NEG * e;
    float w = __expf(e);
    den += w; a0 += w * b2fl(u.x); a1 += w * b2fh(u.x); a2 += w * b2fl(u.y); a3 += w * b2fh(u.y);
  }
  const float inv = 1.0f / den;
  const float4 bb = ((const float4*)b1)[lane];
  float r0 = fmaxf(a0 * inv + bb.x, 0.f);
  float r1 = fmaxf(a1 * inv + bb.y, 0.f);
  float r2 = fmaxf(a2 * inv + bb.z, 0.f);
  float r3 = fmaxf(a3 * inv + bb.w, 0.f);
  ((float4*)(relu1 + (size_t)node * F1))[lane] = make_float4(r0, r1, r2, r3);
}

// ---------------- GEMM2 (register-tiled: 2 rows x 4 cols / thread) ----------------
__global__ __launch_bounds__(256) void k_gemm2(const float* __restrict__ relu1,
    const float* __restrict__ W2, const float* __restrict__ a2s_w,
    const float* __restrict__ a2d_w, unsigned short* __restrict__ h2b,
    float* __restrict__ as2, float* __restrict__ ad2, int n) {
  __shared__ float w2s[F1 * OUT_DIM];  // 32 KB
  __shared__ float xs[32][72];         // [k][row], 2-way bank alias = free
  const int tid = threadIdx.x;
  const int rb = blockIdx.x * 64;
  for (int i = tid; i < F1 * OUT_DIM; i += 256) w2s[i] = W2[i];
  const int rx = tid >> 3;       // 0..31 -> rows rx, rx+32
  const int cq = tid & 7;        // 0..7  -> cols 4cq..4cq+3
  float accA[4] = {0.f, 0.f, 0.f, 0.f};
  float accB[4] = {0.f, 0.f, 0.f, 0.f};
  for (int kb = 0; kb < F1; kb += 32) {
    __syncthreads();
#pragma unroll
    for (int i = 0; i < 8; ++i) {
      int idx = tid + i * 256;
      int r = idx >> 5, c = idx & 31;
      int row = rb + r;
      xs[c][r] = (row < n) ? relu1[(size_t)row * F1 + kb + c] : 0.f;
    }
    __syncthreads();
#pragma unroll
    for (int kk = 0; kk < 32; ++kk) {
      const float xa = xs[kk][rx];
      const float xb = xs[kk][rx + 32];
      const float4 wv = *(const float4*)&w2s[(kb + kk) * OUT_DIM + 4 * cq];
      accA[0] += xa * wv.x; accA[1] += xa * wv.y; accA[2] += xa * wv.z; accA[3] += xa * wv.w;
      accB[0] += xb * wv.x; accB[1] += xb * wv.y; accB[2] += xb * wv.z; accB[3] += xb * wv.w;
    }
  }
  const float4 sv = *(const float4*)&a2s_w[4 * cq];
  const float4 dv = *(const float4*)&a2d_w[4 * cq];
  const int rA = rb + rx, rB = rb + rx + 32;
  if (rA < n) {
    ushort4 v; v.x = f2b(accA[0]); v.y = f2b(accA[1]); v.z = f2b(accA[2]); v.w = f2b(accA[3]);
    *(ushort4*)&h2b[(size_t)rA * OUT_DIM + 4 * cq] = v;
  }
  if (rB < n) {
    ushort4 v; v.x = f2b(accB[0]); v.y = f2b(accB[1]); v.z = f2b(accB[2]); v.w = f2b(accB[3]);
    *(ushort4*)&h2b[(size_t)rB * OUT_DIM + 4 * cq] = v;
  }
  float ssA = accA[0] * sv.x + accA[1] * sv.y + accA[2] * sv.z + accA[3] * sv.w;
  float sdA = accA[0] * dv.x + accA[1] * dv.y + accA[2] * dv.z + accA[3] * dv.w;
  float ssB = accB[0] * sv.x + accB[1] * sv.y + accB[2] * sv.z + accB[3] * sv.w;
  float sdB = accB[0] * dv.x + accB[1] * dv.y + accB[2] * dv.z + accB[3] * dv.w;
#pragma unroll
  for (int m = 1; m <= 4; m <<= 1) {
    ssA += __shfl_xor(ssA, m, 64);
    sdA += __shfl_xor(sdA, m, 64);
    ssB += __shfl_xor(ssB, m, 64);
    sdB += __shfl_xor(sdB, m, 64);
  }
  if (cq == 0) {
    if (rA < n) { as2[rA] = ssA; ad2[rA] = sdA; }
    if (rB < n) { as2[rB] = ssB; ad2[rB] = sdB; }
  }
}

// -------- fused GAT layer 2 (bf16 gather, quarter-wave per edge) --------
__global__ __launch_bounds__(256) void k_agg2(const unsigned short* __restrict__ h2b,
    const float* __restrict__ as2, const float* __restrict__ ad2,
    const int* __restrict__ offs, const int* __restrict__ csr_src,
    const float* __restrict__ b2, const float* __restrict__ linW,
    float* __restrict__ score, int n) {
  int node = blockIdx.x * 4 + (threadIdx.x >> 6);
  int lane = threadIdx.x & 63;
  if (node >= n) return;
  const int sub = lane >> 4;
  const int p = lane & 15;
  const int j0 = offs[node], j1 = offs[node + 1];
  const float adv = ad2[node];
  float acc0 = 0.f, acc1 = 0.f, den = 0.f;
  int jj = j0;
  for (; jj + 8 <= j1; jj += 8) {
    const int sA = csr_src[jj + sub];
    const int sB = csr_src[jj + 4 + sub];
    const float aA = as2[sA], aB = as2[sB];
    const unsigned uA = ((const unsigned*)(h2b + (size_t)sA * OUT_DIM))[p];
    const unsigned uB = ((const unsigned*)(h2b + (size_t)sB * OUT_DIM))[p];
    float e, w;
    e = aA + adv; e = (e >= 0.f) ? e : NEG * e; w = __expf(e);
    den += w; acc0 += w * b2fl(uA); acc1 += w * b2fh(uA);
    e = aB + adv; e = (e >= 0.f) ? e : NEG * e; w = __expf(e);
    den += w; acc0 += w * b2fl(uB); acc1 += w * b2fh(uB);
  }
  for (; jj < j1; jj += 4) {
    const int idx = jj + sub;
    const bool valid = idx < j1;
    const int s = valid ? csr_src[idx] : csr_src[j1 - 1];
    const float a = as2[s];
    const unsigned u = ((const unsigned*)(h2b + (size_t)s * OUT_DIM))[p];
    float e = a + adv; e = (e >= 0.f) ? e : NEG * e;
    float w = valid ? __expf(e) : 0.f;
    den += w; acc0 += w * b2fl(u); acc1 += w * b2fh(u);
  }
  den  += __shfl_xor(den, 16, 64);  den  += __shfl_xor(den, 32, 64);
  acc0 += __shfl_xor(acc0, 16, 64); acc0 += __shfl_xor(acc0, 32, 64);
  acc1 += __shfl_xor(acc1, 16, 64); acc1 += __shfl_xor(acc1, 32, 64);
  const float inv = 1.0f / den;
  float o0 = acc0 * inv + b2[2 * p];
  float o1 = acc1 * inv + b2[2 * p + 1];
  float m = fmaxf(o0, o1);
#pragma unroll
  for (int mm = 1; mm <= 8; mm <<= 1) m = fmaxf(m, __shfl_xor(m, mm, 64));
  float ssum = __expf(o0 - m) + __expf(o1 - m);
#pragma unroll
  for (int mm = 1; mm <= 8; mm <<= 1) ssum += __shfl_xor(ssum, mm, 64);
  const float lse = m + __logf(ssum);
  float sc = (o0 - lse) * linW[2 * p] + (o1 - lse) * linW[2 * p + 1];
#pragma unroll
  for (int mm = 1; mm <= 8; mm <<= 1) sc += __shfl_xor(sc, mm, 64);
  if (lane == 0) score[node] = sc;
}

// -------- pooling: LDS per-graph partials, few global atomics per block --------
__global__ __launch_bounds__(256) void k_pool(const float* __restrict__ score,
    const int* __restrict__ batch, float* __restrict__ gsum,
    float* __restrict__ gcnt, int n) {
  __shared__ float ps[64];
  __shared__ float pc[64];
  const int tid = threadIdx.x;
  if (tid < 64) { ps[tid] = 0.f; pc[tid] = 0.f; }
  __syncthreads();
  int i = blockIdx.x * 256 + tid;
  if (i < n) {
    int g = batch[i];
    atomicAdd(&ps[g], score[i]);
    atomicAdd(&pc[g], 1.0f);
  }
  __syncthreads();
  if (tid < 64 && pc[tid] != 0.f) {
    atomicAdd(&gsum[tid], ps[tid]);
    atomicAdd(&gcnt[tid], pc[tid]);
  }
}

__global__ void k_final(const float* __restrict__ gsum, const float* __restrict__ gcnt,
                        const float* __restrict__ linb, float* __restrict__ out, int g_) {
  int g = threadIdx.x;
  if (g < g_) out[g] = gsum[g] / fmaxf(gcnt[g], 1.0f) + linb[0];
}

extern "C" void kernel_launch(void* const* d_in, const int* in_sizes, int n_in,
                              void* d_out, int out_size, void* d_ws, size_t ws_size,
                              hipStream_t stream) {
  const float* x    = (const float*)d_in[0];
  const int*   adj  = (const int*)d_in[1];
  const int*   batch= (const int*)d_in[2];
  const float* W1   = (const float*)d_in[3];
  const float* a1s  = (const float*)d_in[4];
  const float* a1d  = (const float*)d_in[5];
  const float* b1   = (const float*)d_in[6];
  const float* W2   = (const float*)d_in[7];
  const float* a2s  = (const float*)d_in[8];
  const float* a2d  = (const float*)d_in[9];
  const float* b2   = (const float*)d_in[10];
  const float* linW = (const float*)d_in[11];
  const float* linb = (const float*)d_in[12];

  const int N = in_sizes[0] / IN_DIM;
  const int E = in_sizes[1] / 2;
  const int ET = E + N;
  const int G = out_size;   // 64
  const int NB = (N + 1023) / 1024;

  char* wsb = (char*)d_ws;
  size_t off = 0;
  auto take = [&](size_t bytes) -> char* {
    char* p = wsb + off;
    off += (bytes + 255) & ~(size_t)255;
    return p;
  };
  unsigned short* h1b = (unsigned short*)take((size_t)N * F1 * 2);
  float* relu1  = (float*)take((size_t)N * F1 * 4);
  float* as1    = (float*)take((size_t)N * 4 * 4);
  float* ad1    = (float*)take((size_t)N * 4 * 4);
  unsigned short* h2b = (unsigned short*)take((size_t)N * OUT_DIM * 2);
  float* as2v   = (float*)take((size_t)N * 4);
  float* ad2v   = (float*)take((size_t)N * 4);
  float* score  = (float*)take((size_t)N * 4);
  int*   cnt    = (int*)take((size_t)N * 4);
  int*   offs   = (int*)take((size_t)(N + 1) * 4);
  int*   cursor = (int*)take((size_t)N * 4);
  int*   csr_src= (int*)take((size_t)ET * 4);
  int*   bsum   = (int*)take((size_t)(NB + 1) * 4);
  float* gsum   = (float*)take((size_t)G * 4);
  float* gcnt   = (float*)take((size_t)G * 4);
  unsigned short* W1t = (unsigned short*)take((size_t)IN_DIM * F1 * 2);
  (void)ws_size; (void)n_in;

  hipMemsetAsync(cnt, 0, (size_t)N * 4, stream);
  hipMemsetAsync(gsum, 0, (size_t)G * 4, stream);
  hipMemsetAsync(gcnt, 0, (size_t)G * 4, stream);

  dim3 b256(256);
  k_prep<<<dim3((IN_DIM * F1) / 256), b256, 0, stream>>>(W1, W1t);
  k_gemm1<<<dim3((N + 63) / 64, F1 / 64), b256, 0, stream>>>(x, W1t, a1s, a1d, h1b, as1, ad1, N);
  k_hist<<<dim3((ET + 255) / 256), b256, 0, stream>>>(adj, cnt, E, N);
  k_scan_local<<<dim3(NB), b256, 0, stream>>>(cnt, offs, bsum, N);
  k_scan_bsum<<<1, 64, 0, stream>>>(bsum, NB, offs + N);
  k_scan_add<<<dim3((N + 255) / 256), b256, 0, stream>>>(offs, bsum, cursor, N);
  k_scatter<<<dim3((ET + 255) / 256), b256, 0, stream>>>(adj, cursor, csr_src, E, N);
  k_agg1<<<dim3((N + 3) / 4), b256, 0, stream>>>(h1b, as1, ad1, offs, csr_src, b1, relu1, N);
  k_gemm2<<<dim3((N + 63) / 64), b256, 0, stream>>>(relu1, W2, a2s, a2d, h2b, as2v, ad2v, N);
  k_agg2<<<dim3((N + 3) / 4), b256, 0, stream>>>(h2b, as2v, ad2v, offs, csr_src, b2, linW, score, N);
  k_pool<<<dim3((N + 255) / 256), b256, 0, stream>>>(score, batch, gsum, gcnt, N);
  k_final<<<1, 64, 0, stream>>>(gsum, gcnt, linb, (float*)d_out, G);
}

// Round 8
// 332.646 us; speedup vs baseline: 2.7929x; 1.1072x over previous
//
#include <hip/hip_runtime.h>

#define IN_DIM 128
#define F1 256      // HEADS*HID = 4*64
#define HID 64
#define OUT_DIM 32
#define NEG 0.2f
#define PADK 136    // LDS row pitch in bf16 elems (128 + 8): frag reads 2-way alias = free

typedef __attribute__((ext_vector_type(8))) short short8;
typedef __attribute__((ext_vector_type(4))) float v4f;

// ---- bf16 helpers ----
__device__ __forceinline__ float b2fl(unsigned u) {
  union { unsigned i; float f; } c; c.i = u << 16; return c.f;
}
__device__ __forceinline__ float b2fh(unsigned u) {
  union { unsigned i; float f; } c; c.i = u & 0xffff0000u; return c.f;
}
__device__ __forceinline__ unsigned short f2b(float f) {
  union { float f; unsigned i; } c; c.f = f;
  unsigned r = c.i + 0x7fffu + ((c.i >> 16) & 1u);   // RNE
  return (unsigned short)(r >> 16);
}

// ---- prep: W1t[n][k] bf16 = transpose of W1[k][n] fp32 (one-time, 32K elems) ----
__global__ __launch_bounds__(256) void k_prep(const float* __restrict__ W1,
    unsigned short* __restrict__ W1t) {
  int idx = blockIdx.x * 256 + threadIdx.x;   // 0..32767
  int nn = idx >> 7, k = idx & 127;
  W1t[idx] = f2b(W1[(size_t)k * F1 + nn]);
}

// ------- GEMM1 via MFMA: h1b[N,256](bf16) = bf16(x)[N,128] @ W1[128,256] -------
__global__ __launch_bounds__(256) void k_gemm1(const float* __restrict__ x,
    const unsigned short* __restrict__ W1t,
    const float* __restrict__ a1s_w, const float* __restrict__ a1d_w,
    unsigned short* __restrict__ h1b, float* __restrict__ as1,
    float* __restrict__ ad1, int n) {
  __shared__ unsigned short xs[64 * PADK];   // 17.4 KB
  __shared__ unsigned short ws[64 * PADK];   // 17.4 KB
  const int tid = threadIdx.x;
  const int rb = blockIdx.x * 64;
  const int head = blockIdx.y;
  const int cb = head * 64;

#pragma unroll
  for (int i = 0; i < 8; ++i) {
    int idx = tid + i * 256;
    int row = idx >> 5, c4 = idx & 31;
    float4 v = make_float4(0.f, 0.f, 0.f, 0.f);
    if (rb + row < n) v = *(const float4*)&x[(size_t)(rb + row) * IN_DIM + c4 * 4];
    ushort4 b; b.x = f2b(v.x); b.y = f2b(v.y); b.z = f2b(v.z); b.w = f2b(v.w);
    *(ushort4*)&xs[row * PADK + c4 * 4] = b;
  }
#pragma unroll
  for (int i = 0; i < 4; ++i) {
    int idx = tid + i * 256;
    int row = idx >> 4, c = idx & 15;
    *(uint4*)&ws[row * PADK + c * 8] =
        *(const uint4*)&W1t[(size_t)(cb + row) * IN_DIM + c * 8];
  }
  __syncthreads();

  const int wv = tid >> 6;
  const int lane = tid & 63;
  const int l15 = lane & 15, quad = lane >> 4;
  v4f acc0 = {0.f, 0.f, 0.f, 0.f}, acc1 = acc0, acc2 = acc0, acc3 = acc0;
#pragma unroll
  for (int kt = 0; kt < 4; ++kt) {
    const int ko = kt * 32 + quad * 8;
    short8 af = *(const short8*)&xs[(wv * 16 + l15) * PADK + ko];
    short8 b0 = *(const short8*)&ws[(l15) * PADK + ko];
    short8 b1 = *(const short8*)&ws[(16 + l15) * PADK + ko];
    short8 b2 = *(const short8*)&ws[(32 + l15) * PADK + ko];
    short8 b3 = *(const short8*)&ws[(48 + l15) * PADK + ko];
    acc0 = __builtin_amdgcn_mfma_f32_16x16x32_bf16(af, b0, acc0, 0, 0, 0);
    acc1 = __builtin_amdgcn_mfma_f32_16x16x32_bf16(af, b1, acc1, 0, 0, 0);
    acc2 = __builtin_amdgcn_mfma_f32_16x16x32_bf16(af, b2, acc2, 0, 0, 0);
    acc3 = __builtin_amdgcn_mfma_f32_16x16x32_bf16(af, b3, acc3, 0, 0, 0);
  }

  const float s0 = a1s_w[cb + l15],      s1 = a1s_w[cb + 16 + l15];
  const float s2 = a1s_w[cb + 32 + l15], s3 = a1s_w[cb + 48 + l15];
  const float d0 = a1d_w[cb + l15],      d1 = a1d_w[cb + 16 + l15];
  const float d2 = a1d_w[cb + 32 + l15], d3 = a1d_w[cb + 48 + l15];
#pragma unroll
  for (int r = 0; r < 4; ++r) {
    const int row = rb + wv * 16 + quad * 4 + r;
    const bool ok = row < n;
    if (ok) {
      size_t base = (size_t)row * F1 + cb;
      h1b[base + l15]      = f2b(acc0[r]);
      h1b[base + 16 + l15] = f2b(acc1[r]);
      h1b[base + 32 + l15] = f2b(acc2[r]);
      h1b[base + 48 + l15] = f2b(acc3[r]);
    }
    float ds = acc0[r] * s0 + acc1[r] * s1 + acc2[r] * s2 + acc3[r] * s3;
    float dd = acc0[r] * d0 + acc1[r] * d1 + acc2[r] * d2 + acc3[r] * d3;
#pragma unroll
    for (int m = 1; m <= 8; m <<= 1) {
      ds += __shfl_xor(ds, m, 64);
      dd += __shfl_xor(dd, m, 64);
    }
    if (ok && l15 == 0) {
      as1[(size_t)row * 4 + head] = ds;
      ad1[(size_t)row * 4 + head] = dd;
    }
  }
}

// ---------------- CSR build ----------------
__global__ __launch_bounds__(256) void k_hist(const int* __restrict__ adj,
    int* __restrict__ cnt, int E_, int n) {
  int e = blockIdx.x * 256 + threadIdx.x;
  int ET = E_ + n;
  if (e >= ET) return;
  int d = (e < E_) ? adj[E_ + e] : (e - E_);
  atomicAdd(&cnt[d], 1);
}

__global__ __launch_bounds__(256) void k_scan_local(const int* __restrict__ cnt,
    int* __restrict__ offs, int* __restrict__ bsum, int n) {
  __shared__ int wsums[4];
  const int tid = threadIdx.x;
  const int lane = tid & 63, w = tid >> 6;
  const int base = blockIdx.x * 1024;
  const int i0 = base + tid * 4;
  int v[4];
#pragma unroll
  for (int k = 0; k < 4; ++k) { int i = i0 + k; v[k] = (i < n) ? cnt[i] : 0; }
  int tsum = v[0] + v[1] + v[2] + v[3];
  int incl = tsum;
#pragma unroll
  for (int d = 1; d < 64; d <<= 1) {
    int t = __shfl_up(incl, (unsigned)d, 64);
    if (lane >= d) incl += t;
  }
  if (lane == 63) wsums[w] = incl;
  __syncthreads();
  int pre = 0;
  for (int k = 0; k < w; ++k) pre += wsums[k];
  int run = pre + incl - tsum;
#pragma unroll
  for (int k = 0; k < 4; ++k) { int i = i0 + k; if (i < n) offs[i] = run; run += v[k]; }
  if (tid == 255) bsum[blockIdx.x] = pre + incl;
}

__global__ void k_scan_bsum(int* __restrict__ bsum, int nb, int* __restrict__ offs_n) {
  int lane = threadIdx.x;   // 64 threads
  int carry = 0;
  for (int base = 0; base < nb; base += 64) {
    int i = base + lane;
    int v = (i < nb) ? bsum[i] : 0;
    int incl = v;
#pragma unroll
    for (int d = 1; d < 64; d <<= 1) {
      int t = __shfl_up(incl, (unsigned)d, 64);
      if (lane >= d) incl += t;
    }
    if (i < nb) bsum[i] = carry + incl - v;
    int tot = __shfl(incl, 63, 64);
    carry += tot;
  }
  if (lane == 0) *offs_n = carry;
}

__global__ __launch_bounds__(256) void k_scan_add(int* __restrict__ offs,
    const int* __restrict__ bsum, int* __restrict__ cursor, int n) {
  int i = blockIdx.x * 256 + threadIdx.x;
  if (i < n) {
    int v = offs[i] + bsum[i >> 10];
    offs[i] = v;
    cursor[i] = v;
  }
}

// -------- scatter + FUSED edge attention weights (layer 1) --------
// Thread-per-edge: full parallelism for the 4 exps (they were computed with
// 16x lane redundancy inside k_agg1's serial edge loop — the R7 VALU fat).
// Bitwise-identical math/order to the old in-loop computation.
__global__ __launch_bounds__(256) void k_scatter(const int* __restrict__ adj,
    const float* __restrict__ as1, const float* __restrict__ ad1,
    int* __restrict__ cursor, int* __restrict__ csr_src,
    float* __restrict__ csr_w, int E_, int n) {
  int e = blockIdx.x * 256 + threadIdx.x;
  int ET = E_ + n;
  if (e >= ET) return;
  int s, d;
  if (e < E_) { s = adj[e]; d = adj[E_ + e]; } else { s = d = e - E_; }
  int pos = atomicAdd(&cursor[d], 1);
  csr_src[pos] = s;
  const float4 qs = *(const float4*)(as1 + (size_t)s * 4);
  const float4 qd = *(const float4*)(ad1 + (size_t)d * 4);
  float4 w;
  float ev;
  ev = qs.x + qd.x; ev = (ev >= 0.f) ? ev : NEG * ev; w.x = __expf(ev);
  ev = qs.y + qd.y; ev = (ev >= 0.f) ? ev : NEG * ev; w.y = __expf(ev);
  ev = qs.z + qd.z; ev = (ev >= 0.f) ? ev : NEG * ev; w.z = __expf(ev);
  ev = qs.w + qd.w; ev = (ev >= 0.f) ? ev : NEG * ev; w.w = __expf(ev);
  *(float4*)(csr_w + (size_t)pos * 4) = w;
}

// ---------------- fused GAT layer 1 (bf16 gather, precomputed weights) ----------------
// lane l: head h=l>>4, features 4(l&15)..+3. Per edge: 1 broadcast w load +
// 1 uint2 gather + den add + 4 unpack-FMAs. relu1 stored bf16 (write halved).
__global__ __launch_bounds__(256) void k_agg1(const unsigned short* __restrict__ h1b,
    const int* __restrict__ offs, const int* __restrict__ csr_src,
    const float* __restrict__ csr_w, const float* __restrict__ b1,
    unsigned short* __restrict__ relu1b, int n) {
  int node = blockIdx.x * 4 + (threadIdx.x >> 6);
  int lane = threadIdx.x & 63;
  if (node >= n) return;
  const int h = lane >> 4;
  const int j0 = offs[node], j1 = offs[node + 1];
  float a0 = 0.f, a1 = 0.f, a2 = 0.f, a3 = 0.f, den = 0.f;
  int j = j0;
  for (; j + 4 <= j1; j += 4) {
    const int s0 = csr_src[j + 0], s1 = csr_src[j + 1];
    const int s2 = csr_src[j + 2], s3 = csr_src[j + 3];
    const float w0 = csr_w[(size_t)(j + 0) * 4 + h];
    const float w1 = csr_w[(size_t)(j + 1) * 4 + h];
    const float w2 = csr_w[(size_t)(j + 2) * 4 + h];
    const float w3 = csr_w[(size_t)(j + 3) * 4 + h];
    const uint2 u0 = ((const uint2*)(h1b + (size_t)s0 * F1))[lane];
    const uint2 u1 = ((const uint2*)(h1b + (size_t)s1 * F1))[lane];
    const uint2 u2 = ((const uint2*)(h1b + (size_t)s2 * F1))[lane];
    const uint2 u3 = ((const uint2*)(h1b + (size_t)s3 * F1))[lane];
    den += w0; a0 += w0 * b2fl(u0.x); a1 += w0 * b2fh(u0.x); a2 += w0 * b2fl(u0.y); a3 += w0 * b2fh(u0.y);
    den += w1; a0 += w1 * b2fl(u1.x); a1 += w1 * b2fh(u1.x); a2 += w1 * b2fl(u1.y); a3 += w1 * b2fh(u1.y);
    den += w2; a0 += w2 * b2fl(u2.x); a1 += w2 * b2fh(u2.x); a2 += w2 * b2fl(u2.y); a3 += w2 * b2fh(u2.y);
    den += w3; a0 += w3 * b2fl(u3.x); a1 += w3 * b2fh(u3.x); a2 += w3 * b2fl(u3.y); a3 += w3 * b2fh(u3.y);
  }
  for (; j < j1; ++j) {
    const int s = csr_src[j];
    const float w = csr_w[(size_t)j * 4 + h];
    const uint2 u = ((const uint2*)(h1b + (size_t)s * F1))[lane];
    den += w; a0 += w * b2fl(u.x); a1 += w * b2fh(u.x); a2 += w * b2fl(u.y); a3 += w * b2fh(u.y);
  }
  const float inv = 1.0f / den;
  const float4 bb = ((const float4*)b1)[lane];
  ushort4 rv;
  rv.x = f2b(fmaxf(a0 * inv + bb.x, 0.f));
  rv.y = f2b(fmaxf(a1 * inv + bb.y, 0.f));
  rv.z = f2b(fmaxf(a2 * inv + bb.z, 0.f));
  rv.w = f2b(fmaxf(a3 * inv + bb.w, 0.f));
  *(ushort4*)&relu1b[(size_t)node * F1 + 4 * lane] = rv;
}

// ---------------- GEMM2 (register-tiled; bf16 relu1 input) ----------------
__global__ __launch_bounds__(256) void k_gemm2(const unsigned short* __restrict__ relu1b,
    const float* __restrict__ W2, const float* __restrict__ a2s_w,
    const float* __restrict__ a2d_w, unsigned short* __restrict__ h2b,
    float* __restrict__ as2, float* __restrict__ ad2, int n) {
  __shared__ float w2s[F1 * OUT_DIM];  // 32 KB
  __shared__ float xs[32][72];         // [k][row], 2-way bank alias = free
  const int tid = threadIdx.x;
  const int rb = blockIdx.x * 64;
  for (int i = tid; i < F1 * OUT_DIM; i += 256) w2s[i] = W2[i];
  const int rx = tid >> 3;       // 0..31 -> rows rx, rx+32
  const int cq = tid & 7;        // 0..7  -> cols 4cq..4cq+3
  float accA[4] = {0.f, 0.f, 0.f, 0.f};
  float accB[4] = {0.f, 0.f, 0.f, 0.f};
  for (int kb = 0; kb < F1; kb += 32) {
    __syncthreads();
#pragma unroll
    for (int i = 0; i < 2; ++i) {
      int idx = tid + i * 256;            // 0..511
      int r = idx >> 3, c4 = idx & 7;     // row 0..63, uint2 group (4 k-vals)
      int row = rb + r;
      uint2 u = make_uint2(0u, 0u);
      if (row < n) u = *(const uint2*)&relu1b[(size_t)row * F1 + kb + c4 * 4];
      xs[c4 * 4 + 0][r] = b2fl(u.x); xs[c4 * 4 + 1][r] = b2fh(u.x);
      xs[c4 * 4 + 2][r] = b2fl(u.y); xs[c4 * 4 + 3][r] = b2fh(u.y);
    }
    __syncthreads();
#pragma unroll
    for (int kk = 0; kk < 32; ++kk) {
      const float xa = xs[kk][rx];
      const float xb = xs[kk][rx + 32];
      const float4 wv = *(const float4*)&w2s[(kb + kk) * OUT_DIM + 4 * cq];
      accA[0] += xa * wv.x; accA[1] += xa * wv.y; accA[2] += xa * wv.z; accA[3] += xa * wv.w;
      accB[0] += xb * wv.x; accB[1] += xb * wv.y; accB[2] += xb * wv.z; accB[3] += xb * wv.w;
    }
  }
  const float4 sv = *(const float4*)&a2s_w[4 * cq];
  const float4 dv = *(const float4*)&a2d_w[4 * cq];
  const int rA = rb + rx, rB = rb + rx + 32;
  if (rA < n) {
    ushort4 v; v.x = f2b(accA[0]); v.y = f2b(accA[1]); v.z = f2b(accA[2]); v.w = f2b(accA[3]);
    *(ushort4*)&h2b[(size_t)rA * OUT_DIM + 4 * cq] = v;
  }
  if (rB < n) {
    ushort4 v; v.x = f2b(accB[0]); v.y = f2b(accB[1]); v.z = f2b(accB[2]); v.w = f2b(accB[3]);
    *(ushort4*)&h2b[(size_t)rB * OUT_DIM + 4 * cq] = v;
  }
  float ssA = accA[0] * sv.x + accA[1] * sv.y + accA[2] * sv.z + accA[3] * sv.w;
  float sdA = accA[0] * dv.x + accA[1] * dv.y + accA[2] * dv.z + accA[3] * dv.w;
  float ssB = accB[0] * sv.x + accB[1] * sv.y + accB[2] * sv.z + accB[3] * sv.w;
  float sdB = accB[0] * dv.x + accB[1] * dv.y + accB[2] * dv.z + accB[3] * dv.w;
#pragma unroll
  for (int m = 1; m <= 4; m <<= 1) {
    ssA += __shfl_xor(ssA, m, 64);
    sdA += __shfl_xor(sdA, m, 64);
    ssB += __shfl_xor(ssB, m, 64);
    sdB += __shfl_xor(sdB, m, 64);
  }
  if (cq == 0) {
    if (rA < n) { as2[rA] = ssA; ad2[rA] = sdA; }
    if (rB < n) { as2[rB] = ssB; ad2[rB] = sdB; }
  }
}

// -------- fused GAT layer 2 (bf16 gather, quarter-wave per edge) --------
__global__ __launch_bounds__(256) void k_agg2(const unsigned short* __restrict__ h2b,
    const float* __restrict__ as2, const float* __restrict__ ad2,
    const int* __restrict__ offs, const int* __restrict__ csr_src,
    const float* __restrict__ b2, const float* __restrict__ linW,
    float* __restrict__ score, int n) {
  int node = blockIdx.x * 4 + (threadIdx.x >> 6);
  int lane = threadIdx.x & 63;
  if (node >= n) return;
  const int sub = lane >> 4;
  const int p = lane & 15;
  const int j0 = offs[node], j1 = offs[node + 1];
  const float adv = ad2[node];
  float acc0 = 0.f, acc1 = 0.f, den = 0.f;
  int jj = j0;
  for (; jj + 8 <= j1; jj += 8) {
    const int sA = csr_src[jj + sub];
    const int sB = csr_src[jj + 4 + sub];
    const float aA = as2[sA], aB = as2[sB];
    const unsigned uA = ((const unsigned*)(h2b + (size_t)sA * OUT_DIM))[p];
    const unsigned uB = ((const unsigned*)(h2b + (size_t)sB * OUT_DIM))[p];
    float e, w;
    e = aA + adv; e = (e >= 0.f) ? e : NEG * e; w = __expf(e);
    den += w; acc0 += w * b2fl(uA); acc1 += w * b2fh(uA);
    e = aB + adv; e = (e >= 0.f) ? e : NEG * e; w = __expf(e);
    den += w; acc0 += w * b2fl(uB); acc1 += w * b2fh(uB);
  }
  for (; jj < j1; jj += 4) {
    const int idx = jj + sub;
    const bool valid = idx < j1;
    const int s = valid ? csr_src[idx] : csr_src[j1 - 1];
    const float a = as2[s];
    const unsigned u = ((const unsigned*)(h2b + (size_t)s * OUT_DIM))[p];
    float e = a + adv; e = (e >= 0.f) ? e : NEG * e;
    float w = valid ? __expf(e) : 0.f;
    den += w; acc0 += w * b2fl(u); acc1 += w * b2fh(u);
  }
  den  += __shfl_xor(den, 16, 64);  den  += __shfl_xor(den, 32, 64);
  acc0 += __shfl_xor(acc0, 16, 64); acc0 += __shfl_xor(acc0, 32, 64);
  acc1 += __shfl_xor(acc1, 16, 64); acc1 += __shfl_xor(acc1, 32, 64);
  const float inv = 1.0f / den;
  float o0 = acc0 * inv + b2[2 * p];
  float o1 = acc1 * inv + b2[2 * p + 1];
  float m = fmaxf(o0, o1);
#pragma unroll
  for (int mm = 1; mm <= 8; mm <<= 1) m = fmaxf(m, __shfl_xor(m, mm, 64));
  float ssum = __expf(o0 - m) + __expf(o1 - m);
#pragma unroll
  for (int mm = 1; mm <= 8; mm <<= 1) ssum += __shfl_xor(ssum, mm, 64);
  const float lse = m + __logf(ssum);
  float sc = (o0 - lse) * linW[2 * p] + (o1 - lse) * linW[2 * p + 1];
#pragma unroll
  for (int mm = 1; mm <= 8; mm <<= 1) sc += __shfl_xor(sc, mm, 64);
  if (lane == 0) score[node] = sc;
}

// -------- pooling: LDS per-graph partials, few global atomics per block --------
__global__ __launch_bounds__(256) void k_pool(const float* __restrict__ score,
    const int* __restrict__ batch, float* __restrict__ gsum,
    float* __restrict__ gcnt, int n) {
  __shared__ float ps[64];
  __shared__ float pc[64];
  const int tid = threadIdx.x;
  if (tid < 64) { ps[tid] = 0.f; pc[tid] = 0.f; }
  __syncthreads();
  int i = blockIdx.x * 256 + tid;
  if (i < n) {
    int g = batch[i];
    atomicAdd(&ps[g], score[i]);
    atomicAdd(&pc[g], 1.0f);
  }
  __syncthreads();
  if (tid < 64 && pc[tid] != 0.f) {
    atomicAdd(&gsum[tid], ps[tid]);
    atomicAdd(&gcnt[tid], pc[tid]);
  }
}

__global__ void k_final(const float* __restrict__ gsum, const float* __restrict__ gcnt,
                        const float* __restrict__ linb, float* __restrict__ out, int g_) {
  int g = threadIdx.x;
  if (g < g_) out[g] = gsum[g] / fmaxf(gcnt[g], 1.0f) + linb[0];
}

extern "C" void kernel_launch(void* const* d_in, const int* in_sizes, int n_in,
                              void* d_out, int out_size, void* d_ws, size_t ws_size,
                              hipStream_t stream) {
  const float* x    = (const float*)d_in[0];
  const int*   adj  = (const int*)d_in[1];
  const int*   batch= (const int*)d_in[2];
  const float* W1   = (const float*)d_in[3];
  const float* a1s  = (const float*)d_in[4];
  const float* a1d  = (const float*)d_in[5];
  const float* b1   = (const float*)d_in[6];
  const float* W2   = (const float*)d_in[7];
  const float* a2s  = (const float*)d_in[8];
  const float* a2d  = (const float*)d_in[9];
  const float* b2   = (const float*)d_in[10];
  const float* linW = (const float*)d_in[11];
  const float* linb = (const float*)d_in[12];

  const int N = in_sizes[0] / IN_DIM;
  const int E = in_sizes[1] / 2;
  const int ET = E + N;
  const int G = out_size;   // 64
  const int NB = (N + 1023) / 1024;

  char* wsb = (char*)d_ws;
  size_t off = 0;
  auto take = [&](size_t bytes) -> char* {
    char* p = wsb + off;
    off += (bytes + 255) & ~(size_t)255;
    return p;
  };
  unsigned short* h1b   = (unsigned short*)take((size_t)N * F1 * 2);
  unsigned short* relu1b= (unsigned short*)take((size_t)N * F1 * 2);
  float* as1    = (float*)take((size_t)N * 4 * 4);
  float* ad1    = (float*)take((size_t)N * 4 * 4);
  unsigned short* h2b = (unsigned short*)take((size_t)N * OUT_DIM * 2);
  float* as2v   = (float*)take((size_t)N * 4);
  float* ad2v   = (float*)take((size_t)N * 4);
  float* score  = (float*)take((size_t)N * 4);
  int*   cnt    = (int*)take((size_t)N * 4);
  int*   offs   = (int*)take((size_t)(N + 1) * 4);
  int*   cursor = (int*)take((size_t)N * 4);
  int*   csr_src= (int*)take((size_t)ET * 4);
  float* csr_w  = (float*)take((size_t)ET * 4 * 4);
  int*   bsum   = (int*)take((size_t)(NB + 1) * 4);
  float* gsum   = (float*)take((size_t)G * 4);
  float* gcnt   = (float*)take((size_t)G * 4);
  unsigned short* W1t = (unsigned short*)take((size_t)IN_DIM * F1 * 2);
  (void)ws_size; (void)n_in;

  hipMemsetAsync(cnt, 0, (size_t)N * 4, stream);
  hipMemsetAsync(gsum, 0, (size_t)G * 4, stream);
  hipMemsetAsync(gcnt, 0, (size_t)G * 4, stream);

  dim3 b256(256);
  k_prep<<<dim3((IN_DIM * F1) / 256), b256, 0, stream>>>(W1, W1t);
  k_gemm1<<<dim3((N + 63) / 64, F1 / 64), b256, 0, stream>>>(x, W1t, a1s, a1d, h1b, as1, ad1, N);
  k_hist<<<dim3((ET + 255) / 256), b256, 0, stream>>>(adj, cnt, E, N);
  k_scan_local<<<dim3(NB), b256, 0, stream>>>(cnt, offs, bsum, N);
  k_scan_bsum<<<1, 64, 0, stream>>>(bsum, NB, offs + N);
  k_scan_add<<<dim3((N + 255) / 256), b256, 0, stream>>>(offs, bsum, cursor, N);
  k_scatter<<<dim3((ET + 255) / 256), b256, 0, stream>>>(adj, as1, ad1, cursor, csr_src, csr_w, E, N);
  k_agg1<<<dim3((N + 3) / 4), b256, 0, stream>>>(h1b, offs, csr_src, csr_w, b1, relu1b, N);
  k_gemm2<<<dim3((N + 63) / 64), b256, 0, stream>>>(relu1b, W2, a2s, a2d, h2b, as2v, ad2v, N);
  k_agg2<<<dim3((N + 3) / 4), b256, 0, stream>>>(h2b, as2v, ad2v, offs, csr_src, b2, linW, score, N);
  k_pool<<<dim3((N + 255) / 256), b256, 0, stream>>>(score, batch, gsum, gcnt, N);
  k_final<<<1, 64, 0, stream>>>(gsum, gcnt, linb, (float*)d_out, G);
}

// Round 9
// 317.056 us; speedup vs baseline: 2.9303x; 1.0492x over previous
//
#include <hip/hip_runtime.h>

#define IN_DIM 128
#define F1 256      // HEADS*HID = 4*64
#define HID 64
#define OUT_DIM 32
#define NEG 0.2f
#define PADK 136    // LDS row pitch in bf16 elems (128 + 8): frag reads 2-way alias = free

typedef __attribute__((ext_vector_type(8))) short short8;
typedef __attribute__((ext_vector_type(4))) float v4f;
typedef __attribute__((ext_vector_type(2))) float v2f;

// ---- bf16 helpers ----
__device__ __forceinline__ float b2fl(unsigned u) {
  union { unsigned i; float f; } c; c.i = u << 16; return c.f;
}
__device__ __forceinline__ float b2fh(unsigned u) {
  union { unsigned i; float f; } c; c.i = u & 0xffff0000u; return c.f;
}
__device__ __forceinline__ unsigned short f2b(float f) {
  union { float f; unsigned i; } c; c.f = f;
  unsigned r = c.i + 0x7fffu + ((c.i >> 16) & 1u);   // RNE
  return (unsigned short)(r >> 16);
}

// ---- prep: W1t[n][k] bf16 = transpose of W1[k][n] fp32 (one-time, 32K elems) ----
__global__ __launch_bounds__(256) void k_prep(const float* __restrict__ W1,
    unsigned short* __restrict__ W1t) {
  int idx = blockIdx.x * 256 + threadIdx.x;   // 0..32767
  int nn = idx >> 7, k = idx & 127;
  W1t[idx] = f2b(W1[(size_t)k * F1 + nn]);
}

// ------- GEMM1 via MFMA: h1f8[N,256](fp8 e4m3) = bf16(x)[N,128] @ W1[128,256] -------
// h1 payload stored fp8 (R9): halves the k_agg1 gather bytes; as1/ad1 dots stay fp32.
__global__ __launch_bounds__(256) void k_gemm1(const float* __restrict__ x,
    const unsigned short* __restrict__ W1t,
    const float* __restrict__ a1s_w, const float* __restrict__ a1d_w,
    unsigned char* __restrict__ h1f8, float* __restrict__ as1,
    float* __restrict__ ad1, int n) {
  __shared__ unsigned short xs[64 * PADK];   // 17.4 KB
  __shared__ unsigned short ws[64 * PADK];   // 17.4 KB
  const int tid = threadIdx.x;
  const int rb = blockIdx.x * 64;
  const int head = blockIdx.y;
  const int cb = head * 64;

#pragma unroll
  for (int i = 0; i < 8; ++i) {
    int idx = tid + i * 256;
    int row = idx >> 5, c4 = idx & 31;
    float4 v = make_float4(0.f, 0.f, 0.f, 0.f);
    if (rb + row < n) v = *(const float4*)&x[(size_t)(rb + row) * IN_DIM + c4 * 4];
    ushort4 b; b.x = f2b(v.x); b.y = f2b(v.y); b.z = f2b(v.z); b.w = f2b(v.w);
    *(ushort4*)&xs[row * PADK + c4 * 4] = b;
  }
#pragma unroll
  for (int i = 0; i < 4; ++i) {
    int idx = tid + i * 256;
    int row = idx >> 4, c = idx & 15;
    *(uint4*)&ws[row * PADK + c * 8] =
        *(const uint4*)&W1t[(size_t)(cb + row) * IN_DIM + c * 8];
  }
  __syncthreads();

  const int wv = tid >> 6;
  const int lane = tid & 63;
  const int l15 = lane & 15, quad = lane >> 4;
  v4f acc0 = {0.f, 0.f, 0.f, 0.f}, acc1 = acc0, acc2 = acc0, acc3 = acc0;
#pragma unroll
  for (int kt = 0; kt < 4; ++kt) {
    const int ko = kt * 32 + quad * 8;
    short8 af = *(const short8*)&xs[(wv * 16 + l15) * PADK + ko];
    short8 b0 = *(const short8*)&ws[(l15) * PADK + ko];
    short8 b1 = *(const short8*)&ws[(16 + l15) * PADK + ko];
    short8 b2 = *(const short8*)&ws[(32 + l15) * PADK + ko];
    short8 b3 = *(const short8*)&ws[(48 + l15) * PADK + ko];
    acc0 = __builtin_amdgcn_mfma_f32_16x16x32_bf16(af, b0, acc0, 0, 0, 0);
    acc1 = __builtin_amdgcn_mfma_f32_16x16x32_bf16(af, b1, acc1, 0, 0, 0);
    acc2 = __builtin_amdgcn_mfma_f32_16x16x32_bf16(af, b2, acc2, 0, 0, 0);
    acc3 = __builtin_amdgcn_mfma_f32_16x16x32_bf16(af, b3, acc3, 0, 0, 0);
  }

  const float s0 = a1s_w[cb + l15],      s1 = a1s_w[cb + 16 + l15];
  const float s2 = a1s_w[cb + 32 + l15], s3 = a1s_w[cb + 48 + l15];
  const float d0 = a1d_w[cb + l15],      d1 = a1d_w[cb + 16 + l15];
  const float d2 = a1d_w[cb + 32 + l15], d3 = a1d_w[cb + 48 + l15];
#pragma unroll
  for (int r = 0; r < 4; ++r) {
    const int row = rb + wv * 16 + quad * 4 + r;
    const bool ok = row < n;
    if (ok) {
      size_t base = (size_t)row * F1 + cb;
      // pack pairs: byte0=acc0, byte1=acc1 / byte0=acc2, byte1=acc3 (HW RNE)
      int pA = __builtin_amdgcn_cvt_pk_fp8_f32(acc0[r], acc1[r], 0, false);
      int pB = __builtin_amdgcn_cvt_pk_fp8_f32(acc2[r], acc3[r], 0, false);
      h1f8[base + l15]      = (unsigned char)(pA & 0xff);
      h1f8[base + 16 + l15] = (unsigned char)((pA >> 8) & 0xff);
      h1f8[base + 32 + l15] = (unsigned char)(pB & 0xff);
      h1f8[base + 48 + l15] = (unsigned char)((pB >> 8) & 0xff);
    }
    float ds = acc0[r] * s0 + acc1[r] * s1 + acc2[r] * s2 + acc3[r] * s3;
    float dd = acc0[r] * d0 + acc1[r] * d1 + acc2[r] * d2 + acc3[r] * d3;
#pragma unroll
    for (int m = 1; m <= 8; m <<= 1) {
      ds += __shfl_xor(ds, m, 64);
      dd += __shfl_xor(dd, m, 64);
    }
    if (ok && l15 == 0) {
      as1[(size_t)row * 4 + head] = ds;
      ad1[(size_t)row * 4 + head] = dd;
    }
  }
}

// ---------------- CSR build ----------------
__global__ __launch_bounds__(256) void k_hist(const int* __restrict__ adj,
    int* __restrict__ cnt, int E_, int n) {
  int e = blockIdx.x * 256 + threadIdx.x;
  int ET = E_ + n;
  if (e >= ET) return;
  int d = (e < E_) ? adj[E_ + e] : (e - E_);
  atomicAdd(&cnt[d], 1);
}

__global__ __launch_bounds__(256) void k_scan_local(const int* __restrict__ cnt,
    int* __restrict__ offs, int* __restrict__ bsum, int n) {
  __shared__ int wsums[4];
  const int tid = threadIdx.x;
  const int lane = tid & 63, w = tid >> 6;
  const int base = blockIdx.x * 1024;
  const int i0 = base + tid * 4;
  int v[4];
#pragma unroll
  for (int k = 0; k < 4; ++k) { int i = i0 + k; v[k] = (i < n) ? cnt[i] : 0; }
  int tsum = v[0] + v[1] + v[2] + v[3];
  int incl = tsum;
#pragma unroll
  for (int d = 1; d < 64; d <<= 1) {
    int t = __shfl_up(incl, (unsigned)d, 64);
    if (lane >= d) incl += t;
  }
  if (lane == 63) wsums[w] = incl;
  __syncthreads();
  int pre = 0;
  for (int k = 0; k < w; ++k) pre += wsums[k];
  int run = pre + incl - tsum;
#pragma unroll
  for (int k = 0; k < 4; ++k) { int i = i0 + k; if (i < n) offs[i] = run; run += v[k]; }
  if (tid == 255) bsum[blockIdx.x] = pre + incl;
}

__global__ void k_scan_bsum(int* __restrict__ bsum, int nb, int* __restrict__ offs_n) {
  int lane = threadIdx.x;   // 64 threads
  int carry = 0;
  for (int base = 0; base < nb; base += 64) {
    int i = base + lane;
    int v = (i < nb) ? bsum[i] : 0;
    int incl = v;
#pragma unroll
    for (int d = 1; d < 64; d <<= 1) {
      int t = __shfl_up(incl, (unsigned)d, 64);
      if (lane >= d) incl += t;
    }
    if (i < nb) bsum[i] = carry + incl - v;
    int tot = __shfl(incl, 63, 64);
    carry += tot;
  }
  if (lane == 0) *offs_n = carry;
}

__global__ __launch_bounds__(256) void k_scan_add(int* __restrict__ offs,
    const int* __restrict__ bsum, int* __restrict__ cursor, int n) {
  int i = blockIdx.x * 256 + threadIdx.x;
  if (i < n) {
    int v = offs[i] + bsum[i >> 10];
    offs[i] = v;
    cursor[i] = v;
  }
}

// -------- scatter + fused edge attention weights (layer 1) --------
__global__ __launch_bounds__(256) void k_scatter(const int* __restrict__ adj,
    const float* __restrict__ as1, const float* __restrict__ ad1,
    int* __restrict__ cursor, int* __restrict__ csr_src,
    float* __restrict__ csr_w, int E_, int n) {
  int e = blockIdx.x * 256 + threadIdx.x;
  int ET = E_ + n;
  if (e >= ET) return;
  int s, d;
  if (e < E_) { s = adj[e]; d = adj[E_ + e]; } else { s = d = e - E_; }
  int pos = atomicAdd(&cursor[d], 1);
  csr_src[pos] = s;
  const float4 qs = *(const float4*)(as1 + (size_t)s * 4);
  const float4 qd = *(const float4*)(ad1 + (size_t)d * 4);
  float4 w;
  float ev;
  ev = qs.x + qd.x; ev = (ev >= 0.f) ? ev : NEG * ev; w.x = __expf(ev);
  ev = qs.y + qd.y; ev = (ev >= 0.f) ? ev : NEG * ev; w.y = __expf(ev);
  ev = qs.z + qd.z; ev = (ev >= 0.f) ? ev : NEG * ev; w.z = __expf(ev);
  ev = qs.w + qd.w; ev = (ev >= 0.f) ? ev : NEG * ev; w.w = __expf(ev);
  *(float4*)(csr_w + (size_t)pos * 4) = w;
}

// ---------------- fused GAT layer 1 (fp8 gather, precomputed weights) ----------------
// lane l: head h=l>>4, features 4(l&15)..+3 — one dword = 4 fp8, whole 256B row/wave.
// Unpack via HW v_cvt_pk_f32_fp8 (2 instrs per 4 feats, cheaper than bf16 shift/mask).
__global__ __launch_bounds__(256) void k_agg1(const unsigned char* __restrict__ h1f8,
    const int* __restrict__ offs, const int* __restrict__ csr_src,
    const float* __restrict__ csr_w, const float* __restrict__ b1,
    unsigned short* __restrict__ relu1b, int n) {
  int node = blockIdx.x * 4 + (threadIdx.x >> 6);
  int lane = threadIdx.x & 63;
  if (node >= n) return;
  const int h = lane >> 4;
  const int j0 = offs[node], j1 = offs[node + 1];
  float a0 = 0.f, a1 = 0.f, a2 = 0.f, a3 = 0.f, den = 0.f;
  int j = j0;
  for (; j + 4 <= j1; j += 4) {
    const int s0 = csr_src[j + 0], s1 = csr_src[j + 1];
    const int s2 = csr_src[j + 2], s3 = csr_src[j + 3];
    const float w0 = csr_w[(size_t)(j + 0) * 4 + h];
    const float w1 = csr_w[(size_t)(j + 1) * 4 + h];
    const float w2 = csr_w[(size_t)(j + 2) * 4 + h];
    const float w3 = csr_w[(size_t)(j + 3) * 4 + h];
    const int u0 = ((const int*)(h1f8 + (size_t)s0 * F1))[lane];
    const int u1 = ((const int*)(h1f8 + (size_t)s1 * F1))[lane];
    const int u2 = ((const int*)(h1f8 + (size_t)s2 * F1))[lane];
    const int u3 = ((const int*)(h1f8 + (size_t)s3 * F1))[lane];
    v2f lo, hi;
    lo = __builtin_amdgcn_cvt_pk_f32_fp8(u0, false); hi = __builtin_amdgcn_cvt_pk_f32_fp8(u0, true);
    den += w0; a0 += w0 * lo.x; a1 += w0 * lo.y; a2 += w0 * hi.x; a3 += w0 * hi.y;
    lo = __builtin_amdgcn_cvt_pk_f32_fp8(u1, false); hi = __builtin_amdgcn_cvt_pk_f32_fp8(u1, true);
    den += w1; a0 += w1 * lo.x; a1 += w1 * lo.y; a2 += w1 * hi.x; a3 += w1 * hi.y;
    lo = __builtin_amdgcn_cvt_pk_f32_fp8(u2, false); hi = __builtin_amdgcn_cvt_pk_f32_fp8(u2, true);
    den += w2; a0 += w2 * lo.x; a1 += w2 * lo.y; a2 += w2 * hi.x; a3 += w2 * hi.y;
    lo = __builtin_amdgcn_cvt_pk_f32_fp8(u3, false); hi = __builtin_amdgcn_cvt_pk_f32_fp8(u3, true);
    den += w3; a0 += w3 * lo.x; a1 += w3 * lo.y; a2 += w3 * hi.x; a3 += w3 * hi.y;
  }
  for (; j < j1; ++j) {
    const int s = csr_src[j];
    const float w = csr_w[(size_t)j * 4 + h];
    const int u = ((const int*)(h1f8 + (size_t)s * F1))[lane];
    v2f lo = __builtin_amdgcn_cvt_pk_f32_fp8(u, false);
    v2f hi = __builtin_amdgcn_cvt_pk_f32_fp8(u, true);
    den += w; a0 += w * lo.x; a1 += w * lo.y; a2 += w * hi.x; a3 += w * hi.y;
  }
  const float inv = 1.0f / den;
  const float4 bb = ((const float4*)b1)[lane];
  ushort4 rv;
  rv.x = f2b(fmaxf(a0 * inv + bb.x, 0.f));
  rv.y = f2b(fmaxf(a1 * inv + bb.y, 0.f));
  rv.z = f2b(fmaxf(a2 * inv + bb.z, 0.f));
  rv.w = f2b(fmaxf(a3 * inv + bb.w, 0.f));
  *(ushort4*)&relu1b[(size_t)node * F1 + 4 * lane] = rv;
}

// ---------------- GEMM2 (register-tiled; bf16 relu1 input) ----------------
__global__ __launch_bounds__(256) void k_gemm2(const unsigned short* __restrict__ relu1b,
    const float* __restrict__ W2, const float* __restrict__ a2s_w,
    const float* __restrict__ a2d_w, unsigned short* __restrict__ h2b,
    float* __restrict__ as2, float* __restrict__ ad2, int n) {
  __shared__ float w2s[F1 * OUT_DIM];  // 32 KB
  __shared__ float xs[32][72];         // [k][row], 2-way bank alias = free
  const int tid = threadIdx.x;
  const int rb = blockIdx.x * 64;
  for (int i = tid; i < F1 * OUT_DIM; i += 256) w2s[i] = W2[i];
  const int rx = tid >> 3;       // 0..31 -> rows rx, rx+32
  const int cq = tid & 7;        // 0..7  -> cols 4cq..4cq+3
  float accA[4] = {0.f, 0.f, 0.f, 0.f};
  float accB[4] = {0.f, 0.f, 0.f, 0.f};
  for (int kb = 0; kb < F1; kb += 32) {
    __syncthreads();
#pragma unroll
    for (int i = 0; i < 2; ++i) {
      int idx = tid + i * 256;            // 0..511
      int r = idx >> 3, c4 = idx & 7;     // row 0..63, uint2 group (4 k-vals)
      int row = rb + r;
      uint2 u = make_uint2(0u, 0u);
      if (row < n) u = *(const uint2*)&relu1b[(size_t)row * F1 + kb + c4 * 4];
      xs[c4 * 4 + 0][r] = b2fl(u.x); xs[c4 * 4 + 1][r] = b2fh(u.x);
      xs[c4 * 4 + 2][r] = b2fl(u.y); xs[c4 * 4 + 3][r] = b2fh(u.y);
    }
    __syncthreads();
#pragma unroll
    for (int kk = 0; kk < 32; ++kk) {
      const float xa = xs[kk][rx];
      const float xb = xs[kk][rx + 32];
      const float4 wv = *(const float4*)&w2s[(kb + kk) * OUT_DIM + 4 * cq];
      accA[0] += xa * wv.x; accA[1] += xa * wv.y; accA[2] += xa * wv.z; accA[3] += xa * wv.w;
      accB[0] += xb * wv.x; accB[1] += xb * wv.y; accB[2] += xb * wv.z; accB[3] += xb * wv.w;
    }
  }
  const float4 sv = *(const float4*)&a2s_w[4 * cq];
  const float4 dv = *(const float4*)&a2d_w[4 * cq];
  const int rA = rb + rx, rB = rb + rx + 32;
  if (rA < n) {
    ushort4 v; v.x = f2b(accA[0]); v.y = f2b(accA[1]); v.z = f2b(accA[2]); v.w = f2b(accA[3]);
    *(ushort4*)&h2b[(size_t)rA * OUT_DIM + 4 * cq] = v;
  }
  if (rB < n) {
    ushort4 v; v.x = f2b(accB[0]); v.y = f2b(accB[1]); v.z = f2b(accB[2]); v.w = f2b(accB[3]);
    *(ushort4*)&h2b[(size_t)rB * OUT_DIM + 4 * cq] = v;
  }
  float ssA = accA[0] * sv.x + accA[1] * sv.y + accA[2] * sv.z + accA[3] * sv.w;
  float sdA = accA[0] * dv.x + accA[1] * dv.y + accA[2] * dv.z + accA[3] * dv.w;
  float ssB = accB[0] * sv.x + accB[1] * sv.y + accB[2] * sv.z + accB[3] * sv.w;
  float sdB = accB[0] * dv.x + accB[1] * dv.y + accB[2] * dv.z + accB[3] * dv.w;
#pragma unroll
  for (int m = 1; m <= 4; m <<= 1) {
    ssA += __shfl_xor(ssA, m, 64);
    sdA += __shfl_xor(sdA, m, 64);
    ssB += __shfl_xor(ssB, m, 64);
    sdB += __shfl_xor(sdB, m, 64);
  }
  if (cq == 0) {
    if (rA < n) { as2[rA] = ssA; ad2[rA] = sdA; }
    if (rB < n) { as2[rB] = ssB; ad2[rB] = sdB; }
  }
}

// -------- fused GAT layer 2 (bf16 gather, quarter-wave per edge) --------
__global__ __launch_bounds__(256) void k_agg2(const unsigned short* __restrict__ h2b,
    const float* __restrict__ as2, const float* __restrict__ ad2,
    const int* __restrict__ offs, const int* __restrict__ csr_src,
    const float* __restrict__ b2, const float* __restrict__ linW,
    float* __restrict__ score, int n) {
  int node = blockIdx.x * 4 + (threadIdx.x >> 6);
  int lane = threadIdx.x & 63;
  if (node >= n) return;
  const int sub = lane >> 4;
  const int p = lane & 15;
  const int j0 = offs[node], j1 = offs[node + 1];
  const float adv = ad2[node];
  float acc0 = 0.f, acc1 = 0.f, den = 0.f;
  int jj = j0;
  for (; jj + 8 <= j1; jj += 8) {
    const int sA = csr_src[jj + sub];
    const int sB = csr_src[jj + 4 + sub];
    const float aA = as2[sA], aB = as2[sB];
    const unsigned uA = ((const unsigned*)(h2b + (size_t)sA * OUT_DIM))[p];
    const unsigned uB = ((const unsigned*)(h2b + (size_t)sB * OUT_DIM))[p];
    float e, w;
    e = aA + adv; e = (e >= 0.f) ? e : NEG * e; w = __expf(e);
    den += w; acc0 += w * b2fl(uA); acc1 += w * b2fh(uA);
    e = aB + adv; e = (e >= 0.f) ? e : NEG * e; w = __expf(e);
    den += w; acc0 += w * b2fl(uB); acc1 += w * b2fh(uB);
  }
  for (; jj < j1; jj += 4) {
    const int idx = jj + sub;
    const bool valid = idx < j1;
    const int s = valid ? csr_src[idx] : csr_src[j1 - 1];
    const float a = as2[s];
    const unsigned u = ((const unsigned*)(h2b + (size_t)s * OUT_DIM))[p];
    float e = a + adv; e = (e >= 0.f) ? e : NEG * e;
    float w = valid ? __expf(e) : 0.f;
    den += w; acc0 += w * b2fl(u); acc1 += w * b2fh(u);
  }
  den  += __shfl_xor(den, 16, 64);  den  += __shfl_xor(den, 32, 64);
  acc0 += __shfl_xor(acc0, 16, 64); acc0 += __shfl_xor(acc0, 32, 64);
  acc1 += __shfl_xor(acc1, 16, 64); acc1 += __shfl_xor(acc1, 32, 64);
  const float inv = 1.0f / den;
  float o0 = acc0 * inv + b2[2 * p];
  float o1 = acc1 * inv + b2[2 * p + 1];
  float m = fmaxf(o0, o1);
#pragma unroll
  for (int mm = 1; mm <= 8; mm <<= 1) m = fmaxf(m, __shfl_xor(m, mm, 64));
  float ssum = __expf(o0 - m) + __expf(o1 - m);
#pragma unroll
  for (int mm = 1; mm <= 8; mm <<= 1) ssum += __shfl_xor(ssum, mm, 64);
  const float lse = m + __logf(ssum);
  float sc = (o0 - lse) * linW[2 * p] + (o1 - lse) * linW[2 * p + 1];
#pragma unroll
  for (int mm = 1; mm <= 8; mm <<= 1) sc += __shfl_xor(sc, mm, 64);
  if (lane == 0) score[node] = sc;
}

// -------- pooling: LDS per-graph partials, few global atomics per block --------
__global__ __launch_bounds__(256) void k_pool(const float* __restrict__ score,
    const int* __restrict__ batch, float* __restrict__ gsum,
    float* __restrict__ gcnt, int n) {
  __shared__ float ps[64];
  __shared__ float pc[64];
  const int tid = threadIdx.x;
  if (tid < 64) { ps[tid] = 0.f; pc[tid] = 0.f; }
  __syncthreads();
  int i = blockIdx.x * 256 + tid;
  if (i < n) {
    int g = batch[i];
    atomicAdd(&ps[g], score[i]);
    atomicAdd(&pc[g], 1.0f);
  }
  __syncthreads();
  if (tid < 64 && pc[tid] != 0.f) {
    atomicAdd(&gsum[tid], ps[tid]);
    atomicAdd(&gcnt[tid], pc[tid]);
  }
}

__global__ void k_final(const float* __restrict__ gsum, const float* __restrict__ gcnt,
                        const float* __restrict__ linb, float* __restrict__ out, int g_) {
  int g = threadIdx.x;
  if (g < g_) out[g] = gsum[g] / fmaxf(gcnt[g], 1.0f) + linb[0];
}

extern "C" void kernel_launch(void* const* d_in, const int* in_sizes, int n_in,
                              void* d_out, int out_size, void* d_ws, size_t ws_size,
                              hipStream_t stream) {
  const float* x    = (const float*)d_in[0];
  const int*   adj  = (const int*)d_in[1];
  const int*   batch= (const int*)d_in[2];
  const float* W1   = (const float*)d_in[3];
  const float* a1s  = (const float*)d_in[4];
  const float* a1d  = (const float*)d_in[5];
  const float* b1   = (const float*)d_in[6];
  const float* W2   = (const float*)d_in[7];
  const float* a2s  = (const float*)d_in[8];
  const float* a2d  = (const float*)d_in[9];
  const float* b2   = (const float*)d_in[10];
  const float* linW = (const float*)d_in[11];
  const float* linb = (const float*)d_in[12];

  const int N = in_sizes[0] / IN_DIM;
  const int E = in_sizes[1] / 2;
  const int ET = E + N;
  const int G = out_size;   // 64
  const int NB = (N + 1023) / 1024;

  char* wsb = (char*)d_ws;
  size_t off = 0;
  auto take = [&](size_t bytes) -> char* {
    char* p = wsb + off;
    off += (bytes + 255) & ~(size_t)255;
    return p;
  };
  unsigned char* h1f8  = (unsigned char*)take((size_t)N * F1);
  unsigned short* relu1b= (unsigned short*)take((size_t)N * F1 * 2);
  float* as1    = (float*)take((size_t)N * 4 * 4);
  float* ad1    = (float*)take((size_t)N * 4 * 4);
  unsigned short* h2b = (unsigned short*)take((size_t)N * OUT_DIM * 2);
  float* as2v   = (float*)take((size_t)N * 4);
  float* ad2v   = (float*)take((size_t)N * 4);
  float* score  = (float*)take((size_t)N * 4);
  int*   cnt    = (int*)take((size_t)N * 4);
  int*   offs   = (int*)take((size_t)(N + 1) * 4);
  int*   cursor = (int*)take((size_t)N * 4);
  int*   csr_src= (int*)take((size_t)ET * 4);
  float* csr_w  = (float*)take((size_t)ET * 4 * 4);
  int*   bsum   = (int*)take((size_t)(NB + 1) * 4);
  float* gsum   = (float*)take((size_t)G * 4);
  float* gcnt   = (float*)take((size_t)G * 4);
  unsigned short* W1t = (unsigned short*)take((size_t)IN_DIM * F1 * 2);
  (void)ws_size; (void)n_in;

  hipMemsetAsync(cnt, 0, (size_t)N * 4, stream);
  hipMemsetAsync(gsum, 0, (size_t)G * 4, stream);
  hipMemsetAsync(gcnt, 0, (size_t)G * 4, stream);

  dim3 b256(256);
  k_prep<<<dim3((IN_DIM * F1) / 256), b256, 0, stream>>>(W1, W1t);
  k_gemm1<<<dim3((N + 63) / 64, F1 / 64), b256, 0, stream>>>(x, W1t, a1s, a1d, h1f8, as1, ad1, N);
  k_hist<<<dim3((ET + 255) / 256), b256, 0, stream>>>(adj, cnt, E, N);
  k_scan_local<<<dim3(NB), b256, 0, stream>>>(cnt, offs, bsum, N);
  k_scan_bsum<<<1, 64, 0, stream>>>(bsum, NB, offs + N);
  k_scan_add<<<dim3((N + 255) / 256), b256, 0, stream>>>(offs, bsum, cursor, N);
  k_scatter<<<dim3((ET + 255) / 256), b256, 0, stream>>>(adj, as1, ad1, cursor, csr_src, csr_w, E, N);
  k_agg1<<<dim3((N + 3) / 4), b256, 0, stream>>>(h1f8, offs, csr_src, csr_w, b1, relu1b, N);
  k_gemm2<<<dim3((N + 63) / 64), b256, 0, stream>>>(relu1b, W2, a2s, a2d, h2b, as2v, ad2v, N);
  k_agg2<<<dim3((N + 3) / 4), b256, 0, stream>>>(h2b, as2v, ad2v, offs, csr_src, b2, linW, score, N);
  k_pool<<<dim3((N + 255) / 256), b256, 0, stream>>>(score, batch, gsum, gcnt, N);
  k_final<<<1, 64, 0, stream>>>(gsum, gcnt, linb, (float*)d_out, G);
}

// Round 10
// 310.124 us; speedup vs baseline: 2.9958x; 1.0224x over previous
//
#include <hip/hip_runtime.h>

#define IN_DIM 128
#define F1 256      // HEADS*HID = 4*64
#define HID 64
#define OUT_DIM 32
#define NEG 0.2f
#define PADK 136    // LDS row pitch in bf16 elems (128 + 8): frag reads 2-way alias = free

typedef __attribute__((ext_vector_type(8))) short short8;
typedef __attribute__((ext_vector_type(4))) float v4f;
typedef __attribute__((ext_vector_type(2))) float v2f;

// ---- bf16 helpers ----
__device__ __forceinline__ float b2fl(unsigned u) {
  union { unsigned i; float f; } c; c.i = u << 16; return c.f;
}
__device__ __forceinline__ float b2fh(unsigned u) {
  union { unsigned i; float f; } c; c.i = u & 0xffff0000u; return c.f;
}
__device__ __forceinline__ unsigned short f2b(float f) {
  union { float f; unsigned i; } c; c.f = f;
  unsigned r = c.i + 0x7fffu + ((c.i >> 16) & 1u);   // RNE
  return (unsigned short)(r >> 16);
}

// ---- prep: W1t[n][k] bf16 = transpose of W1[k][n] fp32 (one-time, 32K elems) ----
__global__ __launch_bounds__(256) void k_prep(const float* __restrict__ W1,
    unsigned short* __restrict__ W1t) {
  int idx = blockIdx.x * 256 + threadIdx.x;   // 0..32767
  int nn = idx >> 7, k = idx & 127;
  W1t[idx] = f2b(W1[(size_t)k * F1 + nn]);
}

// ------- GEMM1 via MFMA: h1f8[N,256](fp8 e4m3) = bf16(x)[N,128] @ W1[128,256] -------
__global__ __launch_bounds__(256) void k_gemm1(const float* __restrict__ x,
    const unsigned short* __restrict__ W1t,
    const float* __restrict__ a1s_w, const float* __restrict__ a1d_w,
    unsigned char* __restrict__ h1f8, float* __restrict__ as1,
    float* __restrict__ ad1, int n) {
  __shared__ unsigned short xs[64 * PADK];   // 17.4 KB
  __shared__ unsigned short ws[64 * PADK];   // 17.4 KB
  const int tid = threadIdx.x;
  const int rb = blockIdx.x * 64;
  const int head = blockIdx.y;
  const int cb = head * 64;

#pragma unroll
  for (int i = 0; i < 8; ++i) {
    int idx = tid + i * 256;
    int row = idx >> 5, c4 = idx & 31;
    float4 v = make_float4(0.f, 0.f, 0.f, 0.f);
    if (rb + row < n) v = *(const float4*)&x[(size_t)(rb + row) * IN_DIM + c4 * 4];
    ushort4 b; b.x = f2b(v.x); b.y = f2b(v.y); b.z = f2b(v.z); b.w = f2b(v.w);
    *(ushort4*)&xs[row * PADK + c4 * 4] = b;
  }
#pragma unroll
  for (int i = 0; i < 4; ++i) {
    int idx = tid + i * 256;
    int row = idx >> 4, c = idx & 15;
    *(uint4*)&ws[row * PADK + c * 8] =
        *(const uint4*)&W1t[(size_t)(cb + row) * IN_DIM + c * 8];
  }
  __syncthreads();

  const int wv = tid >> 6;
  const int lane = tid & 63;
  const int l15 = lane & 15, quad = lane >> 4;
  v4f acc0 = {0.f, 0.f, 0.f, 0.f}, acc1 = acc0, acc2 = acc0, acc3 = acc0;
#pragma unroll
  for (int kt = 0; kt < 4; ++kt) {
    const int ko = kt * 32 + quad * 8;
    short8 af = *(const short8*)&xs[(wv * 16 + l15) * PADK + ko];
    short8 b0 = *(const short8*)&ws[(l15) * PADK + ko];
    short8 b1 = *(const short8*)&ws[(16 + l15) * PADK + ko];
    short8 b2 = *(const short8*)&ws[(32 + l15) * PADK + ko];
    short8 b3 = *(const short8*)&ws[(48 + l15) * PADK + ko];
    acc0 = __builtin_amdgcn_mfma_f32_16x16x32_bf16(af, b0, acc0, 0, 0, 0);
    acc1 = __builtin_amdgcn_mfma_f32_16x16x32_bf16(af, b1, acc1, 0, 0, 0);
    acc2 = __builtin_amdgcn_mfma_f32_16x16x32_bf16(af, b2, acc2, 0, 0, 0);
    acc3 = __builtin_amdgcn_mfma_f32_16x16x32_bf16(af, b3, acc3, 0, 0, 0);
  }

  const float s0 = a1s_w[cb + l15],      s1 = a1s_w[cb + 16 + l15];
  const float s2 = a1s_w[cb + 32 + l15], s3 = a1s_w[cb + 48 + l15];
  const float d0 = a1d_w[cb + l15],      d1 = a1d_w[cb + 16 + l15];
  const float d2 = a1d_w[cb + 32 + l15], d3 = a1d_w[cb + 48 + l15];
#pragma unroll
  for (int r = 0; r < 4; ++r) {
    const int row = rb + wv * 16 + quad * 4 + r;
    const bool ok = row < n;
    if (ok) {
      size_t base = (size_t)row * F1 + cb;
      int pA = __builtin_amdgcn_cvt_pk_fp8_f32(acc0[r], acc1[r], 0, false);
      int pB = __builtin_amdgcn_cvt_pk_fp8_f32(acc2[r], acc3[r], 0, false);
      h1f8[base + l15]      = (unsigned char)(pA & 0xff);
      h1f8[base + 16 + l15] = (unsigned char)((pA >> 8) & 0xff);
      h1f8[base + 32 + l15] = (unsigned char)(pB & 0xff);
      h1f8[base + 48 + l15] = (unsigned char)((pB >> 8) & 0xff);
    }
    float ds = acc0[r] * s0 + acc1[r] * s1 + acc2[r] * s2 + acc3[r] * s3;
    float dd = acc0[r] * d0 + acc1[r] * d1 + acc2[r] * d2 + acc3[r] * d3;
#pragma unroll
    for (int m = 1; m <= 8; m <<= 1) {
      ds += __shfl_xor(ds, m, 64);
      dd += __shfl_xor(dd, m, 64);
    }
    if (ok && l15 == 0) {
      as1[(size_t)row * 4 + head] = ds;
      ad1[(size_t)row * 4 + head] = dd;
    }
  }
}

// ---------------- CSR build ----------------
__global__ __launch_bounds__(256) void k_hist(const int* __restrict__ adj,
    int* __restrict__ cnt, int E_, int n) {
  int e = blockIdx.x * 256 + threadIdx.x;
  int ET = E_ + n;
  if (e >= ET) return;
  int d = (e < E_) ? adj[E_ + e] : (e - E_);
  atomicAdd(&cnt[d], 1);
}

__global__ __launch_bounds__(256) void k_scan_local(const int* __restrict__ cnt,
    int* __restrict__ offs, int* __restrict__ bsum, int n) {
  __shared__ int wsums[4];
  const int tid = threadIdx.x;
  const int lane = tid & 63, w = tid >> 6;
  const int base = blockIdx.x * 1024;
  const int i0 = base + tid * 4;
  int v[4];
#pragma unroll
  for (int k = 0; k < 4; ++k) { int i = i0 + k; v[k] = (i < n) ? cnt[i] : 0; }
  int tsum = v[0] + v[1] + v[2] + v[3];
  int incl = tsum;
#pragma unroll
  for (int d = 1; d < 64; d <<= 1) {
    int t = __shfl_up(incl, (unsigned)d, 64);
    if (lane >= d) incl += t;
  }
  if (lane == 63) wsums[w] = incl;
  __syncthreads();
  int pre = 0;
  for (int k = 0; k < w; ++k) pre += wsums[k];
  int run = pre + incl - tsum;
#pragma unroll
  for (int k = 0; k < 4; ++k) { int i = i0 + k; if (i < n) offs[i] = run; run += v[k]; }
  if (tid == 255) bsum[blockIdx.x] = pre + incl;
}

__global__ void k_scan_bsum(int* __restrict__ bsum, int nb, int* __restrict__ offs_n) {
  int lane = threadIdx.x;   // 64 threads
  int carry = 0;
  for (int base = 0; base < nb; base += 64) {
    int i = base + lane;
    int v = (i < nb) ? bsum[i] : 0;
    int incl = v;
#pragma unroll
    for (int d = 1; d < 64; d <<= 1) {
      int t = __shfl_up(incl, (unsigned)d, 64);
      if (lane >= d) incl += t;
    }
    if (i < nb) bsum[i] = carry + incl - v;
    int tot = __shfl(incl, 63, 64);
    carry += tot;
  }
  if (lane == 0) *offs_n = carry;
}

__global__ __launch_bounds__(256) void k_scan_add(int* __restrict__ offs,
    const int* __restrict__ bsum, int* __restrict__ cursor, int n) {
  int i = blockIdx.x * 256 + threadIdx.x;
  if (i < n) {
    int v = offs[i] + bsum[i >> 10];
    offs[i] = v;
    cursor[i] = v;
  }
}

// -------- XCD-binned scatter + fused edge attention weights (layer 1) --------
// R9's k_scatter was random-write-transaction bound: 81 MB WRITE vs 17 MB logical
// (each edge's (csr_src,csr_w) stores allocate ~2 random 64B lines; same line
// written from all 8 XCDs -> HBM ping-pong, non-shared per-XCD L2s).
// Fix: 8 dst-bins, bin = blockIdx & 7 -> under round-robin block->XCD dispatch
// each bin's CSR region (~2 MB) is written by ONE XCD and stays L2-resident
// until full. adj is re-read 8x (L3-resident, cheap). Mapping is a speed
// heuristic only; correctness is bin-independent.
__global__ __launch_bounds__(256) void k_scatter(const int* __restrict__ adj,
    const float* __restrict__ as1, const float* __restrict__ ad1,
    int* __restrict__ cursor, int* __restrict__ csr_src,
    float* __restrict__ csr_w, int E_, int n, int binw) {
  const int bin = blockIdx.x & 7;
  const int chunk = blockIdx.x >> 3;
  const int e = chunk * 256 + threadIdx.x;
  const int ET = E_ + n;
  if (e >= ET) return;
  int s, d;
  if (e < E_) { s = adj[e]; d = adj[E_ + e]; } else { s = d = e - E_; }
  const int lo = bin * binw;
  if (d < lo || d >= lo + binw) return;   // not my bin
  int pos = atomicAdd(&cursor[d], 1);
  csr_src[pos] = s;
  const float4 qs = *(const float4*)(as1 + (size_t)s * 4);
  const float4 qd = *(const float4*)(ad1 + (size_t)d * 4);
  float4 w;
  float ev;
  ev = qs.x + qd.x; ev = (ev >= 0.f) ? ev : NEG * ev; w.x = __expf(ev);
  ev = qs.y + qd.y; ev = (ev >= 0.f) ? ev : NEG * ev; w.y = __expf(ev);
  ev = qs.z + qd.z; ev = (ev >= 0.f) ? ev : NEG * ev; w.z = __expf(ev);
  ev = qs.w + qd.w; ev = (ev >= 0.f) ? ev : NEG * ev; w.w = __expf(ev);
  *(float4*)(csr_w + (size_t)pos * 4) = w;
}

// ---------------- fused GAT layer 1 (fp8 gather, precomputed weights) ----------------
__global__ __launch_bounds__(256) void k_agg1(const unsigned char* __restrict__ h1f8,
    const int* __restrict__ offs, const int* __restrict__ csr_src,
    const float* __restrict__ csr_w, const float* __restrict__ b1,
    unsigned short* __restrict__ relu1b, int n) {
  int node = blockIdx.x * 4 + (threadIdx.x >> 6);
  int lane = threadIdx.x & 63;
  if (node >= n) return;
  const int h = lane >> 4;
  const int j0 = offs[node], j1 = offs[node + 1];
  float a0 = 0.f, a1 = 0.f, a2 = 0.f, a3 = 0.f, den = 0.f;
  int j = j0;
  for (; j + 4 <= j1; j += 4) {
    const int s0 = csr_src[j + 0], s1 = csr_src[j + 1];
    const int s2 = csr_src[j + 2], s3 = csr_src[j + 3];
    const float w0 = csr_w[(size_t)(j + 0) * 4 + h];
    const float w1 = csr_w[(size_t)(j + 1) * 4 + h];
    const float w2 = csr_w[(size_t)(j + 2) * 4 + h];
    const float w3 = csr_w[(size_t)(j + 3) * 4 + h];
    const int u0 = ((const int*)(h1f8 + (size_t)s0 * F1))[lane];
    const int u1 = ((const int*)(h1f8 + (size_t)s1 * F1))[lane];
    const int u2 = ((const int*)(h1f8 + (size_t)s2 * F1))[lane];
    const int u3 = ((const int*)(h1f8 + (size_t)s3 * F1))[lane];
    v2f lo, hi;
    lo = __builtin_amdgcn_cvt_pk_f32_fp8(u0, false); hi = __builtin_amdgcn_cvt_pk_f32_fp8(u0, true);
    den += w0; a0 += w0 * lo.x; a1 += w0 * lo.y; a2 += w0 * hi.x; a3 += w0 * hi.y;
    lo = __builtin_amdgcn_cvt_pk_f32_fp8(u1, false); hi = __builtin_amdgcn_cvt_pk_f32_fp8(u1, true);
    den += w1; a0 += w1 * lo.x; a1 += w1 * lo.y; a2 += w1 * hi.x; a3 += w1 * hi.y;
    lo = __builtin_amdgcn_cvt_pk_f32_fp8(u2, false); hi = __builtin_amdgcn_cvt_pk_f32_fp8(u2, true);
    den += w2; a0 += w2 * lo.x; a1 += w2 * lo.y; a2 += w2 * hi.x; a3 += w2 * hi.y;
    lo = __builtin_amdgcn_cvt_pk_f32_fp8(u3, false); hi = __builtin_amdgcn_cvt_pk_f32_fp8(u3, true);
    den += w3; a0 += w3 * lo.x; a1 += w3 * lo.y; a2 += w3 * hi.x; a3 += w3 * hi.y;
  }
  for (; j < j1; ++j) {
    const int s = csr_src[j];
    const float w = csr_w[(size_t)j * 4 + h];
    const int u = ((const int*)(h1f8 + (size_t)s * F1))[lane];
    v2f lo = __builtin_amdgcn_cvt_pk_f32_fp8(u, false);
    v2f hi = __builtin_amdgcn_cvt_pk_f32_fp8(u, true);
    den += w; a0 += w * lo.x; a1 += w * lo.y; a2 += w * hi.x; a3 += w * hi.y;
  }
  const float inv = 1.0f / den;
  const float4 bb = ((const float4*)b1)[lane];
  ushort4 rv;
  rv.x = f2b(fmaxf(a0 * inv + bb.x, 0.f));
  rv.y = f2b(fmaxf(a1 * inv + bb.y, 0.f));
  rv.z = f2b(fmaxf(a2 * inv + bb.z, 0.f));
  rv.w = f2b(fmaxf(a3 * inv + bb.w, 0.f));
  *(ushort4*)&relu1b[(size_t)node * F1 + 4 * lane] = rv;
}

// ---------------- GEMM2 (register-tiled; bf16 relu1 input) ----------------
__global__ __launch_bounds__(256) void k_gemm2(const unsigned short* __restrict__ relu1b,
    const float* __restrict__ W2, const float* __restrict__ a2s_w,
    const float* __restrict__ a2d_w, unsigned short* __restrict__ h2b,
    float* __restrict__ as2, float* __restrict__ ad2, int n) {
  __shared__ float w2s[F1 * OUT_DIM];  // 32 KB
  __shared__ float xs[32][72];         // [k][row], 2-way bank alias = free
  const int tid = threadIdx.x;
  const int rb = blockIdx.x * 64;
  for (int i = tid; i < F1 * OUT_DIM; i += 256) w2s[i] = W2[i];
  const int rx = tid >> 3;       // 0..31 -> rows rx, rx+32
  const int cq = tid & 7;        // 0..7  -> cols 4cq..4cq+3
  float accA[4] = {0.f, 0.f, 0.f, 0.f};
  float accB[4] = {0.f, 0.f, 0.f, 0.f};
  for (int kb = 0; kb < F1; kb += 32) {
    __syncthreads();
#pragma unroll
    for (int i = 0; i < 2; ++i) {
      int idx = tid + i * 256;            // 0..511
      int r = idx >> 3, c4 = idx & 7;     // row 0..63, uint2 group (4 k-vals)
      int row = rb + r;
      uint2 u = make_uint2(0u, 0u);
      if (row < n) u = *(const uint2*)&relu1b[(size_t)row * F1 + kb + c4 * 4];
      xs[c4 * 4 + 0][r] = b2fl(u.x); xs[c4 * 4 + 1][r] = b2fh(u.x);
      xs[c4 * 4 + 2][r] = b2fl(u.y); xs[c4 * 4 + 3][r] = b2fh(u.y);
    }
    __syncthreads();
#pragma unroll
    for (int kk = 0; kk < 32; ++kk) {
      const float xa = xs[kk][rx];
      const float xb = xs[kk][rx + 32];
      const float4 wv = *(const float4*)&w2s[(kb + kk) * OUT_DIM + 4 * cq];
      accA[0] += xa * wv.x; accA[1] += xa * wv.y; accA[2] += xa * wv.z; accA[3] += xa * wv.w;
      accB[0] += xb * wv.x; accB[1] += xb * wv.y; accB[2] += xb * wv.z; accB[3] += xb * wv.w;
    }
  }
  const float4 sv = *(const float4*)&a2s_w[4 * cq];
  const float4 dv = *(const float4*)&a2d_w[4 * cq];
  const int rA = rb + rx, rB = rb + rx + 32;
  if (rA < n) {
    ushort4 v; v.x = f2b(accA[0]); v.y = f2b(accA[1]); v.z = f2b(accA[2]); v.w = f2b(accA[3]);
    *(ushort4*)&h2b[(size_t)rA * OUT_DIM + 4 * cq] = v;
  }
  if (rB < n) {
    ushort4 v; v.x = f2b(accB[0]); v.y = f2b(accB[1]); v.z = f2b(accB[2]); v.w = f2b(accB[3]);
    *(ushort4*)&h2b[(size_t)rB * OUT_DIM + 4 * cq] = v;
  }
  float ssA = accA[0] * sv.x + accA[1] * sv.y + accA[2] * sv.z + accA[3] * sv.w;
  float sdA = accA[0] * dv.x + accA[1] * dv.y + accA[2] * dv.z + accA[3] * dv.w;
  float ssB = accB[0] * sv.x + accB[1] * sv.y + accB[2] * sv.z + accB[3] * sv.w;
  float sdB = accB[0] * dv.x + accB[1] * dv.y + accB[2] * dv.z + accB[3] * dv.w;
#pragma unroll
  for (int m = 1; m <= 4; m <<= 1) {
    ssA += __shfl_xor(ssA, m, 64);
    sdA += __shfl_xor(sdA, m, 64);
    ssB += __shfl_xor(ssB, m, 64);
    sdB += __shfl_xor(sdB, m, 64);
  }
  if (cq == 0) {
    if (rA < n) { as2[rA] = ssA; ad2[rA] = sdA; }
    if (rB < n) { as2[rB] = ssB; ad2[rB] = sdB; }
  }
}

// -------- fused GAT layer 2 (bf16 gather, quarter-wave per edge) --------
__global__ __launch_bounds__(256) void k_agg2(const unsigned short* __restrict__ h2b,
    const float* __restrict__ as2, const float* __restrict__ ad2,
    const int* __restrict__ offs, const int* __restrict__ csr_src,
    const float* __restrict__ b2, const float* __restrict__ linW,
    float* __restrict__ score, int n) {
  int node = blockIdx.x * 4 + (threadIdx.x >> 6);
  int lane = threadIdx.x & 63;
  if (node >= n) return;
  const int sub = lane >> 4;
  const int p = lane & 15;
  const int j0 = offs[node], j1 = offs[node + 1];
  const float adv = ad2[node];
  float acc0 = 0.f, acc1 = 0.f, den = 0.f;
  int jj = j0;
  for (; jj + 8 <= j1; jj += 8) {
    const int sA = csr_src[jj + sub];
    const int sB = csr_src[jj + 4 + sub];
    const float aA = as2[sA], aB = as2[sB];
    const unsigned uA = ((const unsigned*)(h2b + (size_t)sA * OUT_DIM))[p];
    const unsigned uB = ((const unsigned*)(h2b + (size_t)sB * OUT_DIM))[p];
    float e, w;
    e = aA + adv; e = (e >= 0.f) ? e : NEG * e; w = __expf(e);
    den += w; acc0 += w * b2fl(uA); acc1 += w * b2fh(uA);
    e = aB + adv; e = (e >= 0.f) ? e : NEG * e; w = __expf(e);
    den += w; acc0 += w * b2fl(uB); acc1 += w * b2fh(uB);
  }
  for (; jj < j1; jj += 4) {
    const int idx = jj + sub;
    const bool valid = idx < j1;
    const int s = valid ? csr_src[idx] : csr_src[j1 - 1];
    const float a = as2[s];
    const unsigned u = ((const unsigned*)(h2b + (size_t)s * OUT_DIM))[p];
    float e = a + adv; e = (e >= 0.f) ? e : NEG * e;
    float w = valid ? __expf(e) : 0.f;
    den += w; acc0 += w * b2fl(u); acc1 += w * b2fh(u);
  }
  den  += __shfl_xor(den, 16, 64);  den  += __shfl_xor(den, 32, 64);
  acc0 += __shfl_xor(acc0, 16, 64); acc0 += __shfl_xor(acc0, 32, 64);
  acc1 += __shfl_xor(acc1, 16, 64); acc1 += __shfl_xor(acc1, 32, 64);
  const float inv = 1.0f / den;
  float o0 = acc0 * inv + b2[2 * p];
  float o1 = acc1 * inv + b2[2 * p + 1];
  float m = fmaxf(o0, o1);
#pragma unroll
  for (int mm = 1; mm <= 8; mm <<= 1) m = fmaxf(m, __shfl_xor(m, mm, 64));
  float ssum = __expf(o0 - m) + __expf(o1 - m);
#pragma unroll
  for (int mm = 1; mm <= 8; mm <<= 1) ssum += __shfl_xor(ssum, mm, 64);
  const float lse = m + __logf(ssum);
  float sc = (o0 - lse) * linW[2 * p] + (o1 - lse) * linW[2 * p + 1];
#pragma unroll
  for (int mm = 1; mm <= 8; mm <<= 1) sc += __shfl_xor(sc, mm, 64);
  if (lane == 0) score[node] = sc;
}

// -------- pooling: LDS per-graph partials, few global atomics per block --------
__global__ __launch_bounds__(256) void k_pool(const float* __restrict__ score,
    const int* __restrict__ batch, float* __restrict__ gsum,
    float* __restrict__ gcnt, int n) {
  __shared__ float ps[64];
  __shared__ float pc[64];
  const int tid = threadIdx.x;
  if (tid < 64) { ps[tid] = 0.f; pc[tid] = 0.f; }
  __syncthreads();
  int i = blockIdx.x * 256 + tid;
  if (i < n) {
    int g = batch[i];
    atomicAdd(&ps[g], score[i]);
    atomicAdd(&pc[g], 1.0f);
  }
  __syncthreads();
  if (tid < 64 && pc[tid] != 0.f) {
    atomicAdd(&gsum[tid], ps[tid]);
    atomicAdd(&gcnt[tid], pc[tid]);
  }
}

__global__ void k_final(const float* __restrict__ gsum, const float* __restrict__ gcnt,
                        const float* __restrict__ linb, float* __restrict__ out, int g_) {
  int g = threadIdx.x;
  if (g < g_) out[g] = gsum[g] / fmaxf(gcnt[g], 1.0f) + linb[0];
}

extern "C" void kernel_launch(void* const* d_in, const int* in_sizes, int n_in,
                              void* d_out, int out_size, void* d_ws, size_t ws_size,
                              hipStream_t stream) {
  const float* x    = (const float*)d_in[0];
  const int*   adj  = (const int*)d_in[1];
  const int*   batch= (const int*)d_in[2];
  const float* W1   = (const float*)d_in[3];
  const float* a1s  = (const float*)d_in[4];
  const float* a1d  = (const float*)d_in[5];
  const float* b1   = (const float*)d_in[6];
  const float* W2   = (const float*)d_in[7];
  const float* a2s  = (const float*)d_in[8];
  const float* a2d  = (const float*)d_in[9];
  const float* b2   = (const float*)d_in[10];
  const float* linW = (const float*)d_in[11];
  const float* linb = (const float*)d_in[12];

  const int N = in_sizes[0] / IN_DIM;
  const int E = in_sizes[1] / 2;
  const int ET = E + N;
  const int G = out_size;   // 64
  const int NB = (N + 1023) / 1024;
  const int BINW = (N + 7) / 8;

  char* wsb = (char*)d_ws;
  size_t off = 0;
  auto take = [&](size_t bytes) -> char* {
    char* p = wsb + off;
    off += (bytes + 255) & ~(size_t)255;
    return p;
  };
  unsigned char* h1f8  = (unsigned char*)take((size_t)N * F1);
  unsigned short* relu1b= (unsigned short*)take((size_t)N * F1 * 2);
  float* as1    = (float*)take((size_t)N * 4 * 4);
  float* ad1    = (float*)take((size_t)N * 4 * 4);
  unsigned short* h2b = (unsigned short*)take((size_t)N * OUT_DIM * 2);
  float* as2v   = (float*)take((size_t)N * 4);
  float* ad2v   = (float*)take((size_t)N * 4);
  float* score  = (float*)take((size_t)N * 4);
  int*   cnt    = (int*)take((size_t)N * 4);
  int*   offs   = (int*)take((size_t)(N + 1) * 4);
  int*   cursor = (int*)take((size_t)N * 4);
  int*   csr_src= (int*)take((size_t)ET * 4);
  float* csr_w  = (float*)take((size_t)ET * 4 * 4);
  int*   bsum   = (int*)take((size_t)(NB + 1) * 4);
  float* gsum   = (float*)take((size_t)G * 4);
  float* gcnt   = (float*)take((size_t)G * 4);
  unsigned short* W1t = (unsigned short*)take((size_t)IN_DIM * F1 * 2);
  (void)ws_size; (void)n_in;

  hipMemsetAsync(cnt, 0, (size_t)N * 4, stream);
  hipMemsetAsync(gsum, 0, (size_t)G * 4, stream);
  hipMemsetAsync(gcnt, 0, (size_t)G * 4, stream);

  dim3 b256(256);
  k_prep<<<dim3((IN_DIM * F1) / 256), b256, 0, stream>>>(W1, W1t);
  k_gemm1<<<dim3((N + 63) / 64, F1 / 64), b256, 0, stream>>>(x, W1t, a1s, a1d, h1f8, as1, ad1, N);
  k_hist<<<dim3((ET + 255) / 256), b256, 0, stream>>>(adj, cnt, E, N);
  k_scan_local<<<dim3(NB), b256, 0, stream>>>(cnt, offs, bsum, N);
  k_scan_bsum<<<1, 64, 0, stream>>>(bsum, NB, offs + N);
  k_scan_add<<<dim3((N + 255) / 256), b256, 0, stream>>>(offs, bsum, cursor, N);
  k_scatter<<<dim3(((ET + 255) / 256) * 8), b256, 0, stream>>>(adj, as1, ad1, cursor, csr_src, csr_w, E, N, BINW);
  k_agg1<<<dim3((N + 3) / 4), b256, 0, stream>>>(h1f8, offs, csr_src, csr_w, b1, relu1b, N);
  k_gemm2<<<dim3((N + 63) / 64), b256, 0, stream>>>(relu1b, W2, a2s, a2d, h2b, as2v, ad2v, N);
  k_agg2<<<dim3((N + 3) / 4), b256, 0, stream>>>(h2b, as2v, ad2v, offs, csr_src, b2, linW, score, N);
  k_pool<<<dim3((N + 255) / 256), b256, 0, stream>>>(score, batch, gsum, gcnt, N);
  k_final<<<1, 64, 0, stream>>>(gsum, gcnt, linb, (float*)d_out, G);
}

// Round 11
// 299.549 us; speedup vs baseline: 3.1015x; 1.0353x over previous
//
#include <hip/hip_runtime.h>

#define IN_DIM 128
#define F1 256      // HEADS*HID = 4*64
#define HID 64
#define OUT_DIM 32
#define NEG 0.2f
#define PADK 136    // LDS row pitch in bf16 elems (128 + 8): frag reads 2-way alias = free

typedef __attribute__((ext_vector_type(8))) short short8;
typedef __attribute__((ext_vector_type(4))) float v4f;
typedef __attribute__((ext_vector_type(2))) float v2f;

// ---- bf16 helpers ----
__device__ __forceinline__ float b2fl(unsigned u) {
  union { unsigned i; float f; } c; c.i = u << 16; return c.f;
}
__device__ __forceinline__ float b2fh(unsigned u) {
  union { unsigned i; float f; } c; c.i = u & 0xffff0000u; return c.f;
}
__device__ __forceinline__ unsigned short f2b(float f) {
  union { float f; unsigned i; } c; c.f = f;
  unsigned r = c.i + 0x7fffu + ((c.i >> 16) & 1u);   // RNE
  return (unsigned short)(r >> 16);
}

// ---- prep: W1t[n][k] bf16 = transpose of W1[k][n] fp32 (one-time, 32K elems) ----
__global__ __launch_bounds__(256) void k_prep(const float* __restrict__ W1,
    unsigned short* __restrict__ W1t) {
  int idx = blockIdx.x * 256 + threadIdx.x;   // 0..32767
  int nn = idx >> 7, k = idx & 127;
  W1t[idx] = f2b(W1[(size_t)k * F1 + nn]);
}

// ------- GEMM1 via MFMA: h1f8[N,256](fp8 e4m3) = bf16(x)[N,128] @ W1[128,256] -------
__global__ __launch_bounds__(256) void k_gemm1(const float* __restrict__ x,
    const unsigned short* __restrict__ W1t,
    const float* __restrict__ a1s_w, const float* __restrict__ a1d_w,
    unsigned char* __restrict__ h1f8, float* __restrict__ as1,
    float* __restrict__ ad1, int n) {
  __shared__ unsigned short xs[64 * PADK];   // 17.4 KB
  __shared__ unsigned short ws[64 * PADK];   // 17.4 KB
  const int tid = threadIdx.x;
  const int rb = blockIdx.x * 64;
  const int head = blockIdx.y;
  const int cb = head * 64;

#pragma unroll
  for (int i = 0; i < 8; ++i) {
    int idx = tid + i * 256;
    int row = idx >> 5, c4 = idx & 31;
    float4 v = make_float4(0.f, 0.f, 0.f, 0.f);
    if (rb + row < n) v = *(const float4*)&x[(size_t)(rb + row) * IN_DIM + c4 * 4];
    ushort4 b; b.x = f2b(v.x); b.y = f2b(v.y); b.z = f2b(v.z); b.w = f2b(v.w);
    *(ushort4*)&xs[row * PADK + c4 * 4] = b;
  }
#pragma unroll
  for (int i = 0; i < 4; ++i) {
    int idx = tid + i * 256;
    int row = idx >> 4, c = idx & 15;
    *(uint4*)&ws[row * PADK + c * 8] =
        *(const uint4*)&W1t[(size_t)(cb + row) * IN_DIM + c * 8];
  }
  __syncthreads();

  const int wv = tid >> 6;
  const int lane = tid & 63;
  const int l15 = lane & 15, quad = lane >> 4;
  v4f acc0 = {0.f, 0.f, 0.f, 0.f}, acc1 = acc0, acc2 = acc0, acc3 = acc0;
#pragma unroll
  for (int kt = 0; kt < 4; ++kt) {
    const int ko = kt * 32 + quad * 8;
    short8 af = *(const short8*)&xs[(wv * 16 + l15) * PADK + ko];
    short8 b0 = *(const short8*)&ws[(l15) * PADK + ko];
    short8 b1 = *(const short8*)&ws[(16 + l15) * PADK + ko];
    short8 b2 = *(const short8*)&ws[(32 + l15) * PADK + ko];
    short8 b3 = *(const short8*)&ws[(48 + l15) * PADK + ko];
    acc0 = __builtin_amdgcn_mfma_f32_16x16x32_bf16(af, b0, acc0, 0, 0, 0);
    acc1 = __builtin_amdgcn_mfma_f32_16x16x32_bf16(af, b1, acc1, 0, 0, 0);
    acc2 = __builtin_amdgcn_mfma_f32_16x16x32_bf16(af, b2, acc2, 0, 0, 0);
    acc3 = __builtin_amdgcn_mfma_f32_16x16x32_bf16(af, b3, acc3, 0, 0, 0);
  }

  const float s0 = a1s_w[cb + l15],      s1 = a1s_w[cb + 16 + l15];
  const float s2 = a1s_w[cb + 32 + l15], s3 = a1s_w[cb + 48 + l15];
  const float d0 = a1d_w[cb + l15],      d1 = a1d_w[cb + 16 + l15];
  const float d2 = a1d_w[cb + 32 + l15], d3 = a1d_w[cb + 48 + l15];
#pragma unroll
  for (int r = 0; r < 4; ++r) {
    const int row = rb + wv * 16 + quad * 4 + r;
    const bool ok = row < n;
    if (ok) {
      size_t base = (size_t)row * F1 + cb;
      int pA = __builtin_amdgcn_cvt_pk_fp8_f32(acc0[r], acc1[r], 0, false);
      int pB = __builtin_amdgcn_cvt_pk_fp8_f32(acc2[r], acc3[r], 0, false);
      h1f8[base + l15]      = (unsigned char)(pA & 0xff);
      h1f8[base + 16 + l15] = (unsigned char)((pA >> 8) & 0xff);
      h1f8[base + 32 + l15] = (unsigned char)(pB & 0xff);
      h1f8[base + 48 + l15] = (unsigned char)((pB >> 8) & 0xff);
    }
    float ds = acc0[r] * s0 + acc1[r] * s1 + acc2[r] * s2 + acc3[r] * s3;
    float dd = acc0[r] * d0 + acc1[r] * d1 + acc2[r] * d2 + acc3[r] * d3;
#pragma unroll
    for (int m = 1; m <= 8; m <<= 1) {
      ds += __shfl_xor(ds, m, 64);
      dd += __shfl_xor(dd, m, 64);
    }
    if (ok && l15 == 0) {
      as1[(size_t)row * 4 + head] = ds;
      ad1[(size_t)row * 4 + head] = dd;
    }
  }
}

// ---- hist + rank capture: rank[e] = within-dst arrival index (R11: the position
// atomic lives HERE, where the atomicAdd already existed; k_scatter needs none) ----
__global__ __launch_bounds__(256) void k_hist(const int* __restrict__ adj,
    int* __restrict__ cnt, int* __restrict__ rank, int E_, int n) {
  int e = blockIdx.x * 256 + threadIdx.x;
  int ET = E_ + n;
  if (e >= ET) return;
  int d = (e < E_) ? adj[E_ + e] : (e - E_);
  rank[e] = atomicAdd(&cnt[d], 1);
}

__global__ __launch_bounds__(256) void k_scan_local(const int* __restrict__ cnt,
    int* __restrict__ offs, int* __restrict__ bsum, int n) {
  __shared__ int wsums[4];
  const int tid = threadIdx.x;
  const int lane = tid & 63, w = tid >> 6;
  const int base = blockIdx.x * 1024;
  const int i0 = base + tid * 4;
  int v[4];
#pragma unroll
  for (int k = 0; k < 4; ++k) { int i = i0 + k; v[k] = (i < n) ? cnt[i] : 0; }
  int tsum = v[0] + v[1] + v[2] + v[3];
  int incl = tsum;
#pragma unroll
  for (int d = 1; d < 64; d <<= 1) {
    int t = __shfl_up(incl, (unsigned)d, 64);
    if (lane >= d) incl += t;
  }
  if (lane == 63) wsums[w] = incl;
  __syncthreads();
  int pre = 0;
  for (int k = 0; k < w; ++k) pre += wsums[k];
  int run = pre + incl - tsum;
#pragma unroll
  for (int k = 0; k < 4; ++k) { int i = i0 + k; if (i < n) offs[i] = run; run += v[k]; }
  if (tid == 255) bsum[blockIdx.x] = pre + incl;
}

__global__ void k_scan_bsum(int* __restrict__ bsum, int nb, int* __restrict__ offs_n) {
  int lane = threadIdx.x;   // 64 threads
  int carry = 0;
  for (int base = 0; base < nb; base += 64) {
    int i = base + lane;
    int v = (i < nb) ? bsum[i] : 0;
    int incl = v;
#pragma unroll
    for (int d = 1; d < 64; d <<= 1) {
      int t = __shfl_up(incl, (unsigned)d, 64);
      if (lane >= d) incl += t;
    }
    if (i < nb) bsum[i] = carry + incl - v;
    int tot = __shfl(incl, 63, 64);
    carry += tot;
  }
  if (lane == 0) *offs_n = carry;
}

__global__ __launch_bounds__(256) void k_scan_add(int* __restrict__ offs,
    const int* __restrict__ bsum, int n) {
  int i = blockIdx.x * 256 + threadIdx.x;
  if (i < n) offs[i] += bsum[i >> 10];
}

// -------- scatter, atomic-free: pos = offs[d] + rank[e]; ONE 16B record store --------
// Record: {src, w01 bf16x2, w23 bf16x2, 0}. R10's scatter had 3 random streams/edge
// (cursor RMW + 4B store + 16B store, 68 MB WRITE); now exactly 1. 8-bin XCD swizzle
// kept for write locality (speed heuristic only).
__global__ __launch_bounds__(256) void k_scatter(const int* __restrict__ adj,
    const int* __restrict__ rank, const int* __restrict__ offs,
    const float* __restrict__ as1, const float* __restrict__ ad1,
    uint4* __restrict__ csr, int E_, int n, int binw) {
  const int bin = blockIdx.x & 7;
  const int chunk = blockIdx.x >> 3;
  const int e = chunk * 256 + threadIdx.x;
  const int ET = E_ + n;
  if (e >= ET) return;
  int d = (e < E_) ? adj[E_ + e] : (e - E_);
  const int lo = bin * binw;
  if (d < lo || d >= lo + binw) return;   // not my bin
  int s = (e < E_) ? adj[e] : (e - E_);
  int pos = offs[d] + rank[e];
  const float4 qs = *(const float4*)(as1 + (size_t)s * 4);
  const float4 qd = *(const float4*)(ad1 + (size_t)d * 4);
  float ev, w0, w1, w2, w3;
  ev = qs.x + qd.x; ev = (ev >= 0.f) ? ev : NEG * ev; w0 = __expf(ev);
  ev = qs.y + qd.y; ev = (ev >= 0.f) ? ev : NEG * ev; w1 = __expf(ev);
  ev = qs.z + qd.z; ev = (ev >= 0.f) ? ev : NEG * ev; w2 = __expf(ev);
  ev = qs.w + qd.w; ev = (ev >= 0.f) ? ev : NEG * ev; w3 = __expf(ev);
  uint4 rec;
  rec.x = (unsigned)s;
  rec.y = (unsigned)f2b(w0) | ((unsigned)f2b(w1) << 16);
  rec.z = (unsigned)f2b(w2) | ((unsigned)f2b(w3) << 16);
  rec.w = 0u;
  csr[pos] = rec;
}

// ---------------- fused GAT layer 1 (fp8 gather, packed edge records) ----------------
// lane l: head h=l>>4, features 4(l&15)..+3 — one dword = 4 fp8 per gather.
__global__ __launch_bounds__(256) void k_agg1(const unsigned char* __restrict__ h1f8,
    const int* __restrict__ offs, const uint4* __restrict__ csr,
    const float* __restrict__ b1, unsigned short* __restrict__ relu1b, int n) {
  int node = blockIdx.x * 4 + (threadIdx.x >> 6);
  int lane = threadIdx.x & 63;
  if (node >= n) return;
  const int h = lane >> 4;
  const bool hHi = (h & 2) != 0, hOdd = (h & 1) != 0;
  const int j0 = offs[node], j1 = offs[node + 1];
  float a0 = 0.f, a1 = 0.f, a2 = 0.f, a3 = 0.f, den = 0.f;
  int j = j0;
  for (; j + 4 <= j1; j += 4) {
    const uint4 r0 = csr[j + 0], r1 = csr[j + 1];
    const uint4 r2 = csr[j + 2], r3 = csr[j + 3];
    const int u0 = ((const int*)(h1f8 + (size_t)r0.x * F1))[lane];
    const int u1 = ((const int*)(h1f8 + (size_t)r1.x * F1))[lane];
    const int u2 = ((const int*)(h1f8 + (size_t)r2.x * F1))[lane];
    const int u3 = ((const int*)(h1f8 + (size_t)r3.x * F1))[lane];
    unsigned ws;
    float w;
    v2f lo, hi;
    ws = hHi ? r0.z : r0.y; w = hOdd ? b2fh(ws) : b2fl(ws);
    lo = __builtin_amdgcn_cvt_pk_f32_fp8(u0, false); hi = __builtin_amdgcn_cvt_pk_f32_fp8(u0, true);
    den += w; a0 += w * lo.x; a1 += w * lo.y; a2 += w * hi.x; a3 += w * hi.y;
    ws = hHi ? r1.z : r1.y; w = hOdd ? b2fh(ws) : b2fl(ws);
    lo = __builtin_amdgcn_cvt_pk_f32_fp8(u1, false); hi = __builtin_amdgcn_cvt_pk_f32_fp8(u1, true);
    den += w; a0 += w * lo.x; a1 += w * lo.y; a2 += w * hi.x; a3 += w * hi.y;
    ws = hHi ? r2.z : r2.y; w = hOdd ? b2fh(ws) : b2fl(ws);
    lo = __builtin_amdgcn_cvt_pk_f32_fp8(u2, false); hi = __builtin_amdgcn_cvt_pk_f32_fp8(u2, true);
    den += w; a0 += w * lo.x; a1 += w * lo.y; a2 += w * hi.x; a3 += w * hi.y;
    ws = hHi ? r3.z : r3.y; w = hOdd ? b2fh(ws) : b2fl(ws);
    lo = __builtin_amdgcn_cvt_pk_f32_fp8(u3, false); hi = __builtin_amdgcn_cvt_pk_f32_fp8(u3, true);
    den += w; a0 += w * lo.x; a1 += w * lo.y; a2 += w * hi.x; a3 += w * hi.y;
  }
  for (; j < j1; ++j) {
    const uint4 r = csr[j];
    const int u = ((const int*)(h1f8 + (size_t)r.x * F1))[lane];
    unsigned ws = hHi ? r.z : r.y;
    float w = hOdd ? b2fh(ws) : b2fl(ws);
    v2f lo = __builtin_amdgcn_cvt_pk_f32_fp8(u, false);
    v2f hi = __builtin_amdgcn_cvt_pk_f32_fp8(u, true);
    den += w; a0 += w * lo.x; a1 += w * lo.y; a2 += w * hi.x; a3 += w * hi.y;
  }
  const float inv = 1.0f / den;
  const float4 bb = ((const float4*)b1)[lane];
  ushort4 rv;
  rv.x = f2b(fmaxf(a0 * inv + bb.x, 0.f));
  rv.y = f2b(fmaxf(a1 * inv + bb.y, 0.f));
  rv.z = f2b(fmaxf(a2 * inv + bb.z, 0.f));
  rv.w = f2b(fmaxf(a3 * inv + bb.w, 0.f));
  *(ushort4*)&relu1b[(size_t)node * F1 + 4 * lane] = rv;
}

// ---------------- GEMM2 (register-tiled; bf16 relu1 input) ----------------
__global__ __launch_bounds__(256) void k_gemm2(const unsigned short* __restrict__ relu1b,
    const float* __restrict__ W2, const float* __restrict__ a2s_w,
    const float* __restrict__ a2d_w, unsigned short* __restrict__ h2b,
    float* __restrict__ as2, float* __restrict__ ad2, int n) {
  __shared__ float w2s[F1 * OUT_DIM];  // 32 KB
  __shared__ float xs[32][72];         // [k][row], 2-way bank alias = free
  const int tid = threadIdx.x;
  const int rb = blockIdx.x * 64;
  for (int i = tid; i < F1 * OUT_DIM; i += 256) w2s[i] = W2[i];
  const int rx = tid >> 3;       // 0..31 -> rows rx, rx+32
  const int cq = tid & 7;        // 0..7  -> cols 4cq..4cq+3
  float accA[4] = {0.f, 0.f, 0.f, 0.f};
  float accB[4] = {0.f, 0.f, 0.f, 0.f};
  for (int kb = 0; kb < F1; kb += 32) {
    __syncthreads();
#pragma unroll
    for (int i = 0; i < 2; ++i) {
      int idx = tid + i * 256;            // 0..511
      int r = idx >> 3, c4 = idx & 7;     // row 0..63, uint2 group (4 k-vals)
      int row = rb + r;
      uint2 u = make_uint2(0u, 0u);
      if (row < n) u = *(const uint2*)&relu1b[(size_t)row * F1 + kb + c4 * 4];
      xs[c4 * 4 + 0][r] = b2fl(u.x); xs[c4 * 4 + 1][r] = b2fh(u.x);
      xs[c4 * 4 + 2][r] = b2fl(u.y); xs[c4 * 4 + 3][r] = b2fh(u.y);
    }
    __syncthreads();
#pragma unroll
    for (int kk = 0; kk < 32; ++kk) {
      const float xa = xs[kk][rx];
      const float xb = xs[kk][rx + 32];
      const float4 wv = *(const float4*)&w2s[(kb + kk) * OUT_DIM + 4 * cq];
      accA[0] += xa * wv.x; accA[1] += xa * wv.y; accA[2] += xa * wv.z; accA[3] += xa * wv.w;
      accB[0] += xb * wv.x; accB[1] += xb * wv.y; accB[2] += xb * wv.z; accB[3] += xb * wv.w;
    }
  }
  const float4 sv = *(const float4*)&a2s_w[4 * cq];
  const float4 dv = *(const float4*)&a2d_w[4 * cq];
  const int rA = rb + rx, rB = rb + rx + 32;
  if (rA < n) {
    ushort4 v; v.x = f2b(accA[0]); v.y = f2b(accA[1]); v.z = f2b(accA[2]); v.w = f2b(accA[3]);
    *(ushort4*)&h2b[(size_t)rA * OUT_DIM + 4 * cq] = v;
  }
  if (rB < n) {
    ushort4 v; v.x = f2b(accB[0]); v.y = f2b(accB[1]); v.z = f2b(accB[2]); v.w = f2b(accB[3]);
    *(ushort4*)&h2b[(size_t)rB * OUT_DIM + 4 * cq] = v;
  }
  float ssA = accA[0] * sv.x + accA[1] * sv.y + accA[2] * sv.z + accA[3] * sv.w;
  float sdA = accA[0] * dv.x + accA[1] * dv.y + accA[2] * dv.z + accA[3] * dv.w;
  float ssB = accB[0] * sv.x + accB[1] * sv.y + accB[2] * sv.z + accB[3] * sv.w;
  float sdB = accB[0] * dv.x + accB[1] * dv.y + accB[2] * dv.z + accB[3] * dv.w;
#pragma unroll
  for (int m = 1; m <= 4; m <<= 1) {
    ssA += __shfl_xor(ssA, m, 64);
    sdA += __shfl_xor(sdA, m, 64);
    ssB += __shfl_xor(ssB, m, 64);
    sdB += __shfl_xor(sdB, m, 64);
  }
  if (cq == 0) {
    if (rA < n) { as2[rA] = ssA; ad2[rA] = sdA; }
    if (rB < n) { as2[rB] = ssB; ad2[rB] = sdB; }
  }
}

// -------- fused GAT layer 2 (bf16 gather, quarter-wave per edge; src from records) ----
__global__ __launch_bounds__(256) void k_agg2(const unsigned short* __restrict__ h2b,
    const float* __restrict__ as2, const float* __restrict__ ad2,
    const int* __restrict__ offs, const uint4* __restrict__ csr,
    const float* __restrict__ b2, const float* __restrict__ linW,
    float* __restrict__ score, int n) {
  int node = blockIdx.x * 4 + (threadIdx.x >> 6);
  int lane = threadIdx.x & 63;
  if (node >= n) return;
  const int sub = lane >> 4;
  const int p = lane & 15;
  const int j0 = offs[node], j1 = offs[node + 1];
  const float adv = ad2[node];
  const int* csr_i = (const int*)csr;   // record stride 4 ints; src at 4*j
  float acc0 = 0.f, acc1 = 0.f, den = 0.f;
  int jj = j0;
  for (; jj + 8 <= j1; jj += 8) {
    const int sA = csr_i[4 * (jj + sub)];
    const int sB = csr_i[4 * (jj + 4 + sub)];
    const float aA = as2[sA], aB = as2[sB];
    const unsigned uA = ((const unsigned*)(h2b + (size_t)sA * OUT_DIM))[p];
    const unsigned uB = ((const unsigned*)(h2b + (size_t)sB * OUT_DIM))[p];
    float e, w;
    e = aA + adv; e = (e >= 0.f) ? e : NEG * e; w = __expf(e);
    den += w; acc0 += w * b2fl(uA); acc1 += w * b2fh(uA);
    e = aB + adv; e = (e >= 0.f) ? e : NEG * e; w = __expf(e);
    den += w; acc0 += w * b2fl(uB); acc1 += w * b2fh(uB);
  }
  for (; jj < j1; jj += 4) {
    const int idx = jj + sub;
    const bool valid = idx < j1;
    const int s = csr_i[4 * (valid ? idx : (j1 - 1))];
    const float a = as2[s];
    const unsigned u = ((const unsigned*)(h2b + (size_t)s * OUT_DIM))[p];
    float e = a + adv; e = (e >= 0.f) ? e : NEG * e;
    float w = valid ? __expf(e) : 0.f;
    den += w; acc0 += w * b2fl(u); acc1 += w * b2fh(u);
  }
  den  += __shfl_xor(den, 16, 64);  den  += __shfl_xor(den, 32, 64);
  acc0 += __shfl_xor(acc0, 16, 64); acc0 += __shfl_xor(acc0, 32, 64);
  acc1 += __shfl_xor(acc1, 16, 64); acc1 += __shfl_xor(acc1, 32, 64);
  const float inv = 1.0f / den;
  float o0 = acc0 * inv + b2[2 * p];
  float o1 = acc1 * inv + b2[2 * p + 1];
  float m = fmaxf(o0, o1);
#pragma unroll
  for (int mm = 1; mm <= 8; mm <<= 1) m = fmaxf(m, __shfl_xor(m, mm, 64));
  float ssum = __expf(o0 - m) + __expf(o1 - m);
#pragma unroll
  for (int mm = 1; mm <= 8; mm <<= 1) ssum += __shfl_xor(ssum, mm, 64);
  const float lse = m + __logf(ssum);
  float sc = (o0 - lse) * linW[2 * p] + (o1 - lse) * linW[2 * p + 1];
#pragma unroll
  for (int mm = 1; mm <= 8; mm <<= 1) sc += __shfl_xor(sc, mm, 64);
  if (lane == 0) score[node] = sc;
}

// -------- pooling: LDS per-graph partials, few global atomics per block --------
__global__ __launch_bounds__(256) void k_pool(const float* __restrict__ score,
    const int* __restrict__ batch, float* __restrict__ gsum,
    float* __restrict__ gcnt, int n) {
  __shared__ float ps[64];
  __shared__ float pc[64];
  const int tid = threadIdx.x;
  if (tid < 64) { ps[tid] = 0.f; pc[tid] = 0.f; }
  __syncthreads();
  int i = blockIdx.x * 256 + tid;
  if (i < n) {
    int g = batch[i];
    atomicAdd(&ps[g], score[i]);
    atomicAdd(&pc[g], 1.0f);
  }
  __syncthreads();
  if (tid < 64 && pc[tid] != 0.f) {
    atomicAdd(&gsum[tid], ps[tid]);
    atomicAdd(&gcnt[tid], pc[tid]);
  }
}

__global__ void k_final(const float* __restrict__ gsum, const float* __restrict__ gcnt,
                        const float* __restrict__ linb, float* __restrict__ out, int g_) {
  int g = threadIdx.x;
  if (g < g_) out[g] = gsum[g] / fmaxf(gcnt[g], 1.0f) + linb[0];
}

extern "C" void kernel_launch(void* const* d_in, const int* in_sizes, int n_in,
                              void* d_out, int out_size, void* d_ws, size_t ws_size,
                              hipStream_t stream) {
  const float* x    = (const float*)d_in[0];
  const int*   adj  = (const int*)d_in[1];
  const int*   batch= (const int*)d_in[2];
  const float* W1   = (const float*)d_in[3];
  const float* a1s  = (const float*)d_in[4];
  const float* a1d  = (const float*)d_in[5];
  const float* b1   = (const float*)d_in[6];
  const float* W2   = (const float*)d_in[7];
  const float* a2s  = (const float*)d_in[8];
  const float* a2d  = (const float*)d_in[9];
  const float* b2   = (const float*)d_in[10];
  const float* linW = (const float*)d_in[11];
  const float* linb = (const float*)d_in[12];

  const int N = in_sizes[0] / IN_DIM;
  const int E = in_sizes[1] / 2;
  const int ET = E + N;
  const int G = out_size;   // 64
  const int NB = (N + 1023) / 1024;
  const int BINW = (N + 7) / 8;

  char* wsb = (char*)d_ws;
  size_t off = 0;
  auto take = [&](size_t bytes) -> char* {
    char* p = wsb + off;
    off += (bytes + 255) & ~(size_t)255;
    return p;
  };
  unsigned char* h1f8  = (unsigned char*)take((size_t)N * F1);
  unsigned short* relu1b= (unsigned short*)take((size_t)N * F1 * 2);
  float* as1    = (float*)take((size_t)N * 4 * 4);
  float* ad1    = (float*)take((size_t)N * 4 * 4);
  unsigned short* h2b = (unsigned short*)take((size_t)N * OUT_DIM * 2);
  float* as2v   = (float*)take((size_t)N * 4);
  float* ad2v   = (float*)take((size_t)N * 4);
  float* score  = (float*)take((size_t)N * 4);
  int*   cnt    = (int*)take((size_t)N * 4);
  int*   offs   = (int*)take((size_t)(N + 1) * 4);
  int*   rank   = (int*)take((size_t)ET * 4);
  uint4* csr    = (uint4*)take((size_t)ET * 16);
  int*   bsum   = (int*)take((size_t)(NB + 1) * 4);
  float* gsum   = (float*)take((size_t)G * 4);
  float* gcnt   = (float*)take((size_t)G * 4);
  unsigned short* W1t = (unsigned short*)take((size_t)IN_DIM * F1 * 2);
  (void)ws_size; (void)n_in;

  hipMemsetAsync(cnt, 0, (size_t)N * 4, stream);
  hipMemsetAsync(gsum, 0, (size_t)G * 4, stream);
  hipMemsetAsync(gcnt, 0, (size_t)G * 4, stream);

  dim3 b256(256);
  k_prep<<<dim3((IN_DIM * F1) / 256), b256, 0, stream>>>(W1, W1t);
  k_gemm1<<<dim3((N + 63) / 64, F1 / 64), b256, 0, stream>>>(x, W1t, a1s, a1d, h1f8, as1, ad1, N);
  k_hist<<<dim3((ET + 255) / 256), b256, 0, stream>>>(adj, cnt, rank, E, N);
  k_scan_local<<<dim3(NB), b256, 0, stream>>>(cnt, offs, bsum, N);
  k_scan_bsum<<<1, 64, 0, stream>>>(bsum, NB, offs + N);
  k_scan_add<<<dim3((N + 255) / 256), b256, 0, stream>>>(offs, bsum, N);
  k_scatter<<<dim3(((ET + 255) / 256) * 8), b256, 0, stream>>>(adj, rank, offs, as1, ad1, csr, E, N, BINW);
  k_agg1<<<dim3((N + 3) / 4), b256, 0, stream>>>(h1f8, offs, csr, b1, relu1b, N);
  k_gemm2<<<dim3((N + 63) / 64), b256, 0, stream>>>(relu1b, W2, a2s, a2d, h2b, as2v, ad2v, N);
  k_agg2<<<dim3((N + 3) / 4), b256, 0, stream>>>(h2b, as2v, ad2v, offs, csr, b2, linW, score, N);
  k_pool<<<dim3((N + 255) / 256), b256, 0, stream>>>(score, batch, gsum, gcnt, N);
  k_final<<<1, 64, 0, stream>>>(gsum, gcnt, linb, (float*)d_out, G);
}